// Round 1
// baseline (1154.280 us; speedup 1.0000x reference)
//
#include <hip/hip_runtime.h>

// NativeSparseAttention fp32 baseline (correctness-first).
// B=2 S=1024 D=1024 H=KV=16 HD=64 Nc=64 CB=16 SB=8 J=2 W=256
// Workspace layout (floats): q,k,v,acc (2M each) + ck,cv,cxk,cxv,imp (128K each)
// + cpek,cpev (1K) + gates (6K) + tk (4K ints)  => ~36.2 MB total.

constexpr int kS  = 1024;
constexpr int kD  = 1024;
constexpr float kInv = 0.125f;  // 1/sqrt(64)

// ---- cpe[d] = sum_t w[t]*wpe[t][d] (the PE contribution to every compressed block) ----
__global__ __launch_bounds__(256) void cpe_kernel(const float* __restrict__ wkc, const float* __restrict__ wvc,
                                                  const float* __restrict__ wpe,
                                                  float* __restrict__ cpek, float* __restrict__ cpev) {
  int d = blockIdx.x * 256 + threadIdx.x;  // 1024 threads
  float a = 0.f, b = 0.f;
  for (int t = 0; t < 16; ++t) {
    float p = wpe[t * kD + d];
    a += wkc[t] * p;
    b += wvc[t] * p;
  }
  cpek[d] = a;
  cpev[d] = b;
}

// ---- cxk[bn][d] = sum_t wkc[t]*x[b, 16n+t, d] (compress x BEFORE the Wk/Wv GEMM) ----
__global__ __launch_bounds__(256) void cx_kernel(const float* __restrict__ x, const float* __restrict__ wkc,
                                                 const float* __restrict__ wvc,
                                                 float* __restrict__ cxk, float* __restrict__ cxv) {
  int idx = blockIdx.x * 256 + threadIdx.x;  // [0, 128*1024)
  int d  = idx & 1023;
  int bn = idx >> 10;                        // b*64+n ; row = bn*16
  const float* xp = x + (size_t)bn * 16 * kD + d;
  float a = 0.f, c = 0.f;
  for (int t = 0; t < 16; ++t) {
    float xv = xp[(size_t)t * kD];
    a += wkc[t] * xv;
    c += wvc[t] * xv;
  }
  cxk[idx] = a;
  cxv[idx] = c;
}

// ---- generic fp32 tiled GEMM: C = alpha*(A@B) [+ epilogue], row-major ----
// mode 0: none ; mode 1: += wpe[row%16][col] ; mode 2: += epi[col]
// Requires M%64==0, N%64==0, K%16==0 (true for all uses here).
__global__ __launch_bounds__(256) void sgemm_nn(const float* __restrict__ A, const float* __restrict__ Bm,
                                                float* __restrict__ C, int M, int N, int K,
                                                float alpha, int mode, const float* __restrict__ epi) {
  __shared__ float As[16][64];
  __shared__ float Bs[16][68];
  int tid = threadIdx.x;
  int tm = tid >> 4, tn = tid & 15;
  int row0 = blockIdx.y * 64, col0 = blockIdx.x * 64;
  float acc[4][4] = {{0.f}};
  for (int k0 = 0; k0 < K; k0 += 16) {
#pragma unroll
    for (int i = 0; i < 4; ++i) {
      int idx = tid + i * 256;
      As[idx & 15][idx >> 4] = A[(size_t)(row0 + (idx >> 4)) * K + k0 + (idx & 15)];
      Bs[idx >> 6][idx & 63] = Bm[(size_t)(k0 + (idx >> 6)) * N + col0 + (idx & 63)];
    }
    __syncthreads();
#pragma unroll
    for (int kk = 0; kk < 16; ++kk) {
      float a[4], b[4];
#pragma unroll
      for (int i = 0; i < 4; ++i) a[i] = As[kk][tm * 4 + i];
#pragma unroll
      for (int j = 0; j < 4; ++j) b[j] = Bs[kk][tn * 4 + j];
#pragma unroll
      for (int i = 0; i < 4; ++i)
#pragma unroll
        for (int j = 0; j < 4; ++j) acc[i][j] += a[i] * b[j];
    }
    __syncthreads();
  }
#pragma unroll
  for (int i = 0; i < 4; ++i) {
    int r = row0 + tm * 4 + i;
#pragma unroll
    for (int j = 0; j < 4; ++j) {
      int c = col0 + tn * 4 + j;
      float v = alpha * acc[i][j];
      if (mode == 1) v += epi[(r & 15) * kD + c];
      else if (mode == 2) v += epi[c];
      C[(size_t)r * N + c] = v;
    }
  }
}

// ---- NT GEMM: C[m,n] = alpha * sum_k A[m,k]*Bt[n,k]  (imp = inv * q @ ck^T) ----
__global__ __launch_bounds__(256) void sgemm_nt(const float* __restrict__ A, const float* __restrict__ Bt,
                                                float* __restrict__ C, int M, int N, int K, float alpha) {
  __shared__ float As[16][64];
  __shared__ float Bs[16][68];
  int tid = threadIdx.x;
  int tm = tid >> 4, tn = tid & 15;
  int row0 = blockIdx.y * 64, col0 = blockIdx.x * 64;
  float acc[4][4] = {{0.f}};
  for (int k0 = 0; k0 < K; k0 += 16) {
#pragma unroll
    for (int i = 0; i < 4; ++i) {
      int idx = tid + i * 256;
      As[idx & 15][idx >> 4] = A[(size_t)(row0 + (idx >> 4)) * K + k0 + (idx & 15)];
      Bs[idx & 15][idx >> 4] = Bt[(size_t)(col0 + (idx >> 4)) * K + k0 + (idx & 15)];
    }
    __syncthreads();
#pragma unroll
    for (int kk = 0; kk < 16; ++kk) {
      float a[4], b[4];
#pragma unroll
      for (int i = 0; i < 4; ++i) a[i] = As[kk][tm * 4 + i];
#pragma unroll
      for (int j = 0; j < 4; ++j) b[j] = Bs[kk][tn * 4 + j];
#pragma unroll
      for (int i = 0; i < 4; ++i)
#pragma unroll
        for (int j = 0; j < 4; ++j) acc[i][j] += a[i] * b[j];
    }
    __syncthreads();
  }
#pragma unroll
  for (int i = 0; i < 4; ++i) {
    int r = row0 + tm * 4 + i;
#pragma unroll
    for (int j = 0; j < 4; ++j) {
      int c = col0 + tn * 4 + j;
      C[(size_t)r * N + c] = alpha * acc[i][j];
    }
  }
}

// ---- top-2 over 64 blocks per (b,s); ties -> lower index (matches lax.top_k) ----
__global__ __launch_bounds__(256) void topk_kernel(const float* __restrict__ imp, int* __restrict__ tk) {
  int bs = blockIdx.x * 256 + threadIdx.x;  // 2048
  const float* p = imp + (size_t)bs * 64;
  float v1 = -3.0e38f, v2 = -3.0e38f;
  int i1 = 0, i2 = 0;
  for (int n = 0; n < 64; ++n) {
    float v = p[n];
    if (v > v1) { v2 = v1; i2 = i1; v1 = v; i1 = n; }
    else if (v > v2) { v2 = v; i2 = n; }
  }
  tk[bs * 2] = i1;
  tk[bs * 2 + 1] = i2;
}

// ---- gates = sigmoid(x@Wg + bg), one block per (b,s) ----
__global__ __launch_bounds__(256) void gates_kernel(const float* __restrict__ x, const float* __restrict__ Wg,
                                                    const float* __restrict__ bg, float* __restrict__ gates) {
  int bs = blockIdx.x;
  int tid = threadIdx.x;
  __shared__ float red[3][256];
  const float* xp = x + (size_t)bs * kD;
  float p0 = 0.f, p1 = 0.f, p2 = 0.f;
  for (int d = tid; d < kD; d += 256) {
    float xv = xp[d];
    p0 += xv * Wg[d * 3 + 0];
    p1 += xv * Wg[d * 3 + 1];
    p2 += xv * Wg[d * 3 + 2];
  }
  red[0][tid] = p0; red[1][tid] = p1; red[2][tid] = p2;
  __syncthreads();
  for (int off = 128; off > 0; off >>= 1) {
    if (tid < off) {
      red[0][tid] += red[0][tid + off];
      red[1][tid] += red[1][tid + off];
      red[2][tid] += red[2][tid + off];
    }
    __syncthreads();
  }
  if (tid < 3) gates[bs * 3 + tid] = 1.f / (1.f + __expf(-(red[tid][0] + bg[tid])));
}

// ---- compressed attention: wave per (b,s,h); lane=n for scores, lane=d for output ----
__global__ __launch_bounds__(256) void comp_attn(const float* __restrict__ q, const float* __restrict__ ck,
                                                 const float* __restrict__ cv, const float* __restrict__ gates,
                                                 float* __restrict__ acc) {
  int wid = threadIdx.x >> 6, lane = threadIdx.x & 63;
  int g = blockIdx.x * 4 + wid;          // (b*1024+s)*16 + h ; 4 waves share same (b,s)
  int h = g & 15, bs = g >> 4, b = bs >> 10;
  __shared__ float qs[4][64];
  __shared__ float ps[4][64];
  qs[wid][lane] = q[(size_t)bs * kD + h * 64 + lane];
  __syncthreads();
  const float4* ck4 = reinterpret_cast<const float4*>(ck + ((size_t)b * 64 + lane) * kD + h * 64);
  float sc = 0.f;
#pragma unroll
  for (int d4 = 0; d4 < 16; ++d4) {
    float4 kv = ck4[d4];
    sc += qs[wid][d4 * 4] * kv.x + qs[wid][d4 * 4 + 1] * kv.y + qs[wid][d4 * 4 + 2] * kv.z +
          qs[wid][d4 * 4 + 3] * kv.w;
  }
  sc *= kInv;
  float m = sc;
#pragma unroll
  for (int off = 32; off > 0; off >>= 1) m = fmaxf(m, __shfl_xor(m, off));
  float e = __expf(sc - m);
  float ssum = e;
#pragma unroll
  for (int off = 32; off > 0; off >>= 1) ssum += __shfl_xor(ssum, off);
  ps[wid][lane] = e / ssum;
  __syncthreads();
  const float* cvp = cv + (size_t)b * 64 * kD + h * 64 + lane;
  float o = 0.f;
#pragma unroll 8
  for (int n = 0; n < 64; ++n) o += ps[wid][n] * cvp[(size_t)n * kD];
  float g0 = gates[bs * 3 + 0];
  acc[(size_t)bs * kD + h * 64 + lane] = g0 * o;  // first writer of acc
}

// ---- selected attention: out batch b, slot j -> tokens from batch j, block tk[j,s,b] ----
__global__ __launch_bounds__(256) void sel_attn(const float* __restrict__ q, const float* __restrict__ k,
                                                const float* __restrict__ v, const int* __restrict__ tk,
                                                const float* __restrict__ gates, float* __restrict__ acc) {
  int wid = threadIdx.x >> 6, lane = threadIdx.x & 63;
  int g = blockIdx.x * 4 + wid;
  int h = g & 15, bs = g >> 4, b = bs >> 10, s = bs & 1023;
  __shared__ float qs[4][64];
  __shared__ float ps[4][16];
  __shared__ int toks[4][16];
  qs[wid][lane] = q[(size_t)bs * kD + h * 64 + lane];
  if (lane < 16) {
    int j = lane >> 3, t = lane & 7;
    int blk = tk[((size_t)j * 1024 + s) * 2 + b];   // top_idx[j, s, b]
    toks[wid][lane] = j * 1024 + blk * 16 + t;      // flat row in k/v (batch j)
  }
  __syncthreads();
  if (lane < 16) {
    const float4* kp = reinterpret_cast<const float4*>(k + (size_t)toks[wid][lane] * kD + h * 64);
    float sc = 0.f;
#pragma unroll
    for (int d4 = 0; d4 < 16; ++d4) {
      float4 kv = kp[d4];
      sc += qs[wid][d4 * 4] * kv.x + qs[wid][d4 * 4 + 1] * kv.y + qs[wid][d4 * 4 + 2] * kv.z +
            qs[wid][d4 * 4 + 3] * kv.w;
    }
    sc *= kInv;
    float m = sc;
#pragma unroll
    for (int off = 8; off > 0; off >>= 1) m = fmaxf(m, __shfl_xor(m, off, 16));
    float e = __expf(sc - m);
    float ss = e;
#pragma unroll
    for (int off = 8; off > 0; off >>= 1) ss += __shfl_xor(ss, off, 16);
    ps[wid][lane] = e / ss;
  }
  __syncthreads();
  float o = 0.f;
#pragma unroll
  for (int mi = 0; mi < 16; ++mi) o += ps[wid][mi] * v[(size_t)toks[wid][mi] * kD + h * 64 + lane];
  float g1 = gates[bs * 3 + 1];
  acc[(size_t)bs * kD + h * 64 + lane] += g1 * o;
}

// ---- sliding-window causal attention (online softmax), wave per (b,s,h) ----
__global__ __launch_bounds__(256) void win_attn(const float* __restrict__ q, const float* __restrict__ k,
                                                const float* __restrict__ v, const float* __restrict__ gates,
                                                float* __restrict__ acc) {
  int wid = threadIdx.x >> 6, lane = threadIdx.x & 63;
  int g = blockIdx.x * 4 + wid;            // 4 waves share the same s => uniform loop trips
  int h = g & 15, bs = g >> 4, b = bs >> 10, s = bs & 1023;
  __shared__ float qs[4][64];
  __shared__ float ps[4][64];
  qs[wid][lane] = q[(size_t)bs * kD + h * 64 + lane];
  __syncthreads();
  int j0 = s - 256; if (j0 < 0) j0 = 0;
  int cnt = s - j0 + 1;                    // 1..257 keys
  const float* kb = k + (size_t)b * kS * kD + h * 64;
  const float* vb = v + (size_t)b * kS * kD + h * 64 + lane;
  float m = -3.0e38f, l = 0.f, o = 0.f;
  for (int c0 = 0; c0 < cnt; c0 += 64) {
    int nn = cnt - c0; if (nn > 64) nn = 64;
    float sc = -3.0e38f;
    if (lane < nn) {
      const float4* kp = reinterpret_cast<const float4*>(kb + (size_t)(j0 + c0 + lane) * kD);
      float a = 0.f;
#pragma unroll
      for (int d4 = 0; d4 < 16; ++d4) {
        float4 kv = kp[d4];
        a += qs[wid][d4 * 4] * kv.x + qs[wid][d4 * 4 + 1] * kv.y + qs[wid][d4 * 4 + 2] * kv.z +
             qs[wid][d4 * 4 + 3] * kv.w;
      }
      sc = a * kInv;
    }
    float cm = sc;
#pragma unroll
    for (int off = 32; off > 0; off >>= 1) cm = fmaxf(cm, __shfl_xor(cm, off));
    float mn = fmaxf(m, cm);
    float e = (lane < nn) ? __expf(sc - mn) : 0.f;
    float es = e;
#pragma unroll
    for (int off = 32; off > 0; off >>= 1) es += __shfl_xor(es, off);
    float scale = __expf(m - mn);          // 0 on first chunk (m = -3e38)
    l = l * scale + es;
    o = o * scale;
    ps[wid][lane] = e;
    __syncthreads();
    const float* vp = vb + (size_t)(j0 + c0) * kD;
    for (int t = 0; t < nn; ++t) o += ps[wid][t] * vp[(size_t)t * kD];
    __syncthreads();
    m = mn;
  }
  float g2 = gates[bs * 3 + 2];
  acc[(size_t)bs * kD + h * 64 + lane] += g2 * o / l;
}

extern "C" void kernel_launch(void* const* d_in, const int* in_sizes, int n_in,
                              void* d_out, int out_size, void* d_ws, size_t ws_size,
                              hipStream_t stream) {
  const float* x   = (const float*)d_in[0];
  const float* Wq  = (const float*)d_in[1];
  const float* Wk  = (const float*)d_in[2];
  const float* Wv  = (const float*)d_in[3];
  const float* Wo  = (const float*)d_in[4];
  const float* bo  = (const float*)d_in[5];
  const float* Wg  = (const float*)d_in[6];
  const float* bg  = (const float*)d_in[7];
  const float* wkc = (const float*)d_in[8];
  const float* wvc = (const float*)d_in[9];
  const float* wpe = (const float*)d_in[10];
  float* out = (float*)d_out;

  float* ws   = (float*)d_ws;
  float* q    = ws;                  // 2048*1024
  float* kbuf = q + 2097152;
  float* vbuf = kbuf + 2097152;
  float* accb = vbuf + 2097152;
  float* ck   = accb + 2097152;      // 128*1024
  float* cv   = ck + 131072;
  float* cxk  = cv + 131072;
  float* cxv  = cxk + 131072;
  float* imp  = cxv + 131072;        // 2*1024*64
  float* cpek = imp + 131072;        // 1024
  float* cpev = cpek + 1024;
  float* gat  = cpev + 1024;         // 2048*3
  int*   tk   = (int*)(gat + 6144);  // 2048*2 ints

  cpe_kernel<<<4, 256, 0, stream>>>(wkc, wvc, wpe, cpek, cpev);
  cx_kernel<<<512, 256, 0, stream>>>(x, wkc, wvc, cxk, cxv);

  dim3 gBig(16, 32);  // N/64, M/64 for 2048x1024
  sgemm_nn<<<gBig, 256, 0, stream>>>(x, Wq, q,    2048, 1024, 1024, 1.f, 0, nullptr);
  sgemm_nn<<<gBig, 256, 0, stream>>>(x, Wk, kbuf, 2048, 1024, 1024, 1.f, 1, wpe);
  sgemm_nn<<<gBig, 256, 0, stream>>>(x, Wv, vbuf, 2048, 1024, 1024, 1.f, 1, wpe);

  dim3 gCk(16, 2);    // 128x1024 thin GEMMs for compressed K/V
  sgemm_nn<<<gCk, 256, 0, stream>>>(cxk, Wk, ck, 128, 1024, 1024, 1.f, 2, cpek);
  sgemm_nn<<<gCk, 256, 0, stream>>>(cxv, Wv, cv, 128, 1024, 1024, 1.f, 2, cpev);

  dim3 gImp(1, 16);   // imp_b = inv * q_b @ ck_b^T  (1024x64x1024), fp32 for exact top-k
  sgemm_nt<<<gImp, 256, 0, stream>>>(q,           ck,          imp,          1024, 64, 1024, kInv);
  sgemm_nt<<<gImp, 256, 0, stream>>>(q + 1048576, ck + 65536,  imp + 65536,  1024, 64, 1024, kInv);

  topk_kernel<<<8, 256, 0, stream>>>(imp, tk);
  gates_kernel<<<2048, 256, 0, stream>>>(x, Wg, bg, gat);

  comp_attn<<<8192, 256, 0, stream>>>(q, ck, cv, gat, accb);         // writes acc = g0*out_comp
  sel_attn<<<8192, 256, 0, stream>>>(q, kbuf, vbuf, tk, gat, accb);  // acc += g1*out_sel
  win_attn<<<8192, 256, 0, stream>>>(q, kbuf, vbuf, gat, accb);      // acc += g2*out_win

  sgemm_nn<<<gBig, 256, 0, stream>>>(accb, Wo, out, 2048, 1024, 1024, 1.f, 2, bo);
}

// Round 2
// 707.319 us; speedup vs baseline: 1.6319x; 1.6319x over previous
//
#include <hip/hip_runtime.h>

// NativeSparseAttention round 2: bf16 MFMA for the 4 big GEMMs (smooth paths),
// fp32 imp path via imp = x @ (Wq @ ck^T) for exact top-k, LDS-tiled flash
// win/comp attention.
// B=2 S=1024 D=1024 H=KV=16 HD=64 Nc=64 CB=16 SB=8 J=2 W=256

typedef __bf16 bf16;
typedef bf16 bf16x8 __attribute__((ext_vector_type(8)));
typedef float f32x4 __attribute__((ext_vector_type(4)));

constexpr int kD = 1024;
constexpr float kInv = 0.125f;  // 1/sqrt(64)

// ---- cpe[d] = sum_t w[t]*wpe[t][d] ----
__global__ __launch_bounds__(256) void cpe_kernel(const float* __restrict__ wkc, const float* __restrict__ wvc,
                                                  const float* __restrict__ wpe,
                                                  float* __restrict__ cpek, float* __restrict__ cpev) {
  int d = blockIdx.x * 256 + threadIdx.x;
  float a = 0.f, b = 0.f;
  for (int t = 0; t < 16; ++t) {
    float p = wpe[t * kD + d];
    a += wkc[t] * p;
    b += wvc[t] * p;
  }
  cpek[d] = a;
  cpev[d] = b;
}

// ---- cxk[bn][d] = sum_t wkc[t]*x[b, 16n+t, d] ----
__global__ __launch_bounds__(256) void cx_kernel(const float* __restrict__ x, const float* __restrict__ wkc,
                                                 const float* __restrict__ wvc,
                                                 float* __restrict__ cxk, float* __restrict__ cxv) {
  int idx = blockIdx.x * 256 + threadIdx.x;  // [0, 128*1024)
  int d = idx & 1023;
  int bn = idx >> 10;
  const float* xp = x + (size_t)bn * 16 * kD + d;
  float a = 0.f, c = 0.f;
  for (int t = 0; t < 16; ++t) {
    float xv = xp[(size_t)t * kD];
    a += wkc[t] * xv;
    c += wvc[t] * xv;
  }
  cxk[idx] = a;
  cxv[idx] = c;
}

// ---- transpose fp32 [R][C] -> bf16 [C][R] (weights to B^T form for MFMA NT GEMM) ----
__global__ __launch_bounds__(256) void transpose_to_bf16(const float* __restrict__ in, bf16* __restrict__ out,
                                                         int R, int C) {
  __shared__ float t[32][33];
  int c0 = blockIdx.x * 32, r0 = blockIdx.y * 32;
  int tx = threadIdx.x & 31, ty = threadIdx.x >> 5;
#pragma unroll
  for (int i = 0; i < 32; i += 8) t[ty + i][tx] = in[(size_t)(r0 + ty + i) * C + c0 + tx];
  __syncthreads();
#pragma unroll
  for (int i = 0; i < 32; i += 8) out[(size_t)(c0 + ty + i) * R + r0 + tx] = (bf16)t[tx][ty + i];
}

// ---- bf16 MFMA GEMM: C[M][N] = A[M][K] @ Bt[N][K]^T (+ epilogue), A fp32 converted on the fly.
// BM=64 BN=64 BK=32, 256 threads = 4 waves, wave quadrant 32x32 (2x2 mfma_16x16x32).
// mode 0: none; 1: += wpe[row%16][col]; 2: += epi[col]
__global__ __launch_bounds__(256) void gemm_bf16(const float* __restrict__ A, const bf16* __restrict__ Bt,
                                                 float* __restrict__ C, int M, int N, int K,
                                                 int mode, const float* __restrict__ epi) {
  __shared__ __align__(16) bf16 As[64][32];
  __shared__ __align__(16) bf16 Bs[64][32];
  int tid = threadIdx.x;
  int wid = tid >> 6, lane = tid & 63;
  int row0 = blockIdx.y * 64, col0 = blockIdx.x * 64;
  int mh = (wid & 1) * 32, nh = (wid >> 1) * 32;
  int lrow = tid >> 2, lcol = (tid & 3) * 8;
  int qd = lane >> 4, l16 = lane & 15;
  f32x4 acc[2][2] = {};
  for (int k0 = 0; k0 < K; k0 += 32) {
    // stage A (fp32 -> bf16) and Bt (bf16)
    const float4* ap = (const float4*)&A[(size_t)(row0 + lrow) * K + k0 + lcol];
    float4 a0 = ap[0], a1 = ap[1];
    bf16x8 av;
    av[0] = (bf16)a0.x; av[1] = (bf16)a0.y; av[2] = (bf16)a0.z; av[3] = (bf16)a0.w;
    av[4] = (bf16)a1.x; av[5] = (bf16)a1.y; av[6] = (bf16)a1.z; av[7] = (bf16)a1.w;
    bf16x8 bv = *(const bf16x8*)&Bt[(size_t)(col0 + lrow) * K + k0 + lcol];
    *(bf16x8*)&As[lrow][lcol] = av;
    *(bf16x8*)&Bs[lrow][lcol] = bv;
    __syncthreads();
    bf16x8 af[2], bfr[2];
#pragma unroll
    for (int i = 0; i < 2; ++i) af[i] = *(const bf16x8*)&As[mh + i * 16 + l16][qd * 8];
#pragma unroll
    for (int j = 0; j < 2; ++j) bfr[j] = *(const bf16x8*)&Bs[nh + j * 16 + l16][qd * 8];
#pragma unroll
    for (int i = 0; i < 2; ++i)
#pragma unroll
      for (int j = 0; j < 2; ++j)
        acc[i][j] = __builtin_amdgcn_mfma_f32_16x16x32_bf16(af[i], bfr[j], acc[i][j], 0, 0, 0);
    __syncthreads();
  }
  // C/D layout: col = lane&15, row = (lane>>4)*4 + reg  [measured m89]
#pragma unroll
  for (int i = 0; i < 2; ++i)
#pragma unroll
    for (int j = 0; j < 2; ++j)
#pragma unroll
      for (int r = 0; r < 4; ++r) {
        int rr = row0 + mh + i * 16 + qd * 4 + r;
        int cc = col0 + nh + j * 16 + l16;
        float v = acc[i][j][r];
        if (mode == 1) v += epi[(rr & 15) * kD + cc];
        else if (mode == 2) v += epi[cc];
        C[(size_t)rr * N + cc] = v;
      }
}

// ---- fp32 tiled NN GEMM (ck/cv path; stays fp32 because it feeds top-k) ----
__global__ __launch_bounds__(256) void sgemm_nn(const float* __restrict__ A, const float* __restrict__ Bm,
                                                float* __restrict__ C, int M, int N, int K,
                                                float alpha, int mode, const float* __restrict__ epi) {
  __shared__ float As[16][64];
  __shared__ float Bs[16][68];
  int tid = threadIdx.x;
  int tm = tid >> 4, tn = tid & 15;
  int row0 = blockIdx.y * 64, col0 = blockIdx.x * 64;
  float acc[4][4] = {{0.f}};
  for (int k0 = 0; k0 < K; k0 += 16) {
#pragma unroll
    for (int i = 0; i < 4; ++i) {
      int idx = tid + i * 256;
      As[idx & 15][idx >> 4] = A[(size_t)(row0 + (idx >> 4)) * K + k0 + (idx & 15)];
      Bs[idx >> 6][idx & 63] = Bm[(size_t)(k0 + (idx >> 6)) * N + col0 + (idx & 63)];
    }
    __syncthreads();
#pragma unroll
    for (int kk = 0; kk < 16; ++kk) {
      float a[4], b[4];
#pragma unroll
      for (int i = 0; i < 4; ++i) a[i] = As[kk][tm * 4 + i];
#pragma unroll
      for (int j = 0; j < 4; ++j) b[j] = Bs[kk][tn * 4 + j];
#pragma unroll
      for (int i = 0; i < 4; ++i)
#pragma unroll
        for (int j = 0; j < 4; ++j) acc[i][j] += a[i] * b[j];
    }
    __syncthreads();
  }
#pragma unroll
  for (int i = 0; i < 4; ++i) {
    int r = row0 + tm * 4 + i;
#pragma unroll
    for (int j = 0; j < 4; ++j) {
      int c = col0 + tn * 4 + j;
      float v = alpha * acc[i][j];
      if (mode == 2) v += epi[c];
      C[(size_t)r * N + c] = v;
    }
  }
}

// ---- fp32 NT GEMM: M1[d][bn] = sum_k Wq[d][k]*ck[bn][k]  (imp path, fp32) ----
__global__ __launch_bounds__(256) void sgemm_nt(const float* __restrict__ A, const float* __restrict__ Bt,
                                                float* __restrict__ C, int M, int N, int K, float alpha) {
  __shared__ float As[16][64];
  __shared__ float Bs[16][68];
  int tid = threadIdx.x;
  int tm = tid >> 4, tn = tid & 15;
  int row0 = blockIdx.y * 64, col0 = blockIdx.x * 64;
  float acc[4][4] = {{0.f}};
  for (int k0 = 0; k0 < K; k0 += 16) {
#pragma unroll
    for (int i = 0; i < 4; ++i) {
      int idx = tid + i * 256;
      As[idx & 15][idx >> 4] = A[(size_t)(row0 + (idx >> 4)) * K + k0 + (idx & 15)];
      Bs[idx & 15][idx >> 4] = Bt[(size_t)(col0 + (idx >> 4)) * K + k0 + (idx & 15)];
    }
    __syncthreads();
#pragma unroll
    for (int kk = 0; kk < 16; ++kk) {
      float a[4], b[4];
#pragma unroll
      for (int i = 0; i < 4; ++i) a[i] = As[kk][tm * 4 + i];
#pragma unroll
      for (int j = 0; j < 4; ++j) b[j] = Bs[kk][tn * 4 + j];
#pragma unroll
      for (int i = 0; i < 4; ++i)
#pragma unroll
        for (int j = 0; j < 4; ++j) acc[i][j] += a[i] * b[j];
    }
    __syncthreads();
  }
#pragma unroll
  for (int i = 0; i < 4; ++i) {
    int r = row0 + tm * 4 + i;
#pragma unroll
    for (int j = 0; j < 4; ++j) {
      int c = col0 + tn * 4 + j;
      C[(size_t)r * N + c] = alpha * acc[i][j];
    }
  }
}

// ---- imp[bs][n] = inv * sum_d x[bs][d] * M1[d][(bs>>10)*64 + n] ----
__global__ __launch_bounds__(256) void imp_gemm(const float* __restrict__ A, const float* __restrict__ Bm,
                                                float* __restrict__ C) {
  __shared__ float As[16][64];
  __shared__ float Bs[16][68];
  int tid = threadIdx.x;
  int tm = tid >> 4, tn = tid & 15;
  int row0 = blockIdx.y * 64;
  int colbase = (row0 >> 10) * 64;
  float acc[4][4] = {{0.f}};
  for (int k0 = 0; k0 < 1024; k0 += 16) {
#pragma unroll
    for (int i = 0; i < 4; ++i) {
      int idx = tid + i * 256;
      As[idx & 15][idx >> 4] = A[(size_t)(row0 + (idx >> 4)) * 1024 + k0 + (idx & 15)];
      Bs[idx >> 6][idx & 63] = Bm[(size_t)(k0 + (idx >> 6)) * 128 + colbase + (idx & 63)];
    }
    __syncthreads();
#pragma unroll
    for (int kk = 0; kk < 16; ++kk) {
      float a[4], b[4];
#pragma unroll
      for (int i = 0; i < 4; ++i) a[i] = As[kk][tm * 4 + i];
#pragma unroll
      for (int j = 0; j < 4; ++j) b[j] = Bs[kk][tn * 4 + j];
#pragma unroll
      for (int i = 0; i < 4; ++i)
#pragma unroll
        for (int j = 0; j < 4; ++j) acc[i][j] += a[i] * b[j];
    }
    __syncthreads();
  }
#pragma unroll
  for (int i = 0; i < 4; ++i) {
    int r = row0 + tm * 4 + i;
#pragma unroll
    for (int j = 0; j < 4; ++j) C[(size_t)r * 64 + tn * 4 + j] = kInv * acc[i][j];
  }
}

// ---- top-2 over 64 blocks per (b,s) ----
__global__ __launch_bounds__(256) void topk_kernel(const float* __restrict__ imp, int* __restrict__ tk) {
  int bs = blockIdx.x * 256 + threadIdx.x;
  const float* p = imp + (size_t)bs * 64;
  float v1 = -3.0e38f, v2 = -3.0e38f;
  int i1 = 0, i2 = 0;
  for (int n = 0; n < 64; ++n) {
    float v = p[n];
    if (v > v1) { v2 = v1; i2 = i1; v1 = v; i1 = n; }
    else if (v > v2) { v2 = v; i2 = n; }
  }
  tk[bs * 2] = i1;
  tk[bs * 2 + 1] = i2;
}

// ---- gates = sigmoid(x@Wg + bg) ----
__global__ __launch_bounds__(256) void gates_kernel(const float* __restrict__ x, const float* __restrict__ Wg,
                                                    const float* __restrict__ bg, float* __restrict__ gates) {
  int bs = blockIdx.x;
  int tid = threadIdx.x;
  __shared__ float red[3][256];
  const float* xp = x + (size_t)bs * kD;
  float p0 = 0.f, p1 = 0.f, p2 = 0.f;
  for (int d = tid; d < kD; d += 256) {
    float xv = xp[d];
    p0 += xv * Wg[d * 3 + 0];
    p1 += xv * Wg[d * 3 + 1];
    p2 += xv * Wg[d * 3 + 2];
  }
  red[0][tid] = p0; red[1][tid] = p1; red[2][tid] = p2;
  __syncthreads();
  for (int off = 128; off > 0; off >>= 1) {
    if (tid < off) {
      red[0][tid] += red[0][tid + off];
      red[1][tid] += red[1][tid + off];
      red[2][tid] += red[2][tid + off];
    }
    __syncthreads();
  }
  if (tid < 3) gates[bs * 3 + tid] = 1.f / (1.f + __expf(-(red[tid][0] + bg[tid])));
}

// ---- compressed attention, LDS-tiled: block = (64-query tile, h, b) ----
__global__ __launch_bounds__(256) void comp_attn2(const float* __restrict__ q, const float* __restrict__ ck,
                                                  const float* __restrict__ cv, const float* __restrict__ gat,
                                                  float* __restrict__ acc) {
  __shared__ float Qs[64][64];
  __shared__ float Ks[64][68];
  __shared__ float Vs[64][64];
  __shared__ float ps[4][8][64];
  int tid = threadIdx.x, wid = tid >> 6, lane = tid & 63;
  int s0 = blockIdx.x * 64, h = blockIdx.y, b = blockIdx.z;
  {
    int r = tid >> 2, c = (tid & 3) * 16;
    const float* qsrc = q + ((size_t)(b * 1024 + s0 + r)) * kD + h * 64 + c;
    const float* ksrc = ck + ((size_t)(b * 64 + r)) * kD + h * 64 + c;
    const float* vsrc = cv + ((size_t)(b * 64 + r)) * kD + h * 64 + c;
#pragma unroll
    for (int i = 0; i < 4; ++i) {
      *(float4*)&Qs[r][c + i * 4] = ((const float4*)qsrc)[i];
      *(float4*)&Ks[r][c + i * 4] = ((const float4*)ksrc)[i];
      *(float4*)&Vs[r][c + i * 4] = ((const float4*)vsrc)[i];
    }
  }
  __syncthreads();
#pragma unroll
  for (int grp = 0; grp < 2; ++grp) {
    float sc[8];
#pragma unroll
    for (int qi = 0; qi < 8; ++qi) sc[qi] = 0.f;
#pragma unroll 4
    for (int d4 = 0; d4 < 16; ++d4) {
      float4 kv = *(const float4*)&Ks[lane][d4 * 4];
#pragma unroll
      for (int qi = 0; qi < 8; ++qi) {
        float4 qv = *(const float4*)&Qs[wid * 16 + grp * 8 + qi][d4 * 4];
        sc[qi] += kv.x * qv.x + kv.y * qv.y + kv.z * qv.z + kv.w * qv.w;
      }
    }
    float es[8];
#pragma unroll
    for (int qi = 0; qi < 8; ++qi) {
      float scv = sc[qi] * kInv;
      float cm = scv;
#pragma unroll
      for (int off = 32; off; off >>= 1) cm = fmaxf(cm, __shfl_xor(cm, off));
      float e = __expf(scv - cm);
      float s = e;
#pragma unroll
      for (int off = 32; off; off >>= 1) s += __shfl_xor(s, off);
      es[qi] = s;
      ps[wid][qi][lane] = e;
    }
    float o[8];
#pragma unroll
    for (int qi = 0; qi < 8; ++qi) o[qi] = 0.f;
#pragma unroll 4
    for (int n4 = 0; n4 < 16; ++n4) {
      float v0 = Vs[n4 * 4 + 0][lane], v1 = Vs[n4 * 4 + 1][lane];
      float v2 = Vs[n4 * 4 + 2][lane], v3 = Vs[n4 * 4 + 3][lane];
#pragma unroll
      for (int qi = 0; qi < 8; ++qi) {
        float4 p = *(const float4*)&ps[wid][qi][n4 * 4];
        o[qi] += p.x * v0 + p.y * v1 + p.z * v2 + p.w * v3;
      }
    }
#pragma unroll
    for (int qi = 0; qi < 8; ++qi) {
      int s = s0 + wid * 16 + grp * 8 + qi;
      size_t row = (size_t)b * 1024 + s;
      float g0 = gat[row * 3 + 0];
      acc[row * kD + h * 64 + lane] = g0 * o[qi] / es[qi];  // first writer of acc
    }
  }
}

// ---- selected attention (unchanged from passing round) ----
__global__ __launch_bounds__(256) void sel_attn(const float* __restrict__ q, const float* __restrict__ k,
                                                const float* __restrict__ v, const int* __restrict__ tk,
                                                const float* __restrict__ gates, float* __restrict__ acc) {
  int wid = threadIdx.x >> 6, lane = threadIdx.x & 63;
  int g = blockIdx.x * 4 + wid;
  int h = g & 15, bs = g >> 4, b = bs >> 10, s = bs & 1023;
  __shared__ float qs[4][64];
  __shared__ float ps[4][16];
  __shared__ int toks[4][16];
  qs[wid][lane] = q[(size_t)bs * kD + h * 64 + lane];
  if (lane < 16) {
    int j = lane >> 3, t = lane & 7;
    int blk = tk[((size_t)j * 1024 + s) * 2 + b];   // top_idx[j, s, b]
    toks[wid][lane] = j * 1024 + blk * 16 + t;
  }
  __syncthreads();
  if (lane < 16) {
    const float4* kp = reinterpret_cast<const float4*>(k + (size_t)toks[wid][lane] * kD + h * 64);
    float sc = 0.f;
#pragma unroll
    for (int d4 = 0; d4 < 16; ++d4) {
      float4 kv = kp[d4];
      sc += qs[wid][d4 * 4] * kv.x + qs[wid][d4 * 4 + 1] * kv.y + qs[wid][d4 * 4 + 2] * kv.z +
            qs[wid][d4 * 4 + 3] * kv.w;
    }
    sc *= kInv;
    float m = sc;
#pragma unroll
    for (int off = 8; off > 0; off >>= 1) m = fmaxf(m, __shfl_xor(m, off, 16));
    float e = __expf(sc - m);
    float ss = e;
#pragma unroll
    for (int off = 8; off > 0; off >>= 1) ss += __shfl_xor(ss, off, 16);
    ps[wid][lane] = e / ss;
  }
  __syncthreads();
  float o = 0.f;
#pragma unroll
  for (int mi = 0; mi < 16; ++mi) o += ps[wid][mi] * v[(size_t)toks[wid][mi] * kD + h * 64 + lane];
  float g1 = gates[bs * 3 + 1];
  acc[(size_t)bs * kD + h * 64 + lane] += g1 * o;
}

// ---- sliding-window attention, LDS-tiled flash: block = (64-query tile, h, b) ----
__global__ __launch_bounds__(256) void win_attn2(const float* __restrict__ q, const float* __restrict__ k,
                                                 const float* __restrict__ v, const float* __restrict__ gat,
                                                 float* __restrict__ acc) {
  __shared__ float Qs[64][64];
  __shared__ float Ks[64][68];
  __shared__ float Vs[64][64];
  __shared__ float ps[4][8][64];
  int tid = threadIdx.x, wid = tid >> 6, lane = tid & 63;
  int s0 = blockIdx.x * 64, h = blockIdx.y, b = blockIdx.z;
  {
    int r = tid >> 2, c = (tid & 3) * 16;
    const float* qsrc = q + ((size_t)(b * 1024 + s0 + r)) * kD + h * 64 + c;
#pragma unroll
    for (int i = 0; i < 4; ++i) *(float4*)&Qs[r][c + i * 4] = ((const float4*)qsrc)[i];
  }
  int kb0 = s0 - 256; if (kb0 < 0) kb0 = 0;
  int nck = (s0 + 64 - kb0) >> 6;   // 1..5 chunks of 64 keys
  float m[16], l[16], o[16];
#pragma unroll
  for (int i = 0; i < 16; ++i) { m[i] = -3.0e38f; l[i] = 0.f; o[i] = 0.f; }
  for (int c = 0; c < nck; ++c) {
    int kbase = kb0 + c * 64;
    __syncthreads();
    {
      int r = tid >> 2, cc = (tid & 3) * 16;
      const float* ksrc = k + ((size_t)(b * 1024 + kbase + r)) * kD + h * 64 + cc;
      const float* vsrc = v + ((size_t)(b * 1024 + kbase + r)) * kD + h * 64 + cc;
#pragma unroll
      for (int i = 0; i < 4; ++i) {
        *(float4*)&Ks[r][cc + i * 4] = ((const float4*)ksrc)[i];
        *(float4*)&Vs[r][cc + i * 4] = ((const float4*)vsrc)[i];
      }
    }
    __syncthreads();
    int gk = kbase + lane;
#pragma unroll
    for (int grp = 0; grp < 2; ++grp) {
      float sc[8];
#pragma unroll
      for (int qi = 0; qi < 8; ++qi) sc[qi] = 0.f;
#pragma unroll 4
      for (int d4 = 0; d4 < 16; ++d4) {
        float4 kv = *(const float4*)&Ks[lane][d4 * 4];
#pragma unroll
        for (int qi = 0; qi < 8; ++qi) {
          float4 qv = *(const float4*)&Qs[wid * 16 + grp * 8 + qi][d4 * 4];
          sc[qi] += kv.x * qv.x + kv.y * qv.y + kv.z * qv.z + kv.w * qv.w;
        }
      }
      float alpha[8];
#pragma unroll
      for (int qi = 0; qi < 8; ++qi) {
        int qidx = grp * 8 + qi;
        int s = s0 + wid * 16 + qidx;
        // every chunk has >=1 valid key per query (window geometry), so mn stays finite
        float scv = (gk <= s && s - gk <= 256) ? sc[qi] * kInv : -3.0e38f;
        float cm = scv;
#pragma unroll
        for (int off = 32; off; off >>= 1) cm = fmaxf(cm, __shfl_xor(cm, off));
        float mn = fmaxf(m[qidx], cm);
        float e = __expf(scv - mn);
        float esum = e;
#pragma unroll
        for (int off = 32; off; off >>= 1) esum += __shfl_xor(esum, off);
        alpha[qi] = __expf(m[qidx] - mn);
        l[qidx] = l[qidx] * alpha[qi] + esum;
        m[qidx] = mn;
        ps[wid][qi][lane] = e;
      }
#pragma unroll
      for (int qi = 0; qi < 8; ++qi) o[grp * 8 + qi] *= alpha[qi];
#pragma unroll 4
      for (int n4 = 0; n4 < 16; ++n4) {
        float v0 = Vs[n4 * 4 + 0][lane], v1 = Vs[n4 * 4 + 1][lane];
        float v2 = Vs[n4 * 4 + 2][lane], v3 = Vs[n4 * 4 + 3][lane];
#pragma unroll
        for (int qi = 0; qi < 8; ++qi) {
          float4 p = *(const float4*)&ps[wid][qi][n4 * 4];
          o[grp * 8 + qi] += p.x * v0 + p.y * v1 + p.z * v2 + p.w * v3;
        }
      }
    }
  }
#pragma unroll
  for (int qidx = 0; qidx < 16; ++qidx) {
    int s = s0 + wid * 16 + qidx;
    size_t row = (size_t)b * 1024 + s;
    float g2 = gat[row * 3 + 2];
    acc[row * kD + h * 64 + lane] += g2 * o[qidx] / l[qidx];
  }
}

extern "C" void kernel_launch(void* const* d_in, const int* in_sizes, int n_in,
                              void* d_out, int out_size, void* d_ws, size_t ws_size,
                              hipStream_t stream) {
  const float* x   = (const float*)d_in[0];
  const float* Wq  = (const float*)d_in[1];
  const float* Wk  = (const float*)d_in[2];
  const float* Wv  = (const float*)d_in[3];
  const float* Wo  = (const float*)d_in[4];
  const float* bo  = (const float*)d_in[5];
  const float* Wg  = (const float*)d_in[6];
  const float* bg  = (const float*)d_in[7];
  const float* wkc = (const float*)d_in[8];
  const float* wvc = (const float*)d_in[9];
  const float* wpe = (const float*)d_in[10];
  float* out = (float*)d_out;

  float* ws   = (float*)d_ws;
  float* q    = ws;                   // 2097152
  float* kbuf = q + 2097152;
  float* vbuf = kbuf + 2097152;
  float* accb = vbuf + 2097152;
  float* ck   = accb + 2097152;       // 131072
  float* cv   = ck + 131072;
  float* cxk  = cv + 131072;          // later reused as M1 [1024][128]
  float* cxv  = cxk + 131072;         // later reused as imp [2048][64]
  float* cpek = cxv + 131072;
  float* cpev = cpek + 1024;
  float* gat  = cpev + 1024;          // 2048*3
  int*   tk   = (int*)(gat + 6144);   // 4096 ints
  bf16*  Wt   = (bf16*)(gat + 6144 + 4096);  // 1048576 bf16 (one transposed weight at a time)
  float* M1   = cxk;
  float* imp  = cxv;

  cpe_kernel<<<4, 256, 0, stream>>>(wkc, wvc, wpe, cpek, cpev);
  cx_kernel<<<512, 256, 0, stream>>>(x, wkc, wvc, cxk, cxv);

  dim3 gT(32, 32);
  dim3 gBig(16, 32);  // N/64, M/64 for 2048x1024
  // q = x@Wq (bf16 MFMA; attention-only consumer, smooth)
  transpose_to_bf16<<<gT, 256, 0, stream>>>(Wq, Wt, 1024, 1024);
  gemm_bf16<<<gBig, 256, 0, stream>>>(x, Wt, q, 2048, 1024, 1024, 0, nullptr);
  // k = x@Wk + pe
  transpose_to_bf16<<<gT, 256, 0, stream>>>(Wk, Wt, 1024, 1024);
  gemm_bf16<<<gBig, 256, 0, stream>>>(x, Wt, kbuf, 2048, 1024, 1024, 1, wpe);
  // v = x@Wv + pe
  transpose_to_bf16<<<gT, 256, 0, stream>>>(Wv, Wt, 1024, 1024);
  gemm_bf16<<<gBig, 256, 0, stream>>>(x, Wt, vbuf, 2048, 1024, 1024, 1, wpe);

  // compressed K/V (fp32 — feeds top-k path)
  dim3 gCk(16, 2);
  sgemm_nn<<<gCk, 256, 0, stream>>>(cxk, Wk, ck, 128, 1024, 1024, 1.f, 2, cpek);
  sgemm_nn<<<gCk, 256, 0, stream>>>(cxv, Wv, cv, 128, 1024, 1024, 1.f, 2, cpev);

  // imp = inv * x @ (Wq @ ck^T)  — fp32-exact top-k path, 8x fewer fp32 FLOPs than q@ck^T
  sgemm_nt<<<dim3(2, 16), 256, 0, stream>>>(Wq, ck, M1, 1024, 128, 1024, 1.f);
  imp_gemm<<<dim3(1, 32), 256, 0, stream>>>(x, M1, imp);

  topk_kernel<<<8, 256, 0, stream>>>(imp, tk);
  gates_kernel<<<2048, 256, 0, stream>>>(x, Wg, bg, gat);

  dim3 gAttn(16, 16, 2);
  comp_attn2<<<gAttn, 256, 0, stream>>>(q, ck, cv, gat, accb);        // acc = g0*out_comp
  sel_attn<<<8192, 256, 0, stream>>>(q, kbuf, vbuf, tk, gat, accb);   // acc += g1*out_sel
  win_attn2<<<gAttn, 256, 0, stream>>>(q, kbuf, vbuf, gat, accb);     // acc += g2*out_win

  // out = acc@Wo + bo (bf16 MFMA)
  transpose_to_bf16<<<gT, 256, 0, stream>>>(Wo, Wt, 1024, 1024);
  gemm_bf16<<<gBig, 256, 0, stream>>>(accb, Wt, out, 2048, 1024, 1024, 2, bo);
}

// Round 3
// 526.633 us; speedup vs baseline: 2.1918x; 1.3431x over previous
//
#include <hip/hip_runtime.h>

// NativeSparseAttention round 3: MFMA flash attention for win+comp (fused),
// XOR-swizzled LDS tiles (conflict-free), bf16 MFMA big GEMMs, fp32 imp path.
// B=2 S=1024 D=1024 H=KV=16 HD=64 Nc=64 CB=16 SB=8 J=2 W=256

typedef __bf16 bf16;
typedef bf16 bf16x8 __attribute__((ext_vector_type(8)));
typedef float f32x4 __attribute__((ext_vector_type(4)));

constexpr int kD = 1024;
constexpr float kInv = 0.125f;  // 1/sqrt(64)

// Swizzled LDS tile: [row][64] bf16, 16B block at colblock cb stored at cb^(row&7).
// Row stride 128B == 32 banks, so bank depends only on phys block -> every
// 64-lane b128 access with distinct (row, cb) pairs distributes 8 lanes/block: optimal.
#define SWZ_IDX(row, cb) (((row) << 6) + (((cb) ^ ((row) & 7)) << 3))
#define LDV(arr, row, cb) (*(const bf16x8*)&(arr)[SWZ_IDX(row, cb)])

// stage 64x64 fp32 tile (row-major) -> swizzled bf16 LDS; coalesced global reads
__device__ inline void stage_rows_bf16(const float* __restrict__ src, size_t pitch,
                                       bf16* __restrict__ dst, int tid) {
  int r = tid >> 2, qq = tid & 3;
  const float4* sp = (const float4*)(src + (size_t)r * pitch) + qq * 4;
  float4 f0 = sp[0], f1 = sp[1], f2 = sp[2], f3 = sp[3];
  bf16x8 lo, hi;
  lo[0] = (bf16)f0.x; lo[1] = (bf16)f0.y; lo[2] = (bf16)f0.z; lo[3] = (bf16)f0.w;
  lo[4] = (bf16)f1.x; lo[5] = (bf16)f1.y; lo[6] = (bf16)f1.z; lo[7] = (bf16)f1.w;
  hi[0] = (bf16)f2.x; hi[1] = (bf16)f2.y; hi[2] = (bf16)f2.z; hi[3] = (bf16)f2.w;
  hi[4] = (bf16)f3.x; hi[5] = (bf16)f3.y; hi[6] = (bf16)f3.z; hi[7] = (bf16)f3.w;
  int cb = qq * 2;
  *(bf16x8*)&dst[SWZ_IDX(r, cb)]     = lo;
  *(bf16x8*)&dst[SWZ_IDX(r, cb + 1)] = hi;
}

// stage 64x64 fp32 tile TRANSPOSED -> swizzled bf16 LDS (dst[d][key] from src[key][d]).
// lane = key (u16 writes land 2-per-dword per phys block: conflict-free);
// wave w covers d in [w*16, w*16+16).
__device__ inline void stage_cols_bf16(const float* __restrict__ src, size_t pitch,
                                       bf16* __restrict__ dst, int tid) {
  int lane = tid & 63, w = tid >> 6;
  const float4* sp = (const float4*)(src + (size_t)lane * pitch + w * 16);
  float4 f[4];
  f[0] = sp[0]; f[1] = sp[1]; f[2] = sp[2]; f[3] = sp[3];
  const float* ff = (const float*)f;
#pragma unroll
  for (int i = 0; i < 16; ++i) {
    int d = w * 16 + i;
    dst[(d << 6) + ((((lane >> 3) ^ (d & 7))) << 3) + (lane & 7)] = (bf16)ff[i];
  }
}

// ---- fused comp + window MFMA flash attention ----
// block = (64-query tile, h, b); 4 waves, wave w owns queries [s0+16w, s0+16w+16)
// acc[b,s,h*64+d] = g0*out_comp + g2*out_win   (sel_attn does += later)
__global__ __launch_bounds__(256) void attn_mfma(const float* __restrict__ q, const float* __restrict__ kg,
                                                 const float* __restrict__ vg, const float* __restrict__ ck,
                                                 const float* __restrict__ cv, const float* __restrict__ gat,
                                                 float* __restrict__ acc) {
  __shared__ bf16 Qs[64 * 64];
  __shared__ bf16 Ks[64 * 64];
  __shared__ bf16 Vt[64 * 64];
  __shared__ bf16 Ps[4 * 16 * 64];
  int tid = threadIdx.x, w = tid >> 6, lane = tid & 63;
  int qd = lane >> 4, l16 = lane & 15;
  int s0 = blockIdx.x * 64, h = blockIdx.y, b = blockIdx.z;
  bf16* Pw = Ps + w * 16 * 64;

  stage_rows_bf16(q + ((size_t)(b * 1024 + s0)) * kD + h * 64, kD, Qs, tid);
  stage_rows_bf16(ck + ((size_t)(b * 64)) * kD + h * 64, kD, Ks, tid);
  stage_cols_bf16(cv + ((size_t)(b * 64)) * kD + h * 64, kD, Vt, tid);
  __syncthreads();

  // ---- compressed attention (single 64-key chunk, no mask) ----
  f32x4 oc[4] = {};
  float lc[4];
  {
    f32x4 sacc[4] = {};
#pragma unroll
    for (int ks = 0; ks < 2; ++ks) {
      bf16x8 aq = LDV(Qs, w * 16 + l16, qd + 4 * ks);
#pragma unroll
      for (int j = 0; j < 4; ++j)
        sacc[j] = __builtin_amdgcn_mfma_f32_16x16x32_bf16(aq, LDV(Ks, 16 * j + l16, qd + 4 * ks), sacc[j], 0, 0, 0);
    }
#pragma unroll
    for (int j = 0; j < 4; ++j)
#pragma unroll
      for (int r = 0; r < 4; ++r) sacc[j][r] *= kInv;
#pragma unroll
    for (int r = 0; r < 4; ++r) {
      float mx = sacc[0][r];
#pragma unroll
      for (int j = 1; j < 4; ++j) mx = fmaxf(mx, sacc[j][r]);
#pragma unroll
      for (int off = 8; off; off >>= 1) mx = fmaxf(mx, __shfl_xor(mx, off));
      int qrow = qd * 4 + r;
      float rs = 0.f;
#pragma unroll
      for (int j = 0; j < 4; ++j) {
        float e = __expf(sacc[j][r] - mx);
        int col = l16 + 16 * j;
        Pw[(qrow << 6) + ((((col >> 3) ^ (qrow & 7))) << 3) + (col & 7)] = (bf16)e;
        rs += e;
      }
#pragma unroll
      for (int off = 8; off; off >>= 1) rs += __shfl_xor(rs, off);
      lc[r] = rs;
    }
    __syncthreads();
#pragma unroll
    for (int ks = 0; ks < 2; ++ks) {
      bf16x8 ap = LDV(Pw, l16, qd + 4 * ks);
#pragma unroll
      for (int j = 0; j < 4; ++j)
        oc[j] = __builtin_amdgcn_mfma_f32_16x16x32_bf16(ap, LDV(Vt, 16 * j + l16, qd + 4 * ks), oc[j], 0, 0, 0);
    }
  }

  // ---- sliding-window attention (online softmax over 64-key chunks) ----
  f32x4 ow[4] = {};
  float mw[4], lw[4];
#pragma unroll
  for (int r = 0; r < 4; ++r) { mw[r] = -1e30f; lw[r] = 0.f; }
  int kb0 = s0 - 256; if (kb0 < 0) kb0 = 0;
  int nck = (s0 + 64 - kb0) >> 6;  // 1..5 chunks; every chunk-row has >=1 valid key
  for (int c = 0; c < nck; ++c) {
    int kbase = kb0 + c * 64;
    __syncthreads();  // prior Ks/Vt readers done before overwrite
    stage_rows_bf16(kg + ((size_t)(b * 1024 + kbase)) * kD + h * 64, kD, Ks, tid);
    stage_cols_bf16(vg + ((size_t)(b * 1024 + kbase)) * kD + h * 64, kD, Vt, tid);
    __syncthreads();
    f32x4 sacc[4] = {};
#pragma unroll
    for (int ks = 0; ks < 2; ++ks) {
      bf16x8 aq = LDV(Qs, w * 16 + l16, qd + 4 * ks);
#pragma unroll
      for (int j = 0; j < 4; ++j)
        sacc[j] = __builtin_amdgcn_mfma_f32_16x16x32_bf16(aq, LDV(Ks, 16 * j + l16, qd + 4 * ks), sacc[j], 0, 0, 0);
    }
#pragma unroll
    for (int j = 0; j < 4; ++j)
#pragma unroll
      for (int r = 0; r < 4; ++r) {
        int key = kbase + 16 * j + l16;
        int sq = s0 + w * 16 + qd * 4 + r;
        float sc = sacc[j][r] * kInv;
        sacc[j][r] = (key <= sq && sq - key <= 256) ? sc : -1e30f;
      }
#pragma unroll
    for (int r = 0; r < 4; ++r) {
      float mx = sacc[0][r];
#pragma unroll
      for (int j = 1; j < 4; ++j) mx = fmaxf(mx, sacc[j][r]);
#pragma unroll
      for (int off = 8; off; off >>= 1) mx = fmaxf(mx, __shfl_xor(mx, off));
      float mn = fmaxf(mw[r], mx);
      float alpha = __expf(mw[r] - mn);  // exactly 0 on first chunk
      mw[r] = mn;
      int qrow = qd * 4 + r;
      float rs = 0.f;
#pragma unroll
      for (int j = 0; j < 4; ++j) {
        float e = __expf(sacc[j][r] - mn);  // masked -> expf(-1e30) == 0
        int col = l16 + 16 * j;
        Pw[(qrow << 6) + ((((col >> 3) ^ (qrow & 7))) << 3) + (col & 7)] = (bf16)e;
        rs += e;
      }
#pragma unroll
      for (int off = 8; off; off >>= 1) rs += __shfl_xor(rs, off);
      lw[r] = lw[r] * alpha + rs;
#pragma unroll
      for (int j = 0; j < 4; ++j) ow[j][r] *= alpha;
    }
    __syncthreads();
#pragma unroll
    for (int ks = 0; ks < 2; ++ks) {
      bf16x8 ap = LDV(Pw, l16, qd + 4 * ks);
#pragma unroll
      for (int j = 0; j < 4; ++j)
        ow[j] = __builtin_amdgcn_mfma_f32_16x16x32_bf16(ap, LDV(Vt, 16 * j + l16, qd + 4 * ks), ow[j], 0, 0, 0);
    }
  }

  // ---- epilogue: acc = g0*oc/lc + g2*ow/lw ----
#pragma unroll
  for (int r = 0; r < 4; ++r) {
    int sq = s0 + w * 16 + qd * 4 + r;
    size_t row = (size_t)b * 1024 + sq;
    float g0 = gat[row * 3 + 0], g2 = gat[row * 3 + 2];
    float c0 = g0 / lc[r], c2 = g2 / lw[r];
#pragma unroll
    for (int j = 0; j < 4; ++j)
      acc[row * kD + h * 64 + 16 * j + l16] = oc[j][r] * c0 + ow[j][r] * c2;
  }
}

// ---- cpe[d] = sum_t w[t]*wpe[t][d] ----
__global__ __launch_bounds__(256) void cpe_kernel(const float* __restrict__ wkc, const float* __restrict__ wvc,
                                                  const float* __restrict__ wpe,
                                                  float* __restrict__ cpek, float* __restrict__ cpev) {
  int d = blockIdx.x * 256 + threadIdx.x;
  float a = 0.f, b = 0.f;
  for (int t = 0; t < 16; ++t) {
    float p = wpe[t * kD + d];
    a += wkc[t] * p;
    b += wvc[t] * p;
  }
  cpek[d] = a;
  cpev[d] = b;
}

// ---- cxk[bn][d] = sum_t wkc[t]*x[b, 16n+t, d] ----
__global__ __launch_bounds__(256) void cx_kernel(const float* __restrict__ x, const float* __restrict__ wkc,
                                                 const float* __restrict__ wvc,
                                                 float* __restrict__ cxk, float* __restrict__ cxv) {
  int idx = blockIdx.x * 256 + threadIdx.x;  // [0, 128*1024)
  int d = idx & 1023;
  int bn = idx >> 10;
  const float* xp = x + (size_t)bn * 16 * kD + d;
  float a = 0.f, c = 0.f;
  for (int t = 0; t < 16; ++t) {
    float xv = xp[(size_t)t * kD];
    a += wkc[t] * xv;
    c += wvc[t] * xv;
  }
  cxk[idx] = a;
  cxv[idx] = c;
}

// ---- transpose fp32 [R][C] -> bf16 [C][R] ----
__global__ __launch_bounds__(256) void transpose_to_bf16(const float* __restrict__ in, bf16* __restrict__ out,
                                                         int R, int C) {
  __shared__ float t[32][33];
  int c0 = blockIdx.x * 32, r0 = blockIdx.y * 32;
  int tx = threadIdx.x & 31, ty = threadIdx.x >> 5;
#pragma unroll
  for (int i = 0; i < 32; i += 8) t[ty + i][tx] = in[(size_t)(r0 + ty + i) * C + c0 + tx];
  __syncthreads();
#pragma unroll
  for (int i = 0; i < 32; i += 8) out[(size_t)(c0 + ty + i) * R + r0 + tx] = (bf16)t[tx][ty + i];
}

// ---- bf16 MFMA GEMM: C[M][N] = A[M][K] @ Bt[N][K]^T (+ epilogue) ----
__global__ __launch_bounds__(256) void gemm_bf16(const float* __restrict__ A, const bf16* __restrict__ Bt,
                                                 float* __restrict__ C, int M, int N, int K,
                                                 int mode, const float* __restrict__ epi) {
  __shared__ __align__(16) bf16 As[64][32];
  __shared__ __align__(16) bf16 Bs[64][32];
  int tid = threadIdx.x;
  int wid = tid >> 6, lane = tid & 63;
  int row0 = blockIdx.y * 64, col0 = blockIdx.x * 64;
  int mh = (wid & 1) * 32, nh = (wid >> 1) * 32;
  int lrow = tid >> 2, lcol = (tid & 3) * 8;
  int qd = lane >> 4, l16 = lane & 15;
  f32x4 acc[2][2] = {};
  for (int k0 = 0; k0 < K; k0 += 32) {
    const float4* ap = (const float4*)&A[(size_t)(row0 + lrow) * K + k0 + lcol];
    float4 a0 = ap[0], a1 = ap[1];
    bf16x8 av;
    av[0] = (bf16)a0.x; av[1] = (bf16)a0.y; av[2] = (bf16)a0.z; av[3] = (bf16)a0.w;
    av[4] = (bf16)a1.x; av[5] = (bf16)a1.y; av[6] = (bf16)a1.z; av[7] = (bf16)a1.w;
    bf16x8 bv = *(const bf16x8*)&Bt[(size_t)(col0 + lrow) * K + k0 + lcol];
    *(bf16x8*)&As[lrow][lcol] = av;
    *(bf16x8*)&Bs[lrow][lcol] = bv;
    __syncthreads();
    bf16x8 af[2], bfr[2];
#pragma unroll
    for (int i = 0; i < 2; ++i) af[i] = *(const bf16x8*)&As[mh + i * 16 + l16][qd * 8];
#pragma unroll
    for (int j = 0; j < 2; ++j) bfr[j] = *(const bf16x8*)&Bs[nh + j * 16 + l16][qd * 8];
#pragma unroll
    for (int i = 0; i < 2; ++i)
#pragma unroll
      for (int j = 0; j < 2; ++j)
        acc[i][j] = __builtin_amdgcn_mfma_f32_16x16x32_bf16(af[i], bfr[j], acc[i][j], 0, 0, 0);
    __syncthreads();
  }
#pragma unroll
  for (int i = 0; i < 2; ++i)
#pragma unroll
    for (int j = 0; j < 2; ++j)
#pragma unroll
      for (int r = 0; r < 4; ++r) {
        int rr = row0 + mh + i * 16 + qd * 4 + r;
        int cc = col0 + nh + j * 16 + l16;
        float v = acc[i][j][r];
        if (mode == 1) v += epi[(rr & 15) * kD + cc];
        else if (mode == 2) v += epi[cc];
        C[(size_t)rr * N + cc] = v;
      }
}

// ---- fp32 tiled NN GEMM (ck/cv path; fp32 because it feeds top-k) ----
__global__ __launch_bounds__(256) void sgemm_nn(const float* __restrict__ A, const float* __restrict__ Bm,
                                                float* __restrict__ C, int M, int N, int K,
                                                float alpha, int mode, const float* __restrict__ epi) {
  __shared__ float As[16][64];
  __shared__ float Bs[16][68];
  int tid = threadIdx.x;
  int tm = tid >> 4, tn = tid & 15;
  int row0 = blockIdx.y * 64, col0 = blockIdx.x * 64;
  float acc[4][4] = {{0.f}};
  for (int k0 = 0; k0 < K; k0 += 16) {
#pragma unroll
    for (int i = 0; i < 4; ++i) {
      int idx = tid + i * 256;
      As[idx & 15][idx >> 4] = A[(size_t)(row0 + (idx >> 4)) * K + k0 + (idx & 15)];
      Bs[idx >> 6][idx & 63] = Bm[(size_t)(k0 + (idx >> 6)) * N + col0 + (idx & 63)];
    }
    __syncthreads();
#pragma unroll
    for (int kk = 0; kk < 16; ++kk) {
      float a[4], b[4];
#pragma unroll
      for (int i = 0; i < 4; ++i) a[i] = As[kk][tm * 4 + i];
#pragma unroll
      for (int j = 0; j < 4; ++j) b[j] = Bs[kk][tn * 4 + j];
#pragma unroll
      for (int i = 0; i < 4; ++i)
#pragma unroll
        for (int j = 0; j < 4; ++j) acc[i][j] += a[i] * b[j];
    }
    __syncthreads();
  }
#pragma unroll
  for (int i = 0; i < 4; ++i) {
    int r = row0 + tm * 4 + i;
#pragma unroll
    for (int j = 0; j < 4; ++j) {
      int c = col0 + tn * 4 + j;
      float v = alpha * acc[i][j];
      if (mode == 2) v += epi[c];
      C[(size_t)r * N + c] = v;
    }
  }
}

// ---- fp32 NT GEMM: M1[d][bn] (imp path) ----
__global__ __launch_bounds__(256) void sgemm_nt(const float* __restrict__ A, const float* __restrict__ Bt,
                                                float* __restrict__ C, int M, int N, int K, float alpha) {
  __shared__ float As[16][64];
  __shared__ float Bs[16][68];
  int tid = threadIdx.x;
  int tm = tid >> 4, tn = tid & 15;
  int row0 = blockIdx.y * 64, col0 = blockIdx.x * 64;
  float acc[4][4] = {{0.f}};
  for (int k0 = 0; k0 < K; k0 += 16) {
#pragma unroll
    for (int i = 0; i < 4; ++i) {
      int idx = tid + i * 256;
      As[idx & 15][idx >> 4] = A[(size_t)(row0 + (idx >> 4)) * K + k0 + (idx & 15)];
      Bs[idx & 15][idx >> 4] = Bt[(size_t)(col0 + (idx >> 4)) * K + k0 + (idx & 15)];
    }
    __syncthreads();
#pragma unroll
    for (int kk = 0; kk < 16; ++kk) {
      float a[4], b[4];
#pragma unroll
      for (int i = 0; i < 4; ++i) a[i] = As[kk][tm * 4 + i];
#pragma unroll
      for (int j = 0; j < 4; ++j) b[j] = Bs[kk][tn * 4 + j];
#pragma unroll
      for (int i = 0; i < 4; ++i)
#pragma unroll
        for (int j = 0; j < 4; ++j) acc[i][j] += a[i] * b[j];
    }
    __syncthreads();
  }
#pragma unroll
  for (int i = 0; i < 4; ++i) {
    int r = row0 + tm * 4 + i;
#pragma unroll
    for (int j = 0; j < 4; ++j) {
      int c = col0 + tn * 4 + j;
      C[(size_t)r * N + c] = alpha * acc[i][j];
    }
  }
}

// ---- imp[bs][n] = inv * sum_d x[bs][d] * M1[d][(bs>>10)*64 + n] ----
__global__ __launch_bounds__(256) void imp_gemm(const float* __restrict__ A, const float* __restrict__ Bm,
                                                float* __restrict__ C) {
  __shared__ float As[16][64];
  __shared__ float Bs[16][68];
  int tid = threadIdx.x;
  int tm = tid >> 4, tn = tid & 15;
  int row0 = blockIdx.y * 64;
  int colbase = (row0 >> 10) * 64;
  float acc[4][4] = {{0.f}};
  for (int k0 = 0; k0 < 1024; k0 += 16) {
#pragma unroll
    for (int i = 0; i < 4; ++i) {
      int idx = tid + i * 256;
      As[idx & 15][idx >> 4] = A[(size_t)(row0 + (idx >> 4)) * 1024 + k0 + (idx & 15)];
      Bs[idx >> 6][idx & 63] = Bm[(size_t)(k0 + (idx >> 6)) * 128 + colbase + (idx & 63)];
    }
    __syncthreads();
#pragma unroll
    for (int kk = 0; kk < 16; ++kk) {
      float a[4], b[4];
#pragma unroll
      for (int i = 0; i < 4; ++i) a[i] = As[kk][tm * 4 + i];
#pragma unroll
      for (int j = 0; j < 4; ++j) b[j] = Bs[kk][tn * 4 + j];
#pragma unroll
      for (int i = 0; i < 4; ++i)
#pragma unroll
        for (int j = 0; j < 4; ++j) acc[i][j] += a[i] * b[j];
    }
    __syncthreads();
  }
#pragma unroll
  for (int i = 0; i < 4; ++i) {
    int r = row0 + tm * 4 + i;
#pragma unroll
    for (int j = 0; j < 4; ++j) C[(size_t)r * 64 + tn * 4 + j] = kInv * acc[i][j];
  }
}

// ---- top-2 over 64 blocks per (b,s) ----
__global__ __launch_bounds__(256) void topk_kernel(const float* __restrict__ imp, int* __restrict__ tk) {
  int bs = blockIdx.x * 256 + threadIdx.x;
  const float* p = imp + (size_t)bs * 64;
  float v1 = -3.0e38f, v2 = -3.0e38f;
  int i1 = 0, i2 = 0;
  for (int n = 0; n < 64; ++n) {
    float v = p[n];
    if (v > v1) { v2 = v1; i2 = i1; v1 = v; i1 = n; }
    else if (v > v2) { v2 = v; i2 = n; }
  }
  tk[bs * 2] = i1;
  tk[bs * 2 + 1] = i2;
}

// ---- gates = sigmoid(x@Wg + bg) ----
__global__ __launch_bounds__(256) void gates_kernel(const float* __restrict__ x, const float* __restrict__ Wg,
                                                    const float* __restrict__ bg, float* __restrict__ gates) {
  int bs = blockIdx.x;
  int tid = threadIdx.x;
  __shared__ float red[3][256];
  const float* xp = x + (size_t)bs * kD;
  float p0 = 0.f, p1 = 0.f, p2 = 0.f;
  for (int d = tid; d < kD; d += 256) {
    float xv = xp[d];
    p0 += xv * Wg[d * 3 + 0];
    p1 += xv * Wg[d * 3 + 1];
    p2 += xv * Wg[d * 3 + 2];
  }
  red[0][tid] = p0; red[1][tid] = p1; red[2][tid] = p2;
  __syncthreads();
  for (int off = 128; off > 0; off >>= 1) {
    if (tid < off) {
      red[0][tid] += red[0][tid + off];
      red[1][tid] += red[1][tid + off];
      red[2][tid] += red[2][tid + off];
    }
    __syncthreads();
  }
  if (tid < 3) gates[bs * 3 + tid] = 1.f / (1.f + __expf(-(red[tid][0] + bg[tid])));
}

// ---- selected attention ----
__global__ __launch_bounds__(256) void sel_attn(const float* __restrict__ q, const float* __restrict__ k,
                                                const float* __restrict__ v, const int* __restrict__ tk,
                                                const float* __restrict__ gates, float* __restrict__ acc) {
  int wid = threadIdx.x >> 6, lane = threadIdx.x & 63;
  int g = blockIdx.x * 4 + wid;
  int h = g & 15, bs = g >> 4, b = bs >> 10, s = bs & 1023;
  __shared__ float qs[4][64];
  __shared__ float ps[4][16];
  __shared__ int toks[4][16];
  qs[wid][lane] = q[(size_t)bs * kD + h * 64 + lane];
  if (lane < 16) {
    int j = lane >> 3, t = lane & 7;
    int blk = tk[((size_t)j * 1024 + s) * 2 + b];   // top_idx[j, s, b]
    toks[wid][lane] = j * 1024 + blk * 16 + t;
  }
  __syncthreads();
  if (lane < 16) {
    const float4* kp = reinterpret_cast<const float4*>(k + (size_t)toks[wid][lane] * kD + h * 64);
    float sc = 0.f;
#pragma unroll
    for (int d4 = 0; d4 < 16; ++d4) {
      float4 kv = kp[d4];
      sc += qs[wid][d4 * 4] * kv.x + qs[wid][d4 * 4 + 1] * kv.y + qs[wid][d4 * 4 + 2] * kv.z +
            qs[wid][d4 * 4 + 3] * kv.w;
    }
    sc *= kInv;
    float m = sc;
#pragma unroll
    for (int off = 8; off > 0; off >>= 1) m = fmaxf(m, __shfl_xor(m, off, 16));
    float e = __expf(sc - m);
    float ss = e;
#pragma unroll
    for (int off = 8; off > 0; off >>= 1) ss += __shfl_xor(ss, off, 16);
    ps[wid][lane] = e / ss;
  }
  __syncthreads();
  float o = 0.f;
#pragma unroll
  for (int mi = 0; mi < 16; ++mi) o += ps[wid][mi] * v[(size_t)toks[wid][mi] * kD + h * 64 + lane];
  float g1 = gates[bs * 3 + 1];
  acc[(size_t)bs * kD + h * 64 + lane] += g1 * o;
}

extern "C" void kernel_launch(void* const* d_in, const int* in_sizes, int n_in,
                              void* d_out, int out_size, void* d_ws, size_t ws_size,
                              hipStream_t stream) {
  const float* x   = (const float*)d_in[0];
  const float* Wq  = (const float*)d_in[1];
  const float* Wk  = (const float*)d_in[2];
  const float* Wv  = (const float*)d_in[3];
  const float* Wo  = (const float*)d_in[4];
  const float* bo  = (const float*)d_in[5];
  const float* Wg  = (const float*)d_in[6];
  const float* bg  = (const float*)d_in[7];
  const float* wkc = (const float*)d_in[8];
  const float* wvc = (const float*)d_in[9];
  const float* wpe = (const float*)d_in[10];
  float* out = (float*)d_out;

  float* ws   = (float*)d_ws;
  float* q    = ws;                   // 2097152
  float* kbuf = q + 2097152;
  float* vbuf = kbuf + 2097152;
  float* accb = vbuf + 2097152;
  float* ck   = accb + 2097152;       // 131072
  float* cv   = ck + 131072;
  float* cxk  = cv + 131072;          // reused as M1 [1024][128]
  float* cxv  = cxk + 131072;         // reused as imp [2048][64]
  float* cpek = cxv + 131072;
  float* cpev = cpek + 1024;
  float* gat  = cpev + 1024;          // 2048*3
  int*   tk   = (int*)(gat + 6144);   // 4096 ints
  bf16*  Wt   = (bf16*)(gat + 6144 + 4096);  // 1048576 bf16
  float* M1   = cxk;
  float* imp  = cxv;

  cpe_kernel<<<4, 256, 0, stream>>>(wkc, wvc, wpe, cpek, cpev);
  cx_kernel<<<512, 256, 0, stream>>>(x, wkc, wvc, cxk, cxv);

  dim3 gT(32, 32);
  dim3 gBig(16, 32);
  transpose_to_bf16<<<gT, 256, 0, stream>>>(Wq, Wt, 1024, 1024);
  gemm_bf16<<<gBig, 256, 0, stream>>>(x, Wt, q, 2048, 1024, 1024, 0, nullptr);
  transpose_to_bf16<<<gT, 256, 0, stream>>>(Wk, Wt, 1024, 1024);
  gemm_bf16<<<gBig, 256, 0, stream>>>(x, Wt, kbuf, 2048, 1024, 1024, 1, wpe);
  transpose_to_bf16<<<gT, 256, 0, stream>>>(Wv, Wt, 1024, 1024);
  gemm_bf16<<<gBig, 256, 0, stream>>>(x, Wt, vbuf, 2048, 1024, 1024, 1, wpe);

  dim3 gCk(16, 2);
  sgemm_nn<<<gCk, 256, 0, stream>>>(cxk, Wk, ck, 128, 1024, 1024, 1.f, 2, cpek);
  sgemm_nn<<<gCk, 256, 0, stream>>>(cxv, Wv, cv, 128, 1024, 1024, 1.f, 2, cpev);

  // imp = inv * x @ (Wq @ ck^T)  — fp32-exact top-k path
  sgemm_nt<<<dim3(2, 16), 256, 0, stream>>>(Wq, ck, M1, 1024, 128, 1024, 1.f);
  imp_gemm<<<dim3(1, 32), 256, 0, stream>>>(x, M1, imp);

  topk_kernel<<<8, 256, 0, stream>>>(imp, tk);
  gates_kernel<<<2048, 256, 0, stream>>>(x, Wg, bg, gat);

  // fused comp+window MFMA attention writes acc; sel_attn does +=
  attn_mfma<<<dim3(16, 16, 2), 256, 0, stream>>>(q, kbuf, vbuf, ck, cv, gat, accb);
  sel_attn<<<8192, 256, 0, stream>>>(q, kbuf, vbuf, tk, gat, accb);

  transpose_to_bf16<<<gT, 256, 0, stream>>>(Wo, Wt, 1024, 1024);
  gemm_bf16<<<gBig, 256, 0, stream>>>(accb, Wt, out, 2048, 1024, 1024, 2, bo);
}

// Round 4
// 325.664 us; speedup vs baseline: 3.5444x; 1.6171x over previous
//
#include <hip/hip_runtime.h>

// NativeSparseAttention round 4: split-K fp32 GEMMs for the imp/ck path
// (was 32-block latency-bound), 128x64-tile bf16 MFMA GEMMs with swizzled LDS.
// B=2 S=1024 D=1024 H=KV=16 HD=64 Nc=64 CB=16 SB=8 J=2 W=256

typedef __bf16 bf16;
typedef bf16 bf16x8 __attribute__((ext_vector_type(8)));
typedef float f32x4 __attribute__((ext_vector_type(4)));

constexpr int kD = 1024;
constexpr float kInv = 0.125f;  // 1/sqrt(64)

// Swizzled LDS tile: row stride 64 bf16 = 128 B = exactly 32 banks, so bank
// depends only on the 16B chunk index; chunk stored at (cb ^ (row&7)) makes
// every 64-lane b128 access hit all 8 chunk-slots evenly: conflict-free.
#define SWZ_IDX(row, cb) (((row) << 6) + (((cb) ^ ((row) & 7)) << 3))
#define LDV(arr, row, cb) (*(const bf16x8*)&(arr)[SWZ_IDX(row, cb)])

// ---- fp32 -> bf16 bulk convert (8 elems/thread) ----
__global__ __launch_bounds__(256) void cvt_bf16(const float* __restrict__ in, bf16* __restrict__ out) {
  int i = blockIdx.x * 256 + threadIdx.x;
  const float4* p = (const float4*)in + (size_t)i * 2;
  float4 a = p[0], b = p[1];
  bf16x8 v;
  v[0] = (bf16)a.x; v[1] = (bf16)a.y; v[2] = (bf16)a.z; v[3] = (bf16)a.w;
  v[4] = (bf16)b.x; v[5] = (bf16)b.y; v[6] = (bf16)b.z; v[7] = (bf16)b.w;
  *(bf16x8*)&out[(size_t)i * 8] = v;
}

// ---- cpe[d] = sum_t w[t]*wpe[t][d] ----
__global__ __launch_bounds__(256) void cpe_kernel(const float* __restrict__ wkc, const float* __restrict__ wvc,
                                                  const float* __restrict__ wpe,
                                                  float* __restrict__ cpek, float* __restrict__ cpev) {
  int d = blockIdx.x * 256 + threadIdx.x;
  float a = 0.f, b = 0.f;
  for (int t = 0; t < 16; ++t) {
    float p = wpe[t * kD + d];
    a += wkc[t] * p;
    b += wvc[t] * p;
  }
  cpek[d] = a;
  cpev[d] = b;
}

// ---- cxk[bn][d] = sum_t wkc[t]*x[b, 16n+t, d] ----
__global__ __launch_bounds__(256) void cx_kernel(const float* __restrict__ x, const float* __restrict__ wkc,
                                                 const float* __restrict__ wvc,
                                                 float* __restrict__ cxk, float* __restrict__ cxv) {
  int idx = blockIdx.x * 256 + threadIdx.x;  // [0, 128*1024)
  int d = idx & 1023;
  int bn = idx >> 10;
  const float* xp = x + (size_t)bn * 16 * kD + d;
  float a = 0.f, c = 0.f;
  for (int t = 0; t < 16; ++t) {
    float xv = xp[(size_t)t * kD];
    a += wkc[t] * xv;
    c += wvc[t] * xv;
  }
  cxk[idx] = a;
  cxv[idx] = c;
}

// ---- transpose fp32 [R][C] -> bf16 [C][R] ----
__global__ __launch_bounds__(256) void transpose_to_bf16(const float* __restrict__ in, bf16* __restrict__ out,
                                                         int R, int C) {
  __shared__ float t[32][33];
  int c0 = blockIdx.x * 32, r0 = blockIdx.y * 32;
  int tx = threadIdx.x & 31, ty = threadIdx.x >> 5;
#pragma unroll
  for (int i = 0; i < 32; i += 8) t[ty + i][tx] = in[(size_t)(r0 + ty + i) * C + c0 + tx];
  __syncthreads();
#pragma unroll
  for (int i = 0; i < 32; i += 8) out[(size_t)(c0 + ty + i) * R + r0 + tx] = (bf16)t[tx][ty + i];
}

// ---- bf16 MFMA GEMM v2: C[M][N] = A[M][K] @ Bt[N][K]^T, BM=128 BN=64 BK=64 ----
// A pre-converted bf16. 4 waves: wave w owns rows (w&1)*64.., cols (w>>1)*32..
// mode 0: none; 1: += wpe[row%16][col]; 2: += epi[col]
__global__ __launch_bounds__(256) void gemm_bf16_v2(const bf16* __restrict__ A, const bf16* __restrict__ Bt,
                                                    float* __restrict__ C, int M, int N, int K,
                                                    int mode, const float* __restrict__ epi) {
  __shared__ bf16 As[128 * 64];
  __shared__ bf16 Bs[64 * 64];
  int tid = threadIdx.x, w = tid >> 6, lane = tid & 63;
  int qd = lane >> 4, l16 = lane & 15;
  int row0 = blockIdx.y * 128, col0 = blockIdx.x * 64;
  int mr = (w & 1) * 64, nc = (w >> 1) * 32;
  int srow = tid >> 3, schunk = tid & 7;  // staging: 32 rows / round, 16B per thread
  f32x4 acc[4][2] = {};
  for (int k0 = 0; k0 < K; k0 += 64) {
    __syncthreads();
#pragma unroll
    for (int rr = 0; rr < 4; ++rr) {
      int r = rr * 32 + srow;
      *(bf16x8*)&As[SWZ_IDX(r, schunk)] = *(const bf16x8*)&A[(size_t)(row0 + r) * K + k0 + schunk * 8];
    }
#pragma unroll
    for (int rr = 0; rr < 2; ++rr) {
      int r = rr * 32 + srow;
      *(bf16x8*)&Bs[SWZ_IDX(r, schunk)] = *(const bf16x8*)&Bt[(size_t)(col0 + r) * K + k0 + schunk * 8];
    }
    __syncthreads();
#pragma unroll
    for (int ks = 0; ks < 2; ++ks) {
      bf16x8 af[4], bfr[2];
#pragma unroll
      for (int i = 0; i < 4; ++i) af[i] = LDV(As, mr + i * 16 + l16, ks * 4 + qd);
#pragma unroll
      for (int j = 0; j < 2; ++j) bfr[j] = LDV(Bs, nc + j * 16 + l16, ks * 4 + qd);
#pragma unroll
      for (int i = 0; i < 4; ++i)
#pragma unroll
        for (int j = 0; j < 2; ++j)
          acc[i][j] = __builtin_amdgcn_mfma_f32_16x16x32_bf16(af[i], bfr[j], acc[i][j], 0, 0, 0);
    }
  }
#pragma unroll
  for (int i = 0; i < 4; ++i)
#pragma unroll
    for (int j = 0; j < 2; ++j)
#pragma unroll
      for (int r = 0; r < 4; ++r) {
        int rr = row0 + mr + i * 16 + qd * 4 + r;
        int cc = col0 + nc + j * 16 + l16;
        float v = acc[i][j][r];
        if (mode == 1) v += epi[(rr & 15) * kD + cc];
        else if (mode == 2) v += epi[cc];
        C[(size_t)rr * N + cc] = v;
      }
}

// ---- split-K fp32 NN GEMM: part[z][M][N], K-chunk KC per z ----
__global__ __launch_bounds__(256) void sgemm_nn_sk(const float* __restrict__ A, const float* __restrict__ Bm,
                                                   float* __restrict__ part, int M, int N, int K, int KC) {
  __shared__ float As2[64][17];  // [m][k] pad: staging & reads <=2-way
  __shared__ float Bs[16][68];
  int tid = threadIdx.x;
  int tm = tid >> 4, tn = tid & 15;
  int row0 = blockIdx.y * 64, col0 = blockIdx.x * 64;
  int k0b = blockIdx.z * KC;
  float acc[4][4] = {{0.f}};
  for (int k0 = k0b; k0 < k0b + KC; k0 += 16) {
#pragma unroll
    for (int i = 0; i < 4; ++i) {
      int idx = tid + i * 256;
      As2[idx >> 4][idx & 15] = A[(size_t)(row0 + (idx >> 4)) * K + k0 + (idx & 15)];
      Bs[idx >> 6][idx & 63] = Bm[(size_t)(k0 + (idx >> 6)) * N + col0 + (idx & 63)];
    }
    __syncthreads();
#pragma unroll
    for (int kk = 0; kk < 16; ++kk) {
      float a[4], b[4];
#pragma unroll
      for (int i = 0; i < 4; ++i) a[i] = As2[tm * 4 + i][kk];
#pragma unroll
      for (int j = 0; j < 4; ++j) b[j] = Bs[kk][tn * 4 + j];
#pragma unroll
      for (int i = 0; i < 4; ++i)
#pragma unroll
        for (int j = 0; j < 4; ++j) acc[i][j] += a[i] * b[j];
    }
    __syncthreads();
  }
  float* pp = part + (size_t)blockIdx.z * M * N;
#pragma unroll
  for (int i = 0; i < 4; ++i) {
    float4 v = make_float4(acc[i][0], acc[i][1], acc[i][2], acc[i][3]);
    *(float4*)&pp[(size_t)(row0 + tm * 4 + i) * N + col0 + tn * 4] = v;
  }
}

// ---- split-K fp32 NT GEMM: C[m][n] = sum_k A[m][k]*Bt[n][k] ----
__global__ __launch_bounds__(256) void sgemm_nt_sk(const float* __restrict__ A, const float* __restrict__ Bt,
                                                   float* __restrict__ part, int M, int N, int K, int KC) {
  __shared__ float As2[64][17];
  __shared__ float Bs2[64][17];
  int tid = threadIdx.x;
  int tm = tid >> 4, tn = tid & 15;
  int row0 = blockIdx.y * 64, col0 = blockIdx.x * 64;
  int k0b = blockIdx.z * KC;
  float acc[4][4] = {{0.f}};
  for (int k0 = k0b; k0 < k0b + KC; k0 += 16) {
#pragma unroll
    for (int i = 0; i < 4; ++i) {
      int idx = tid + i * 256;
      As2[idx >> 4][idx & 15] = A[(size_t)(row0 + (idx >> 4)) * K + k0 + (idx & 15)];
      Bs2[idx >> 4][idx & 15] = Bt[(size_t)(col0 + (idx >> 4)) * K + k0 + (idx & 15)];
    }
    __syncthreads();
#pragma unroll
    for (int kk = 0; kk < 16; ++kk) {
      float a[4], b[4];
#pragma unroll
      for (int i = 0; i < 4; ++i) a[i] = As2[tm * 4 + i][kk];
#pragma unroll
      for (int j = 0; j < 4; ++j) b[j] = Bs2[tn * 4 + j][kk];
#pragma unroll
      for (int i = 0; i < 4; ++i)
#pragma unroll
        for (int j = 0; j < 4; ++j) acc[i][j] += a[i] * b[j];
    }
    __syncthreads();
  }
  float* pp = part + (size_t)blockIdx.z * M * N;
#pragma unroll
  for (int i = 0; i < 4; ++i) {
    float4 v = make_float4(acc[i][0], acc[i][1], acc[i][2], acc[i][3]);
    *(float4*)&pp[(size_t)(row0 + tm * 4 + i) * N + col0 + tn * 4] = v;
  }
}

// ---- split-K imp: part[z][2048][64]; B = M1 [1024][128], cols (batch*64..) ----
__global__ __launch_bounds__(256) void imp_sk(const float* __restrict__ A, const float* __restrict__ M1,
                                              float* __restrict__ part, int KC) {
  __shared__ float As2[64][17];
  __shared__ float Bs[16][68];
  int tid = threadIdx.x;
  int tm = tid >> 4, tn = tid & 15;
  int row0 = blockIdx.y * 64;
  int colbase = (row0 >> 10) * 64;
  int k0b = blockIdx.z * KC;
  float acc[4][4] = {{0.f}};
  for (int k0 = k0b; k0 < k0b + KC; k0 += 16) {
#pragma unroll
    for (int i = 0; i < 4; ++i) {
      int idx = tid + i * 256;
      As2[idx >> 4][idx & 15] = A[(size_t)(row0 + (idx >> 4)) * 1024 + k0 + (idx & 15)];
    }
#pragma unroll
    for (int i = 0; i < 1; ++i) {
      int idx = tid;  // 256 threads cover 4 rows x 64 cols; loop 4x for 16 rows
#pragma unroll
      for (int rr = 0; rr < 4; ++rr) {
        int id2 = idx + rr * 256;
        Bs[id2 >> 6][id2 & 63] = M1[(size_t)(k0 + (id2 >> 6)) * 128 + colbase + (id2 & 63)];
      }
    }
    __syncthreads();
#pragma unroll
    for (int kk = 0; kk < 16; ++kk) {
      float a[4], b[4];
#pragma unroll
      for (int i = 0; i < 4; ++i) a[i] = As2[tm * 4 + i][kk];
#pragma unroll
      for (int j = 0; j < 4; ++j) b[j] = Bs[kk][tn * 4 + j];
#pragma unroll
      for (int i = 0; i < 4; ++i)
#pragma unroll
        for (int j = 0; j < 4; ++j) acc[i][j] += a[i] * b[j];
    }
    __syncthreads();
  }
  float* pp = part + (size_t)blockIdx.z * 2048 * 64;
#pragma unroll
  for (int i = 0; i < 4; ++i) {
    float4 v = make_float4(acc[i][0], acc[i][1], acc[i][2], acc[i][3]);
    *(float4*)&pp[(size_t)(row0 + tm * 4 + i) * 64 + tn * 4] = v;
  }
}

// ---- reduce split-K partials: C[i] = alpha*sum_z part[z][i] (+ epi[col]) ----
__global__ __launch_bounds__(256) void reduce_sk(const float* __restrict__ part, float* __restrict__ C,
                                                 int total, int SK, float alpha, int mode,
                                                 const float* __restrict__ epi, int colmask) {
  int i4 = (blockIdx.x * 256 + threadIdx.x) * 4;
  float4 s = *(const float4*)&part[i4];
  for (int z = 1; z < SK; ++z) {
    float4 p = *(const float4*)&part[(size_t)z * total + i4];
    s.x += p.x; s.y += p.y; s.z += p.z; s.w += p.w;
  }
  s.x *= alpha; s.y *= alpha; s.z *= alpha; s.w *= alpha;
  if (mode == 2) {
    int c = i4 & colmask;
    s.x += epi[c]; s.y += epi[c + 1]; s.z += epi[c + 2]; s.w += epi[c + 3];
  }
  *(float4*)&C[i4] = s;
}

// ---- top-2 over 64 blocks per (b,s) ----
__global__ __launch_bounds__(256) void topk_kernel(const float* __restrict__ imp, int* __restrict__ tk) {
  int bs = blockIdx.x * 256 + threadIdx.x;
  const float* p = imp + (size_t)bs * 64;
  float v1 = -3.0e38f, v2 = -3.0e38f;
  int i1 = 0, i2 = 0;
  for (int n = 0; n < 64; ++n) {
    float v = p[n];
    if (v > v1) { v2 = v1; i2 = i1; v1 = v; i1 = n; }
    else if (v > v2) { v2 = v; i2 = n; }
  }
  tk[bs * 2] = i1;
  tk[bs * 2 + 1] = i2;
}

// ---- gates = sigmoid(x@Wg + bg) ----
__global__ __launch_bounds__(256) void gates_kernel(const float* __restrict__ x, const float* __restrict__ Wg,
                                                    const float* __restrict__ bg, float* __restrict__ gates) {
  int bs = blockIdx.x;
  int tid = threadIdx.x;
  __shared__ float red[3][256];
  const float* xp = x + (size_t)bs * kD;
  float p0 = 0.f, p1 = 0.f, p2 = 0.f;
  for (int d = tid; d < kD; d += 256) {
    float xv = xp[d];
    p0 += xv * Wg[d * 3 + 0];
    p1 += xv * Wg[d * 3 + 1];
    p2 += xv * Wg[d * 3 + 2];
  }
  red[0][tid] = p0; red[1][tid] = p1; red[2][tid] = p2;
  __syncthreads();
  for (int off = 128; off > 0; off >>= 1) {
    if (tid < off) {
      red[0][tid] += red[0][tid + off];
      red[1][tid] += red[1][tid + off];
      red[2][tid] += red[2][tid + off];
    }
    __syncthreads();
  }
  if (tid < 3) gates[bs * 3 + tid] = 1.f / (1.f + __expf(-(red[tid][0] + bg[tid])));
}

// ---- staging helpers for attention (fp32 global -> swizzled bf16 LDS) ----
__device__ inline void stage_rows_bf16(const float* __restrict__ src, size_t pitch,
                                       bf16* __restrict__ dst, int tid) {
  int r = tid >> 2, qq = tid & 3;
  const float4* sp = (const float4*)(src + (size_t)r * pitch) + qq * 4;
  float4 f0 = sp[0], f1 = sp[1], f2 = sp[2], f3 = sp[3];
  bf16x8 lo, hi;
  lo[0] = (bf16)f0.x; lo[1] = (bf16)f0.y; lo[2] = (bf16)f0.z; lo[3] = (bf16)f0.w;
  lo[4] = (bf16)f1.x; lo[5] = (bf16)f1.y; lo[6] = (bf16)f1.z; lo[7] = (bf16)f1.w;
  hi[0] = (bf16)f2.x; hi[1] = (bf16)f2.y; hi[2] = (bf16)f2.z; hi[3] = (bf16)f2.w;
  hi[4] = (bf16)f3.x; hi[5] = (bf16)f3.y; hi[6] = (bf16)f3.z; hi[7] = (bf16)f3.w;
  int cb = qq * 2;
  *(bf16x8*)&dst[SWZ_IDX(r, cb)]     = lo;
  *(bf16x8*)&dst[SWZ_IDX(r, cb + 1)] = hi;
}

__device__ inline void stage_cols_bf16(const float* __restrict__ src, size_t pitch,
                                       bf16* __restrict__ dst, int tid) {
  int lane = tid & 63, w = tid >> 6;
  const float4* sp = (const float4*)(src + (size_t)lane * pitch + w * 16);
  float4 f[4];
  f[0] = sp[0]; f[1] = sp[1]; f[2] = sp[2]; f[3] = sp[3];
  const float* ff = (const float*)f;
#pragma unroll
  for (int i = 0; i < 16; ++i) {
    int d = w * 16 + i;
    dst[(d << 6) + ((((lane >> 3) ^ (d & 7))) << 3) + (lane & 7)] = (bf16)ff[i];
  }
}

// ---- fused comp + window MFMA flash attention ----
__global__ __launch_bounds__(256) void attn_mfma(const float* __restrict__ q, const float* __restrict__ kg,
                                                 const float* __restrict__ vg, const float* __restrict__ ck,
                                                 const float* __restrict__ cv, const float* __restrict__ gat,
                                                 float* __restrict__ acc) {
  __shared__ bf16 Qs[64 * 64];
  __shared__ bf16 Ks[64 * 64];
  __shared__ bf16 Vt[64 * 64];
  __shared__ bf16 Ps[4 * 16 * 64];
  int tid = threadIdx.x, w = tid >> 6, lane = tid & 63;
  int qd = lane >> 4, l16 = lane & 15;
  int s0 = blockIdx.x * 64, h = blockIdx.y, b = blockIdx.z;
  bf16* Pw = Ps + w * 16 * 64;

  stage_rows_bf16(q + ((size_t)(b * 1024 + s0)) * kD + h * 64, kD, Qs, tid);
  stage_rows_bf16(ck + ((size_t)(b * 64)) * kD + h * 64, kD, Ks, tid);
  stage_cols_bf16(cv + ((size_t)(b * 64)) * kD + h * 64, kD, Vt, tid);
  __syncthreads();

  f32x4 oc[4] = {};
  float lc[4];
  {
    f32x4 sacc[4] = {};
#pragma unroll
    for (int ks = 0; ks < 2; ++ks) {
      bf16x8 aq = LDV(Qs, w * 16 + l16, qd + 4 * ks);
#pragma unroll
      for (int j = 0; j < 4; ++j)
        sacc[j] = __builtin_amdgcn_mfma_f32_16x16x32_bf16(aq, LDV(Ks, 16 * j + l16, qd + 4 * ks), sacc[j], 0, 0, 0);
    }
#pragma unroll
    for (int j = 0; j < 4; ++j)
#pragma unroll
      for (int r = 0; r < 4; ++r) sacc[j][r] *= kInv;
#pragma unroll
    for (int r = 0; r < 4; ++r) {
      float mx = sacc[0][r];
#pragma unroll
      for (int j = 1; j < 4; ++j) mx = fmaxf(mx, sacc[j][r]);
#pragma unroll
      for (int off = 8; off; off >>= 1) mx = fmaxf(mx, __shfl_xor(mx, off));
      int qrow = qd * 4 + r;
      float rs = 0.f;
#pragma unroll
      for (int j = 0; j < 4; ++j) {
        float e = __expf(sacc[j][r] - mx);
        int col = l16 + 16 * j;
        Pw[(qrow << 6) + ((((col >> 3) ^ (qrow & 7))) << 3) + (col & 7)] = (bf16)e;
        rs += e;
      }
#pragma unroll
      for (int off = 8; off; off >>= 1) rs += __shfl_xor(rs, off);
      lc[r] = rs;
    }
    __syncthreads();
#pragma unroll
    for (int ks = 0; ks < 2; ++ks) {
      bf16x8 ap = LDV(Pw, l16, qd + 4 * ks);
#pragma unroll
      for (int j = 0; j < 4; ++j)
        oc[j] = __builtin_amdgcn_mfma_f32_16x16x32_bf16(ap, LDV(Vt, 16 * j + l16, qd + 4 * ks), oc[j], 0, 0, 0);
    }
  }

  f32x4 ow[4] = {};
  float mw[4], lw[4];
#pragma unroll
  for (int r = 0; r < 4; ++r) { mw[r] = -1e30f; lw[r] = 0.f; }
  int kb0 = s0 - 256; if (kb0 < 0) kb0 = 0;
  int nck = (s0 + 64 - kb0) >> 6;
  for (int c = 0; c < nck; ++c) {
    int kbase = kb0 + c * 64;
    __syncthreads();
    stage_rows_bf16(kg + ((size_t)(b * 1024 + kbase)) * kD + h * 64, kD, Ks, tid);
    stage_cols_bf16(vg + ((size_t)(b * 1024 + kbase)) * kD + h * 64, kD, Vt, tid);
    __syncthreads();
    f32x4 sacc[4] = {};
#pragma unroll
    for (int ks = 0; ks < 2; ++ks) {
      bf16x8 aq = LDV(Qs, w * 16 + l16, qd + 4 * ks);
#pragma unroll
      for (int j = 0; j < 4; ++j)
        sacc[j] = __builtin_amdgcn_mfma_f32_16x16x32_bf16(aq, LDV(Ks, 16 * j + l16, qd + 4 * ks), sacc[j], 0, 0, 0);
    }
#pragma unroll
    for (int j = 0; j < 4; ++j)
#pragma unroll
      for (int r = 0; r < 4; ++r) {
        int key = kbase + 16 * j + l16;
        int sq = s0 + w * 16 + qd * 4 + r;
        float sc = sacc[j][r] * kInv;
        sacc[j][r] = (key <= sq && sq - key <= 256) ? sc : -1e30f;
      }
#pragma unroll
    for (int r = 0; r < 4; ++r) {
      float mx = sacc[0][r];
#pragma unroll
      for (int j = 1; j < 4; ++j) mx = fmaxf(mx, sacc[j][r]);
#pragma unroll
      for (int off = 8; off; off >>= 1) mx = fmaxf(mx, __shfl_xor(mx, off));
      float mn = fmaxf(mw[r], mx);
      float alpha = __expf(mw[r] - mn);
      mw[r] = mn;
      int qrow = qd * 4 + r;
      float rs = 0.f;
#pragma unroll
      for (int j = 0; j < 4; ++j) {
        float e = __expf(sacc[j][r] - mn);
        int col = l16 + 16 * j;
        Pw[(qrow << 6) + ((((col >> 3) ^ (qrow & 7))) << 3) + (col & 7)] = (bf16)e;
        rs += e;
      }
#pragma unroll
      for (int off = 8; off; off >>= 1) rs += __shfl_xor(rs, off);
      lw[r] = lw[r] * alpha + rs;
#pragma unroll
      for (int j = 0; j < 4; ++j) ow[j][r] *= alpha;
    }
    __syncthreads();
#pragma unroll
    for (int ks = 0; ks < 2; ++ks) {
      bf16x8 ap = LDV(Pw, l16, qd + 4 * ks);
#pragma unroll
      for (int j = 0; j < 4; ++j)
        ow[j] = __builtin_amdgcn_mfma_f32_16x16x32_bf16(ap, LDV(Vt, 16 * j + l16, qd + 4 * ks), ow[j], 0, 0, 0);
    }
  }

#pragma unroll
  for (int r = 0; r < 4; ++r) {
    int sq = s0 + w * 16 + qd * 4 + r;
    size_t row = (size_t)b * 1024 + sq;
    float g0 = gat[row * 3 + 0], g2 = gat[row * 3 + 2];
    float c0 = g0 / lc[r], c2 = g2 / lw[r];
#pragma unroll
    for (int j = 0; j < 4; ++j)
      acc[row * kD + h * 64 + 16 * j + l16] = oc[j][r] * c0 + ow[j][r] * c2;
  }
}

// ---- selected attention ----
__global__ __launch_bounds__(256) void sel_attn(const float* __restrict__ q, const float* __restrict__ k,
                                                const float* __restrict__ v, const int* __restrict__ tk,
                                                const float* __restrict__ gates, float* __restrict__ acc) {
  int wid = threadIdx.x >> 6, lane = threadIdx.x & 63;
  int g = blockIdx.x * 4 + wid;
  int h = g & 15, bs = g >> 4, b = bs >> 10, s = bs & 1023;
  __shared__ float qs[4][64];
  __shared__ float ps[4][16];
  __shared__ int toks[4][16];
  qs[wid][lane] = q[(size_t)bs * kD + h * 64 + lane];
  if (lane < 16) {
    int j = lane >> 3, t = lane & 7;
    int blk = tk[((size_t)j * 1024 + s) * 2 + b];
    toks[wid][lane] = j * 1024 + blk * 16 + t;
  }
  __syncthreads();
  if (lane < 16) {
    const float4* kp = reinterpret_cast<const float4*>(k + (size_t)toks[wid][lane] * kD + h * 64);
    float sc = 0.f;
#pragma unroll
    for (int d4 = 0; d4 < 16; ++d4) {
      float4 kv = kp[d4];
      sc += qs[wid][d4 * 4] * kv.x + qs[wid][d4 * 4 + 1] * kv.y + qs[wid][d4 * 4 + 2] * kv.z +
            qs[wid][d4 * 4 + 3] * kv.w;
    }
    sc *= kInv;
    float m = sc;
#pragma unroll
    for (int off = 8; off > 0; off >>= 1) m = fmaxf(m, __shfl_xor(m, off, 16));
    float e = __expf(sc - m);
    float ss = e;
#pragma unroll
    for (int off = 8; off > 0; off >>= 1) ss += __shfl_xor(ss, off, 16);
    ps[wid][lane] = e / ss;
  }
  __syncthreads();
  float o = 0.f;
#pragma unroll
  for (int mi = 0; mi < 16; ++mi) o += ps[wid][mi] * v[(size_t)toks[wid][mi] * kD + h * 64 + lane];
  float g1 = gates[bs * 3 + 1];
  acc[(size_t)bs * kD + h * 64 + lane] += g1 * o;
}

extern "C" void kernel_launch(void* const* d_in, const int* in_sizes, int n_in,
                              void* d_out, int out_size, void* d_ws, size_t ws_size,
                              hipStream_t stream) {
  const float* x   = (const float*)d_in[0];
  const float* Wq  = (const float*)d_in[1];
  const float* Wk  = (const float*)d_in[2];
  const float* Wv  = (const float*)d_in[3];
  const float* Wo  = (const float*)d_in[4];
  const float* bo  = (const float*)d_in[5];
  const float* Wg  = (const float*)d_in[6];
  const float* bg  = (const float*)d_in[7];
  const float* wkc = (const float*)d_in[8];
  const float* wvc = (const float*)d_in[9];
  const float* wpe = (const float*)d_in[10];
  float* out = (float*)d_out;

  float* ws   = (float*)d_ws;
  float* q    = ws;                    // 2097152 f32
  float* kbuf = q + 2097152;
  float* vbuf = kbuf + 2097152;
  float* accb = vbuf + 2097152;
  float* ck   = accb + 2097152;        // 131072
  float* cv   = ck + 131072;
  float* cxk  = cv + 131072;           // reused as M1 [1024][128]
  float* cxv  = cxk + 131072;          // reused as imp [2048][64]
  float* cpek = cxv + 131072;
  float* cpev = cpek + 1024;
  float* gat  = cpev + 1024;           // 6144
  int*   tk   = (int*)(gat + 6144);    // 4096 ints
  bf16*  Wt   = (bf16*)(gat + 6144 + 4096);   // 1048576 bf16 = 524288 f32
  bf16*  xbf  = (bf16*)((float*)Wt + 524288); // 2097152 bf16 = 1048576 f32
  float* skbuf = (float*)xbf + 1048576;       // 1048576 f32 (8 x 131072)
  bf16*  accbf = (bf16*)skbuf;                // aliases skbuf (sequentially safe)
  float* M1   = cxk;
  float* imp  = cxv;

  cpe_kernel<<<4, 256, 0, stream>>>(wkc, wvc, wpe, cpek, cpev);
  cx_kernel<<<512, 256, 0, stream>>>(x, wkc, wvc, cxk, cxv);
  cvt_bf16<<<1024, 256, 0, stream>>>(x, xbf);

  dim3 gT(32, 32);
  dim3 gBig(16, 16);  // N/64, M/128 for 2048x1024
  transpose_to_bf16<<<gT, 256, 0, stream>>>(Wq, Wt, 1024, 1024);
  gemm_bf16_v2<<<gBig, 256, 0, stream>>>(xbf, Wt, q, 2048, 1024, 1024, 0, nullptr);
  transpose_to_bf16<<<gT, 256, 0, stream>>>(Wk, Wt, 1024, 1024);
  gemm_bf16_v2<<<gBig, 256, 0, stream>>>(xbf, Wt, kbuf, 2048, 1024, 1024, 1, wpe);
  transpose_to_bf16<<<gT, 256, 0, stream>>>(Wv, Wt, 1024, 1024);
  gemm_bf16_v2<<<gBig, 256, 0, stream>>>(xbf, Wt, vbuf, 2048, 1024, 1024, 1, wpe);

  // compressed K/V, fp32 split-K (feeds top-k path)
  sgemm_nn_sk<<<dim3(16, 2, 8), 256, 0, stream>>>(cxk, Wk, skbuf, 128, 1024, 1024, 128);
  reduce_sk<<<128, 256, 0, stream>>>(skbuf, ck, 131072, 8, 1.f, 2, cpek, 1023);
  sgemm_nn_sk<<<dim3(16, 2, 8), 256, 0, stream>>>(cxv, Wv, skbuf, 128, 1024, 1024, 128);
  reduce_sk<<<128, 256, 0, stream>>>(skbuf, cv, 131072, 8, 1.f, 2, cpev, 1023);

  // imp = inv * x @ (Wq @ ck^T), fp32-exact
  sgemm_nt_sk<<<dim3(2, 16, 8), 256, 0, stream>>>(Wq, ck, skbuf, 1024, 128, 1024, 128);
  reduce_sk<<<128, 256, 0, stream>>>(skbuf, M1, 131072, 8, 1.f, 0, nullptr, 0);
  imp_sk<<<dim3(1, 32, 8), 256, 0, stream>>>(x, M1, skbuf, 128);
  reduce_sk<<<128, 256, 0, stream>>>(skbuf, imp, 131072, 8, kInv, 0, nullptr, 0);

  topk_kernel<<<8, 256, 0, stream>>>(imp, tk);
  gates_kernel<<<2048, 256, 0, stream>>>(x, Wg, bg, gat);

  attn_mfma<<<dim3(16, 16, 2), 256, 0, stream>>>(q, kbuf, vbuf, ck, cv, gat, accb);
  sel_attn<<<8192, 256, 0, stream>>>(q, kbuf, vbuf, tk, gat, accb);

  // out = acc@Wo + bo
  cvt_bf16<<<1024, 256, 0, stream>>>(accb, accbf);
  transpose_to_bf16<<<gT, 256, 0, stream>>>(Wo, Wt, 1024, 1024);
  gemm_bf16_v2<<<gBig, 256, 0, stream>>>(accbf, Wt, out, 2048, 1024, 1024, 2, bo);
}

// Round 5
// 236.656 us; speedup vs baseline: 4.8775x; 1.3761x over previous
//
#include <hip/hip_runtime.h>

// NativeSparseAttention round 5: global_load_lds async staging (swizzle moved to
// the global-read side), bf16 q/k/v, dispatch count 24 -> 15, full-lane sel_attn.
// B=2 S=1024 D=1024 H=KV=16 HD=64 Nc=64 CB=16 SB=8 J=2 W=256

typedef __bf16 bf16;
typedef bf16 bf16x8 __attribute__((ext_vector_type(8)));
typedef float f32x4 __attribute__((ext_vector_type(4)));

constexpr int kD = 1024;
constexpr float kInv = 0.125f;  // 1/sqrt(64), exact power of 2

// Swizzled LDS tile: row stride 64 bf16 = 128 B = 32 banks; 16B chunk cb of row
// stored at slot cb^(row&7) -> every 64-lane b128 access conflict-free.
#define SWZ_IDX(row, cb) (((row) << 6) + (((cb) ^ ((row) & 7)) << 3))
#define LDV(arr, row, cb) (*(const bf16x8*)&(arr)[SWZ_IDX(row, cb)])

// Async 16B global->LDS. LDS dest = wave-uniform base + lane*16 (HW constraint);
// we read globally in swizzled order so LDS slot s of row r holds chunk s^(r&7).
__device__ __forceinline__ void async_ld16(const bf16* g, bf16* l) {
  __builtin_amdgcn_global_load_lds(
      (const __attribute__((address_space(1))) unsigned int*)g,
      (__attribute__((address_space(3))) unsigned int*)l, 16, 0, 0);
}

// ---- fp32 -> bf16 bulk convert (8 elems/thread) ----
__global__ __launch_bounds__(256) void cvt_bf16(const float* __restrict__ in, bf16* __restrict__ out) {
  int i = blockIdx.x * 256 + threadIdx.x;
  const float4* p = (const float4*)in + (size_t)i * 2;
  float4 a = p[0], b = p[1];
  bf16x8 v;
  v[0] = (bf16)a.x; v[1] = (bf16)a.y; v[2] = (bf16)a.z; v[3] = (bf16)a.w;
  v[4] = (bf16)b.x; v[5] = (bf16)b.y; v[6] = (bf16)b.z; v[7] = (bf16)b.w;
  *(bf16x8*)&out[(size_t)i * 8] = v;
}

// ---- cxk[bn][d] = sum_t wkc[t]*x[b, 16n+t, d] ----
__global__ __launch_bounds__(256) void cx_kernel(const float* __restrict__ x, const float* __restrict__ wkc,
                                                 const float* __restrict__ wvc,
                                                 float* __restrict__ cxk, float* __restrict__ cxv) {
  int idx = blockIdx.x * 256 + threadIdx.x;
  int d = idx & 1023;
  int bn = idx >> 10;
  const float* xp = x + (size_t)bn * 16 * kD + d;
  float a = 0.f, c = 0.f;
  for (int t = 0; t < 16; ++t) {
    float xv = xp[(size_t)t * kD];
    a += wkc[t] * xv;
    c += wvc[t] * xv;
  }
  cxk[idx] = a;
  cxv[idx] = c;
}

// ---- transpose all 4 weights fp32 [1024][1024] -> bf16 [C][R], one dispatch ----
__global__ __launch_bounds__(256) void transpose4(const float* __restrict__ Wq, const float* __restrict__ Wk,
                                                  const float* __restrict__ Wv, const float* __restrict__ Wo,
                                                  bf16* __restrict__ Wt4) {
  __shared__ float t[32][33];
  const float* in = (blockIdx.z == 0) ? Wq : (blockIdx.z == 1) ? Wk : (blockIdx.z == 2) ? Wv : Wo;
  bf16* out = Wt4 + (size_t)blockIdx.z * 1048576;
  int c0 = blockIdx.x * 32, r0 = blockIdx.y * 32;
  int tx = threadIdx.x & 31, ty = threadIdx.x >> 5;
#pragma unroll
  for (int i = 0; i < 32; i += 8) t[ty + i][tx] = in[(size_t)(r0 + ty + i) * 1024 + c0 + tx];
  __syncthreads();
#pragma unroll
  for (int i = 0; i < 32; i += 8) out[(size_t)(c0 + ty + i) * 1024 + r0 + tx] = (bf16)t[tx][ty + i];
}

// ---- bf16 MFMA GEMM core: BM=128 BN=64 BK=64, async LDS staging ----
__device__ __forceinline__ void gemm_core(const bf16* __restrict__ A, const bf16* __restrict__ Bt,
                                          int K, int row0, int col0, bf16* As, bf16* Bs,
                                          int tid, f32x4 (&acc)[4][2]) {
  int w = tid >> 6, lane = tid & 63;
  int l8 = lane >> 3, s8 = lane & 7;
  int qd = lane >> 4, l16 = lane & 15;
  int mr = (w & 1) * 64, nc = (w >> 1) * 32;
  for (int k0 = 0; k0 < K; k0 += 64) {
    __syncthreads();
#pragma unroll
    for (int i = 0; i < 4; ++i) {  // As 128x64: wave w rows [w*32, w*32+32)
      int row = w * 32 + i * 8 + l8;
      async_ld16(&A[(size_t)(row0 + row) * K + k0 + (s8 ^ l8) * 8], As + w * 2048 + i * 512);
    }
#pragma unroll
    for (int i = 0; i < 2; ++i) {  // Bs 64x64: wave w rows [w*16, w*16+16)
      int row = w * 16 + i * 8 + l8;
      async_ld16(&Bt[(size_t)(col0 + row) * K + k0 + (s8 ^ l8) * 8], Bs + w * 1024 + i * 512);
    }
    __syncthreads();
#pragma unroll
    for (int ks = 0; ks < 2; ++ks) {
      bf16x8 af[4], bfr[2];
#pragma unroll
      for (int i = 0; i < 4; ++i) af[i] = LDV(As, mr + i * 16 + l16, ks * 4 + qd);
#pragma unroll
      for (int j = 0; j < 2; ++j) bfr[j] = LDV(Bs, nc + j * 16 + l16, ks * 4 + qd);
#pragma unroll
      for (int i = 0; i < 4; ++i)
#pragma unroll
        for (int j = 0; j < 2; ++j)
          acc[i][j] = __builtin_amdgcn_mfma_f32_16x16x32_bf16(af[i], bfr[j], acc[i][j], 0, 0, 0);
    }
  }
}

// ---- q/k/v = x@W (+pe for k,v), bf16 out, one dispatch (z = 0,1,2) ----
__global__ __launch_bounds__(256) void gemm_qkv(const bf16* __restrict__ xbf, const bf16* __restrict__ Wt4,
                                                bf16* __restrict__ qkv, const float* __restrict__ wpe) {
  __shared__ bf16 As[128 * 64];
  __shared__ bf16 Bs[64 * 64];
  int tid = threadIdx.x, z = blockIdx.z;
  int row0 = blockIdx.y * 128, col0 = blockIdx.x * 64;
  f32x4 acc[4][2] = {};
  gemm_core(xbf, Wt4 + (size_t)z * 1048576, 1024, row0, col0, As, Bs, tid, acc);
  int w = tid >> 6, lane = tid & 63, qd = lane >> 4, l16 = lane & 15;
  int mr = (w & 1) * 64, nc = (w >> 1) * 32;
  bf16* C = qkv + (size_t)z * 2097152;
#pragma unroll
  for (int i = 0; i < 4; ++i)
#pragma unroll
    for (int j = 0; j < 2; ++j)
#pragma unroll
      for (int r = 0; r < 4; ++r) {
        int rr = row0 + mr + i * 16 + qd * 4 + r;
        int cc = col0 + nc + j * 16 + l16;
        float v = acc[i][j][r];
        if (z) v += wpe[(rr & 15) * kD + cc];
        C[(size_t)rr * kD + cc] = (bf16)v;
      }
}

// ---- out = accbf@Wo + bo, fp32 out ----
__global__ __launch_bounds__(256) void gemm_out(const bf16* __restrict__ accbf, const bf16* __restrict__ Wot,
                                                float* __restrict__ out, const float* __restrict__ bo) {
  __shared__ bf16 As[128 * 64];
  __shared__ bf16 Bs[64 * 64];
  int tid = threadIdx.x;
  int row0 = blockIdx.y * 128, col0 = blockIdx.x * 64;
  f32x4 acc[4][2] = {};
  gemm_core(accbf, Wot, 1024, row0, col0, As, Bs, tid, acc);
  int w = tid >> 6, lane = tid & 63, qd = lane >> 4, l16 = lane & 15;
  int mr = (w & 1) * 64, nc = (w >> 1) * 32;
#pragma unroll
  for (int i = 0; i < 4; ++i)
#pragma unroll
    for (int j = 0; j < 2; ++j)
#pragma unroll
      for (int r = 0; r < 4; ++r) {
        int rr = row0 + mr + i * 16 + qd * 4 + r;
        int cc = col0 + nc + j * 16 + l16;
        out[(size_t)rr * kD + cc] = acc[i][j][r] + bo[cc];
      }
}

// ---- split-K fp32 NN GEMM for ck|cv merged: z<8 -> cxk, z>=8 -> cxv ----
__global__ __launch_bounds__(256) void sgemm_nn_sk2(const float* __restrict__ Ak, const float* __restrict__ Av,
                                                    const float* __restrict__ Wk, const float* __restrict__ Wv,
                                                    float* __restrict__ part) {
  __shared__ float As2[64][17];
  __shared__ float Bs[16][68];
  const float* A = (blockIdx.z < 8) ? Ak : Av;
  const float* Bm = (blockIdx.z < 8) ? Wk : Wv;
  int tid = threadIdx.x;
  int tm = tid >> 4, tn = tid & 15;
  int row0 = blockIdx.y * 64, col0 = blockIdx.x * 64;
  int k0b = (blockIdx.z & 7) * 128;
  float acc[4][4] = {{0.f}};
  for (int k0 = k0b; k0 < k0b + 128; k0 += 16) {
#pragma unroll
    for (int i = 0; i < 4; ++i) {
      int idx = tid + i * 256;
      As2[idx >> 4][idx & 15] = A[(size_t)(row0 + (idx >> 4)) * 1024 + k0 + (idx & 15)];
      Bs[idx >> 6][idx & 63] = Bm[(size_t)(k0 + (idx >> 6)) * 1024 + col0 + (idx & 63)];
    }
    __syncthreads();
#pragma unroll
    for (int kk = 0; kk < 16; ++kk) {
      float a[4], b[4];
#pragma unroll
      for (int i = 0; i < 4; ++i) a[i] = As2[tm * 4 + i][kk];
#pragma unroll
      for (int j = 0; j < 4; ++j) b[j] = Bs[kk][tn * 4 + j];
#pragma unroll
      for (int i = 0; i < 4; ++i)
#pragma unroll
        for (int j = 0; j < 4; ++j) acc[i][j] += a[i] * b[j];
    }
    __syncthreads();
  }
  float* pp = part + (size_t)blockIdx.z * 131072;
#pragma unroll
  for (int i = 0; i < 4; ++i) {
    float4 v = make_float4(acc[i][0], acc[i][1], acc[i][2], acc[i][3]);
    *(float4*)&pp[(size_t)(row0 + tm * 4 + i) * 1024 + col0 + tn * 4] = v;
  }
}

// ---- reduce ck|cv partials with inline cpe: blocks 0..127 ck, 128..255 cv ----
__global__ __launch_bounds__(256) void reduce_ckcv(const float* __restrict__ part, float* __restrict__ ck,
                                                   float* __restrict__ cv, const float* __restrict__ wkc,
                                                   const float* __restrict__ wvc, const float* __restrict__ wpe) {
  int half = blockIdx.x >> 7;
  int i4 = (((blockIdx.x & 127) * 256) + threadIdx.x) * 4;
  const float* pp = part + (size_t)half * 8 * 131072;
  float4 s = *(const float4*)&pp[i4];
  for (int z = 1; z < 8; ++z) {
    float4 p = *(const float4*)&pp[(size_t)z * 131072 + i4];
    s.x += p.x; s.y += p.y; s.z += p.z; s.w += p.w;
  }
  int c = i4 & 1023;
  const float* w = half ? wvc : wkc;
  float e0 = 0.f, e1 = 0.f, e2 = 0.f, e3 = 0.f;
  for (int t = 0; t < 16; ++t) {
    float wt = w[t];
    const float* pe = wpe + t * 1024 + c;
    e0 += wt * pe[0]; e1 += wt * pe[1]; e2 += wt * pe[2]; e3 += wt * pe[3];
  }
  s.x += e0; s.y += e1; s.z += e2; s.w += e3;
  float* dst = half ? cv : ck;
  *(float4*)&dst[i4] = s;
}

// ---- split-K fp32 NT GEMM: M1 partials (imp path, fp32-exact) ----
__global__ __launch_bounds__(256) void sgemm_nt_sk(const float* __restrict__ A, const float* __restrict__ Bt,
                                                   float* __restrict__ part, int M, int N, int K, int KC) {
  __shared__ float As2[64][17];
  __shared__ float Bs2[64][17];
  int tid = threadIdx.x;
  int tm = tid >> 4, tn = tid & 15;
  int row0 = blockIdx.y * 64, col0 = blockIdx.x * 64;
  int k0b = blockIdx.z * KC;
  float acc[4][4] = {{0.f}};
  for (int k0 = k0b; k0 < k0b + KC; k0 += 16) {
#pragma unroll
    for (int i = 0; i < 4; ++i) {
      int idx = tid + i * 256;
      As2[idx >> 4][idx & 15] = A[(size_t)(row0 + (idx >> 4)) * K + k0 + (idx & 15)];
      Bs2[idx >> 4][idx & 15] = Bt[(size_t)(col0 + (idx >> 4)) * K + k0 + (idx & 15)];
    }
    __syncthreads();
#pragma unroll
    for (int kk = 0; kk < 16; ++kk) {
      float a[4], b[4];
#pragma unroll
      for (int i = 0; i < 4; ++i) a[i] = As2[tm * 4 + i][kk];
#pragma unroll
      for (int j = 0; j < 4; ++j) b[j] = Bs2[tn * 4 + j][kk];
#pragma unroll
      for (int i = 0; i < 4; ++i)
#pragma unroll
        for (int j = 0; j < 4; ++j) acc[i][j] += a[i] * b[j];
    }
    __syncthreads();
  }
  float* pp = part + (size_t)blockIdx.z * M * N;
#pragma unroll
  for (int i = 0; i < 4; ++i) {
    float4 v = make_float4(acc[i][0], acc[i][1], acc[i][2], acc[i][3]);
    *(float4*)&pp[(size_t)(row0 + tm * 4 + i) * N + col0 + tn * 4] = v;
  }
}

// ---- generic split-K reduce (used for M1) ----
__global__ __launch_bounds__(256) void reduce_sk(const float* __restrict__ part, float* __restrict__ C,
                                                 int total, int SK) {
  int i4 = (blockIdx.x * 256 + threadIdx.x) * 4;
  float4 s = *(const float4*)&part[i4];
  for (int z = 1; z < SK; ++z) {
    float4 p = *(const float4*)&part[(size_t)z * total + i4];
    s.x += p.x; s.y += p.y; s.z += p.z; s.w += p.w;
  }
  *(float4*)&C[i4] = s;
}

// ---- split-K imp partials: part[z][2048][64] = x @ M1[:, batch cols] ----
__global__ __launch_bounds__(256) void imp_sk(const float* __restrict__ A, const float* __restrict__ M1,
                                              float* __restrict__ part, int KC) {
  __shared__ float As2[64][17];
  __shared__ float Bs[16][68];
  int tid = threadIdx.x;
  int tm = tid >> 4, tn = tid & 15;
  int row0 = blockIdx.y * 64;
  int colbase = (row0 >> 10) * 64;
  int k0b = blockIdx.z * KC;
  float acc[4][4] = {{0.f}};
  for (int k0 = k0b; k0 < k0b + KC; k0 += 16) {
#pragma unroll
    for (int i = 0; i < 4; ++i) {
      int idx = tid + i * 256;
      As2[idx >> 4][idx & 15] = A[(size_t)(row0 + (idx >> 4)) * 1024 + k0 + (idx & 15)];
    }
#pragma unroll
    for (int rr = 0; rr < 4; ++rr) {
      int id2 = tid + rr * 256;
      Bs[id2 >> 6][id2 & 63] = M1[(size_t)(k0 + (id2 >> 6)) * 128 + colbase + (id2 & 63)];
    }
    __syncthreads();
#pragma unroll
    for (int kk = 0; kk < 16; ++kk) {
      float a[4], b[4];
#pragma unroll
      for (int i = 0; i < 4; ++i) a[i] = As2[tm * 4 + i][kk];
#pragma unroll
      for (int j = 0; j < 4; ++j) b[j] = Bs[kk][tn * 4 + j];
#pragma unroll
      for (int i = 0; i < 4; ++i)
#pragma unroll
        for (int j = 0; j < 4; ++j) acc[i][j] += a[i] * b[j];
    }
    __syncthreads();
  }
  float* pp = part + (size_t)blockIdx.z * 131072;
#pragma unroll
  for (int i = 0; i < 4; ++i) {
    float4 v = make_float4(acc[i][0], acc[i][1], acc[i][2], acc[i][3]);
    *(float4*)&pp[(size_t)(row0 + tm * 4 + i) * 64 + tn * 4] = v;
  }
}

// ---- fused imp-reduce + top-2 (kInv is 2^-3: exact scale, ordering unchanged) ----
__global__ __launch_bounds__(256) void topk_sum(const float* __restrict__ part, int* __restrict__ tk) {
  int bs = blockIdx.x * 256 + threadIdx.x;
  float vals[64];
  const float* p0 = part + (size_t)bs * 64;
#pragma unroll
  for (int n4 = 0; n4 < 16; ++n4) {
    float4 v = *(const float4*)&p0[n4 * 4];
    vals[n4 * 4] = v.x; vals[n4 * 4 + 1] = v.y; vals[n4 * 4 + 2] = v.z; vals[n4 * 4 + 3] = v.w;
  }
  for (int z = 1; z < 8; ++z) {
    const float* p = p0 + (size_t)z * 131072;
#pragma unroll
    for (int n4 = 0; n4 < 16; ++n4) {
      float4 v = *(const float4*)&p[n4 * 4];
      vals[n4 * 4] += v.x; vals[n4 * 4 + 1] += v.y; vals[n4 * 4 + 2] += v.z; vals[n4 * 4 + 3] += v.w;
    }
  }
  float v1 = -3.0e38f, v2 = -3.0e38f;
  int i1 = 0, i2 = 0;
  for (int n = 0; n < 64; ++n) {
    float v = vals[n];
    if (v > v1) { v2 = v1; i2 = i1; v1 = v; i1 = n; }
    else if (v > v2) { v2 = v; i2 = n; }
  }
  tk[bs * 2] = i1;
  tk[bs * 2 + 1] = i2;
}

// ---- gates = sigmoid(x@Wg + bg) ----
__global__ __launch_bounds__(256) void gates_kernel(const float* __restrict__ x, const float* __restrict__ Wg,
                                                    const float* __restrict__ bg, float* __restrict__ gates) {
  int bs = blockIdx.x;
  int tid = threadIdx.x;
  __shared__ float red[3][256];
  const float* xp = x + (size_t)bs * kD;
  float p0 = 0.f, p1 = 0.f, p2 = 0.f;
  for (int d = tid; d < kD; d += 256) {
    float xv = xp[d];
    p0 += xv * Wg[d * 3 + 0];
    p1 += xv * Wg[d * 3 + 1];
    p2 += xv * Wg[d * 3 + 2];
  }
  red[0][tid] = p0; red[1][tid] = p1; red[2][tid] = p2;
  __syncthreads();
  for (int off = 128; off > 0; off >>= 1) {
    if (tid < off) {
      red[0][tid] += red[0][tid + off];
      red[1][tid] += red[1][tid + off];
      red[2][tid] += red[2][tid + off];
    }
    __syncthreads();
  }
  if (tid < 3) gates[bs * 3 + tid] = 1.f / (1.f + __expf(-(red[tid][0] + bg[tid])));
}

// ---- staging helpers for comp attention (fp32 ck/cv -> swizzled bf16 LDS) ----
__device__ inline void stage_rows_bf16(const float* __restrict__ src, size_t pitch,
                                       bf16* __restrict__ dst, int tid) {
  int r = tid >> 2, qq = tid & 3;
  const float4* sp = (const float4*)(src + (size_t)r * pitch) + qq * 4;
  float4 f0 = sp[0], f1 = sp[1], f2 = sp[2], f3 = sp[3];
  bf16x8 lo, hi;
  lo[0] = (bf16)f0.x; lo[1] = (bf16)f0.y; lo[2] = (bf16)f0.z; lo[3] = (bf16)f0.w;
  lo[4] = (bf16)f1.x; lo[5] = (bf16)f1.y; lo[6] = (bf16)f1.z; lo[7] = (bf16)f1.w;
  hi[0] = (bf16)f2.x; hi[1] = (bf16)f2.y; hi[2] = (bf16)f2.z; hi[3] = (bf16)f2.w;
  hi[4] = (bf16)f3.x; hi[5] = (bf16)f3.y; hi[6] = (bf16)f3.z; hi[7] = (bf16)f3.w;
  int cb = qq * 2;
  *(bf16x8*)&dst[SWZ_IDX(r, cb)]     = lo;
  *(bf16x8*)&dst[SWZ_IDX(r, cb + 1)] = hi;
}

__device__ inline void stage_cols_bf16(const float* __restrict__ src, size_t pitch,
                                       bf16* __restrict__ dst, int tid) {
  int lane = tid & 63, w = tid >> 6;
  const float4* sp = (const float4*)(src + (size_t)lane * pitch + w * 16);
  float4 f[4];
  f[0] = sp[0]; f[1] = sp[1]; f[2] = sp[2]; f[3] = sp[3];
  const float* ff = (const float*)f;
#pragma unroll
  for (int i = 0; i < 16; ++i) {
    int d = w * 16 + i;
    dst[(d << 6) + ((((lane >> 3) ^ (d & 7))) << 3) + (lane & 7)] = (bf16)ff[i];
  }
}

// ---- fused comp + window MFMA flash attention (bf16 q/k/v, async Q/K staging) ----
__global__ __launch_bounds__(256) void attn_mfma(const bf16* __restrict__ qbf, const bf16* __restrict__ kbf,
                                                 const bf16* __restrict__ vbf, const float* __restrict__ ck,
                                                 const float* __restrict__ cv, const float* __restrict__ gat,
                                                 float* __restrict__ acc) {
  __shared__ bf16 Qs[64 * 64];
  __shared__ bf16 Ks[64 * 64];
  __shared__ bf16 Vt[64 * 64];
  __shared__ bf16 Ps[4 * 16 * 64];
  int tid = threadIdx.x, w = tid >> 6, lane = tid & 63;
  int l8 = lane >> 3, s8 = lane & 7;
  int qd = lane >> 4, l16 = lane & 15;
  int s0 = blockIdx.x * 64, h = blockIdx.y, b = blockIdx.z;
  bf16* Pw = Ps + w * 1024;

  const bf16* qsrc = qbf + ((size_t)(b * 1024 + s0)) * kD + h * 64;
#pragma unroll
  for (int i = 0; i < 2; ++i) {
    int row = w * 16 + i * 8 + l8;
    async_ld16(&qsrc[(size_t)row * kD + (s8 ^ l8) * 8], Qs + w * 1024 + i * 512);
  }
  stage_rows_bf16(ck + ((size_t)(b * 64)) * kD + h * 64, kD, Ks, tid);
  stage_cols_bf16(cv + ((size_t)(b * 64)) * kD + h * 64, kD, Vt, tid);
  __syncthreads();

  // ---- compressed attention (single 64-key chunk, no mask) ----
  f32x4 oc[4] = {};
  float lc[4];
  {
    f32x4 sacc[4] = {};
#pragma unroll
    for (int ks = 0; ks < 2; ++ks) {
      bf16x8 aq = LDV(Qs, w * 16 + l16, qd + 4 * ks);
#pragma unroll
      for (int j = 0; j < 4; ++j)
        sacc[j] = __builtin_amdgcn_mfma_f32_16x16x32_bf16(aq, LDV(Ks, 16 * j + l16, qd + 4 * ks), sacc[j], 0, 0, 0);
    }
#pragma unroll
    for (int j = 0; j < 4; ++j)
#pragma unroll
      for (int r = 0; r < 4; ++r) sacc[j][r] *= kInv;
#pragma unroll
    for (int r = 0; r < 4; ++r) {
      float mx = sacc[0][r];
#pragma unroll
      for (int j = 1; j < 4; ++j) mx = fmaxf(mx, sacc[j][r]);
#pragma unroll
      for (int off = 8; off; off >>= 1) mx = fmaxf(mx, __shfl_xor(mx, off));
      int qrow = qd * 4 + r;
      float rs = 0.f;
#pragma unroll
      for (int j = 0; j < 4; ++j) {
        float e = __expf(sacc[j][r] - mx);
        int col = l16 + 16 * j;
        Pw[(qrow << 6) + ((((col >> 3) ^ (qrow & 7))) << 3) + (col & 7)] = (bf16)e;
        rs += e;
      }
#pragma unroll
      for (int off = 8; off; off >>= 1) rs += __shfl_xor(rs, off);
      lc[r] = rs;
    }
    __syncthreads();
#pragma unroll
    for (int ks = 0; ks < 2; ++ks) {
      bf16x8 ap = LDV(Pw, l16, qd + 4 * ks);
#pragma unroll
      for (int j = 0; j < 4; ++j)
        oc[j] = __builtin_amdgcn_mfma_f32_16x16x32_bf16(ap, LDV(Vt, 16 * j + l16, qd + 4 * ks), oc[j], 0, 0, 0);
    }
  }

  // ---- sliding-window attention (online softmax over 64-key chunks) ----
  f32x4 ow[4] = {};
  float mw[4], lw[4];
#pragma unroll
  for (int r = 0; r < 4; ++r) { mw[r] = -1e30f; lw[r] = 0.f; }
  int kb0 = s0 - 256; if (kb0 < 0) kb0 = 0;
  int nck = (s0 + 64 - kb0) >> 6;
  for (int c = 0; c < nck; ++c) {
    int kbase = kb0 + c * 64;
    __syncthreads();
    const bf16* ksrc = kbf + ((size_t)(b * 1024 + kbase)) * kD + h * 64;
#pragma unroll
    for (int i = 0; i < 2; ++i) {
      int row = w * 16 + i * 8 + l8;
      async_ld16(&ksrc[(size_t)row * kD + (s8 ^ l8) * 8], Ks + w * 1024 + i * 512);
    }
    const bf16* vsrc = vbf + ((size_t)(b * 1024 + kbase + lane)) * kD + h * 64 + w * 16;
    bf16x8 v0 = *(const bf16x8*)vsrc;
    bf16x8 v1 = *(const bf16x8*)(vsrc + 8);
#pragma unroll
    for (int i = 0; i < 8; ++i) { int d = w * 16 + i;     Vt[(d << 6) + ((l8 ^ (d & 7)) << 3) + s8] = v0[i]; }
#pragma unroll
    for (int i = 0; i < 8; ++i) { int d = w * 16 + 8 + i; Vt[(d << 6) + ((l8 ^ (d & 7)) << 3) + s8] = v1[i]; }
    __syncthreads();
    f32x4 sacc[4] = {};
#pragma unroll
    for (int ks = 0; ks < 2; ++ks) {
      bf16x8 aq = LDV(Qs, w * 16 + l16, qd + 4 * ks);
#pragma unroll
      for (int j = 0; j < 4; ++j)
        sacc[j] = __builtin_amdgcn_mfma_f32_16x16x32_bf16(aq, LDV(Ks, 16 * j + l16, qd + 4 * ks), sacc[j], 0, 0, 0);
    }
#pragma unroll
    for (int j = 0; j < 4; ++j)
#pragma unroll
      for (int r = 0; r < 4; ++r) {
        int key = kbase + 16 * j + l16;
        int sq = s0 + w * 16 + qd * 4 + r;
        float sc = sacc[j][r] * kInv;
        sacc[j][r] = (key <= sq && sq - key <= 256) ? sc : -1e30f;
      }
#pragma unroll
    for (int r = 0; r < 4; ++r) {
      float mx = sacc[0][r];
#pragma unroll
      for (int j = 1; j < 4; ++j) mx = fmaxf(mx, sacc[j][r]);
#pragma unroll
      for (int off = 8; off; off >>= 1) mx = fmaxf(mx, __shfl_xor(mx, off));
      float mn = fmaxf(mw[r], mx);
      float alpha = __expf(mw[r] - mn);
      mw[r] = mn;
      int qrow = qd * 4 + r;
      float rs = 0.f;
#pragma unroll
      for (int j = 0; j < 4; ++j) {
        float e = __expf(sacc[j][r] - mn);
        int col = l16 + 16 * j;
        Pw[(qrow << 6) + ((((col >> 3) ^ (qrow & 7))) << 3) + (col & 7)] = (bf16)e;
        rs += e;
      }
#pragma unroll
      for (int off = 8; off; off >>= 1) rs += __shfl_xor(rs, off);
      lw[r] = lw[r] * alpha + rs;
#pragma unroll
      for (int j = 0; j < 4; ++j) ow[j][r] *= alpha;
    }
    __syncthreads();
#pragma unroll
    for (int ks = 0; ks < 2; ++ks) {
      bf16x8 ap = LDV(Pw, l16, qd + 4 * ks);
#pragma unroll
      for (int j = 0; j < 4; ++j)
        ow[j] = __builtin_amdgcn_mfma_f32_16x16x32_bf16(ap, LDV(Vt, 16 * j + l16, qd + 4 * ks), ow[j], 0, 0, 0);
    }
  }

#pragma unroll
  for (int r = 0; r < 4; ++r) {
    int sq = s0 + w * 16 + qd * 4 + r;
    size_t row = (size_t)b * 1024 + sq;
    float g0 = gat[row * 3 + 0], g2 = gat[row * 3 + 2];
    float c0 = g0 / lc[r], c2 = g2 / lw[r];
#pragma unroll
    for (int j = 0; j < 4; ++j)
      acc[row * kD + h * 64 + 16 * j + l16] = oc[j][r] * c0 + ow[j][r] * c2;
  }
}

// ---- selected attention v2: full 64-lane score phase, shfl-passed P ----
__global__ __launch_bounds__(256) void sel_attn2(const bf16* __restrict__ qbf, const bf16* __restrict__ kbf,
                                                 const bf16* __restrict__ vbf, const int* __restrict__ tk,
                                                 const float* __restrict__ gat, float* __restrict__ acc) {
  int wid = threadIdx.x >> 6, lane = threadIdx.x & 63;
  int g = blockIdx.x * 4 + wid;
  int h = g & 15, bs = g >> 4, b = bs >> 10, s = bs & 1023;
  __shared__ float qs[4][64];
  qs[wid][lane] = (float)qbf[(size_t)bs * kD + h * 64 + lane];
  __syncthreads();
  int m = lane & 15, dg = lane >> 4;
  int blk = tk[((size_t)(m >> 3) * 1024 + s) * 2 + b];     // top_idx[j, s, b]
  int tok = (m >> 3) * 1024 + blk * 16 + (m & 7);          // row in batch j=m>>3
  const bf16* kp = kbf + (size_t)tok * kD + h * 64 + dg * 16;
  bf16x8 k0 = *(const bf16x8*)kp;
  bf16x8 k1 = *(const bf16x8*)(kp + 8);
  float sc = 0.f;
#pragma unroll
  for (int i = 0; i < 8; ++i) sc += (float)k0[i] * qs[wid][dg * 16 + i];
#pragma unroll
  for (int i = 0; i < 8; ++i) sc += (float)k1[i] * qs[wid][dg * 16 + 8 + i];
  sc += __shfl_xor(sc, 16);
  sc += __shfl_xor(sc, 32);
  sc *= kInv;
  float mx = sc;
#pragma unroll
  for (int off = 8; off; off >>= 1) mx = fmaxf(mx, __shfl_xor(mx, off));
  float e = __expf(sc - mx);
  float ss = e;
#pragma unroll
  for (int off = 8; off; off >>= 1) ss += __shfl_xor(ss, off);
  float p = e / ss;
  const bf16* vb = vbf + h * 64 + lane;
  float o = 0.f;
#pragma unroll
  for (int mi = 0; mi < 16; ++mi) {
    int tm = __shfl(tok, mi);
    float pm = __shfl(p, mi);
    o += pm * (float)vb[(size_t)tm * kD];
  }
  acc[(size_t)bs * kD + h * 64 + lane] += gat[bs * 3 + 1] * o;
}

extern "C" void kernel_launch(void* const* d_in, const int* in_sizes, int n_in,
                              void* d_out, int out_size, void* d_ws, size_t ws_size,
                              hipStream_t stream) {
  const float* x   = (const float*)d_in[0];
  const float* Wq  = (const float*)d_in[1];
  const float* Wk  = (const float*)d_in[2];
  const float* Wv  = (const float*)d_in[3];
  const float* Wo  = (const float*)d_in[4];
  const float* bo  = (const float*)d_in[5];
  const float* Wg  = (const float*)d_in[6];
  const float* bg  = (const float*)d_in[7];
  const float* wkc = (const float*)d_in[8];
  const float* wvc = (const float*)d_in[9];
  const float* wpe = (const float*)d_in[10];
  float* out = (float*)d_out;

  float* ws    = (float*)d_ws;
  bf16*  qkvbf = (bf16*)ws;                    // 3 x 2097152 bf16 (= 3145728 f32)
  float* accb  = ws + 3145728;                 // 2097152
  float* ck    = accb + 2097152;               // 131072
  float* cv    = ck + 131072;
  float* cxk   = cv + 131072;
  float* cxv   = cxk + 131072;
  float* M1    = cxv + 131072;                 // [1024][128]
  float* gat   = M1 + 131072;                  // 6144
  int*   tk    = (int*)(gat + 6144);           // 4096 ints
  bf16*  xbf   = (bf16*)(gat + 6144 + 4096);   // 2097152 bf16 (= 1048576 f32)
  bf16*  Wt4   = (bf16*)((float*)xbf + 1048576);   // 4 x 1048576 bf16 (= 2097152 f32)
  bf16*  accbf = (bf16*)((float*)Wt4 + 2097152);   // 2097152 bf16 (= 1048576 f32)
  float* skbuf  = (float*)accbf + 1048576;     // 16 x 131072 (ck|cv partials)
  float* skbuf2 = skbuf + 2097152;             // 8 x 131072 (M1 then imp partials)
  const bf16* qbf = qkvbf;
  const bf16* kbf = qkvbf + 2097152;
  const bf16* vbf = qkvbf + 2 * 2097152;

  cx_kernel<<<512, 256, 0, stream>>>(x, wkc, wvc, cxk, cxv);
  cvt_bf16<<<1024, 256, 0, stream>>>(x, xbf);
  transpose4<<<dim3(32, 32, 4), 256, 0, stream>>>(Wq, Wk, Wv, Wo, Wt4);

  gemm_qkv<<<dim3(16, 16, 3), 256, 0, stream>>>(xbf, Wt4, qkvbf, wpe);

  sgemm_nn_sk2<<<dim3(16, 2, 16), 256, 0, stream>>>(cxk, cxv, Wk, Wv, skbuf);
  reduce_ckcv<<<256, 256, 0, stream>>>(skbuf, ck, cv, wkc, wvc, wpe);

  sgemm_nt_sk<<<dim3(2, 16, 8), 256, 0, stream>>>(Wq, ck, skbuf2, 1024, 128, 1024, 128);
  reduce_sk<<<128, 256, 0, stream>>>(skbuf2, M1, 131072, 8);
  imp_sk<<<dim3(1, 32, 8), 256, 0, stream>>>(x, M1, skbuf2, 128);
  topk_sum<<<8, 256, 0, stream>>>(skbuf2, tk);

  gates_kernel<<<2048, 256, 0, stream>>>(x, Wg, bg, gat);

  attn_mfma<<<dim3(16, 16, 2), 256, 0, stream>>>(qbf, kbf, vbf, ck, cv, gat, accb);
  sel_attn2<<<8192, 256, 0, stream>>>(qbf, kbf, vbf, tk, gat, accb);

  cvt_bf16<<<1024, 256, 0, stream>>>(accb, accbf);
  gemm_out<<<dim3(16, 16), 256, 0, stream>>>(accbf, Wt4 + (size_t)3 * 1048576, out, bo);
}

// Round 6
// 221.915 us; speedup vs baseline: 5.2015x; 1.0664x over previous
//
#include <hip/hip_runtime.h>

// NativeSparseAttention round 6: z-fused QKV MFMA GEMM (A-fragment reuse x3,
// ds:mfma ratio 1.03, 256 balanced blocks), sel-first + bf16 attn epilogue
// (drops cvt + fp32 acc round-trip), prep fusion, wave-parallel top-k.
// B=2 S=1024 D=1024 H=KV=16 HD=64 Nc=64 CB=16 SB=8 J=2 W=256

typedef __bf16 bf16;
typedef bf16 bf16x8 __attribute__((ext_vector_type(8)));
typedef float f32x4 __attribute__((ext_vector_type(4)));

constexpr int kD = 1024;
constexpr float kInv = 0.125f;  // 1/sqrt(64), exact power of 2

// Swizzled LDS tile: row stride 64 bf16 = 128 B = 32 banks; 16B chunk cb of row
// stored at slot cb^(row&7) -> every 64-lane b128 access conflict-free.
#define SWZ_IDX(row, cb) (((row) << 6) + (((cb) ^ ((row) & 7)) << 3))
#define LDV(arr, row, cb) (*(const bf16x8*)&(arr)[SWZ_IDX(row, cb)])

// Async 16B global->LDS; LDS dest = wave-uniform base + lane*16. One call per
// wave stages 8 rows x 64 cols (lane = l8*8+s8 -> row +l8, chunk-slot s8 holds
// global chunk s8^l8, matching SWZ_IDX for rows where row&7 == l8).
__device__ __forceinline__ void async_ld16(const bf16* g, bf16* l) {
  __builtin_amdgcn_global_load_lds(
      (const __attribute__((address_space(1))) unsigned int*)g,
      (__attribute__((address_space(3))) unsigned int*)l, 16, 0, 0);
}

// ---- prep: blocks [0,512) cx ; [512,1536) x->bf16 ; [1536,3584) gates ----
__global__ __launch_bounds__(256) void prep_kernel(const float* __restrict__ x, const float* __restrict__ wkc,
                                                   const float* __restrict__ wvc, const float* __restrict__ Wg,
                                                   const float* __restrict__ bg, float* __restrict__ cxk,
                                                   float* __restrict__ cxv, bf16* __restrict__ xbf,
                                                   float* __restrict__ gates) {
  int blk = blockIdx.x, tid = threadIdx.x;
  if (blk < 512) {  // cx: cxk[bn][d] = sum_t wkc[t]*x[b,16n+t,d]
    int idx = blk * 256 + tid;
    int d = idx & 1023, bn = idx >> 10;
    const float* xp = x + (size_t)bn * 16 * kD + d;
    float a = 0.f, c = 0.f;
    for (int t = 0; t < 16; ++t) {
      float xv = xp[(size_t)t * kD];
      a += wkc[t] * xv;
      c += wvc[t] * xv;
    }
    cxk[idx] = a;
    cxv[idx] = c;
  } else if (blk < 1536) {  // cvt x -> bf16
    int i = (blk - 512) * 256 + tid;
    const float4* p = (const float4*)x + (size_t)i * 2;
    float4 a = p[0], b = p[1];
    bf16x8 v;
    v[0] = (bf16)a.x; v[1] = (bf16)a.y; v[2] = (bf16)a.z; v[3] = (bf16)a.w;
    v[4] = (bf16)b.x; v[5] = (bf16)b.y; v[6] = (bf16)b.z; v[7] = (bf16)b.w;
    *(bf16x8*)&xbf[(size_t)i * 8] = v;
  } else {  // gates = sigmoid(x@Wg + bg), one block per bs
    int bs = blk - 1536;
    __shared__ float red[3][256];
    const float* xp = x + (size_t)bs * kD;
    float p0 = 0.f, p1 = 0.f, p2 = 0.f;
    for (int d = tid; d < kD; d += 256) {
      float xv = xp[d];
      p0 += xv * Wg[d * 3 + 0];
      p1 += xv * Wg[d * 3 + 1];
      p2 += xv * Wg[d * 3 + 2];
    }
    red[0][tid] = p0; red[1][tid] = p1; red[2][tid] = p2;
    __syncthreads();
    for (int off = 128; off > 0; off >>= 1) {
      if (tid < off) {
        red[0][tid] += red[0][tid + off];
        red[1][tid] += red[1][tid + off];
        red[2][tid] += red[2][tid + off];
      }
      __syncthreads();
    }
    if (tid < 3) gates[bs * 3 + tid] = 1.f / (1.f + __expf(-(red[tid][0] + bg[tid])));
  }
}

// ---- transpose all 4 weights fp32 [1024][1024] -> bf16 [C][R] ----
__global__ __launch_bounds__(256) void transpose4(const float* __restrict__ Wq, const float* __restrict__ Wk,
                                                  const float* __restrict__ Wv, const float* __restrict__ Wo,
                                                  bf16* __restrict__ Wt4) {
  __shared__ float t[32][33];
  const float* in = (blockIdx.z == 0) ? Wq : (blockIdx.z == 1) ? Wk : (blockIdx.z == 2) ? Wv : Wo;
  bf16* out = Wt4 + (size_t)blockIdx.z * 1048576;
  int c0 = blockIdx.x * 32, r0 = blockIdx.y * 32;
  int tx = threadIdx.x & 31, ty = threadIdx.x >> 5;
#pragma unroll
  for (int i = 0; i < 32; i += 8) t[ty + i][tx] = in[(size_t)(r0 + ty + i) * 1024 + c0 + tx];
  __syncthreads();
#pragma unroll
  for (int i = 0; i < 32; i += 8) out[(size_t)(c0 + ty + i) * 1024 + r0 + tx] = (bf16)t[tx][ty + i];
}

// ---- z-fused QKV GEMM: one 128x64 tile for all 3 weights; A-frags reused 3x ----
__global__ __launch_bounds__(256) void gemm_qkv3(const bf16* __restrict__ xbf, const bf16* __restrict__ Wt4,
                                                 bf16* __restrict__ qkv, const float* __restrict__ wpe) {
  __shared__ bf16 As[128 * 64];     // 16 KB
  __shared__ bf16 Bs[3 * 64 * 64];  // 24 KB
  int tid = threadIdx.x, w = tid >> 6, lane = tid & 63;
  int l8 = lane >> 3, s8 = lane & 7;
  int qd = lane >> 4, l16 = lane & 15;
  int row0 = blockIdx.y * 128, col0 = blockIdx.x * 64;
  int mr = (w & 1) * 64, nc = (w >> 1) * 32;
  f32x4 acc[3][4][2] = {};
  for (int k0 = 0; k0 < 1024; k0 += 64) {
    __syncthreads();
#pragma unroll
    for (int i = 0; i < 4; ++i) {  // As: 128 rows, wave w rows [w*32, w*32+32)
      int row = w * 32 + i * 8 + l8;
      async_ld16(&xbf[(size_t)(row0 + row) * 1024 + k0 + (s8 ^ l8) * 8], As + w * 2048 + i * 512);
    }
#pragma unroll
    for (int i = 0; i < 6; ++i) {  // Bs: 3 z-tiles x 64 rows; 24 groups of 8 rows
      int g = w * 6 + i;
      int z = g >> 3, rg = g & 7;
      int row = rg * 8 + l8;
      async_ld16(&Wt4[(size_t)z * 1048576 + (size_t)(col0 + row) * 1024 + k0 + (s8 ^ l8) * 8],
                 Bs + z * 4096 + rg * 512);
    }
    __syncthreads();
#pragma unroll
    for (int ks = 0; ks < 2; ++ks) {
      bf16x8 af[4];
#pragma unroll
      for (int i = 0; i < 4; ++i) af[i] = LDV(As, mr + i * 16 + l16, ks * 4 + qd);
#pragma unroll
      for (int z = 0; z < 3; ++z) {
        bf16x8 bfr[2];
#pragma unroll
        for (int j = 0; j < 2; ++j) bfr[j] = LDV(Bs + z * 4096, nc + j * 16 + l16, ks * 4 + qd);
#pragma unroll
        for (int i = 0; i < 4; ++i)
#pragma unroll
          for (int j = 0; j < 2; ++j)
            acc[z][i][j] = __builtin_amdgcn_mfma_f32_16x16x32_bf16(af[i], bfr[j], acc[z][i][j], 0, 0, 0);
      }
    }
  }
#pragma unroll
  for (int z = 0; z < 3; ++z) {
    bf16* C = qkv + (size_t)z * 2097152;
#pragma unroll
    for (int i = 0; i < 4; ++i)
#pragma unroll
      for (int j = 0; j < 2; ++j)
#pragma unroll
        for (int r = 0; r < 4; ++r) {
          int rr = row0 + mr + i * 16 + qd * 4 + r;
          int cc = col0 + nc + j * 16 + l16;
          float v = acc[z][i][j][r];
          if (z) v += wpe[(rr & 15) * kD + cc];
          C[(size_t)rr * kD + cc] = (bf16)v;
        }
  }
}

// ---- bf16 MFMA GEMM core (gemm_out): BM=128 BN=64 BK=64, async staging ----
__device__ __forceinline__ void gemm_core(const bf16* __restrict__ A, const bf16* __restrict__ Bt,
                                          int K, int row0, int col0, bf16* As, bf16* Bs,
                                          int tid, f32x4 (&acc)[4][2]) {
  int w = tid >> 6, lane = tid & 63;
  int l8 = lane >> 3, s8 = lane & 7;
  int qd = lane >> 4, l16 = lane & 15;
  int mr = (w & 1) * 64, nc = (w >> 1) * 32;
  for (int k0 = 0; k0 < K; k0 += 64) {
    __syncthreads();
#pragma unroll
    for (int i = 0; i < 4; ++i) {
      int row = w * 32 + i * 8 + l8;
      async_ld16(&A[(size_t)(row0 + row) * K + k0 + (s8 ^ l8) * 8], As + w * 2048 + i * 512);
    }
#pragma unroll
    for (int i = 0; i < 2; ++i) {
      int row = w * 16 + i * 8 + l8;
      async_ld16(&Bt[(size_t)(col0 + row) * K + k0 + (s8 ^ l8) * 8], Bs + w * 1024 + i * 512);
    }
    __syncthreads();
#pragma unroll
    for (int ks = 0; ks < 2; ++ks) {
      bf16x8 af[4], bfr[2];
#pragma unroll
      for (int i = 0; i < 4; ++i) af[i] = LDV(As, mr + i * 16 + l16, ks * 4 + qd);
#pragma unroll
      for (int j = 0; j < 2; ++j) bfr[j] = LDV(Bs, nc + j * 16 + l16, ks * 4 + qd);
#pragma unroll
      for (int i = 0; i < 4; ++i)
#pragma unroll
        for (int j = 0; j < 2; ++j)
          acc[i][j] = __builtin_amdgcn_mfma_f32_16x16x32_bf16(af[i], bfr[j], acc[i][j], 0, 0, 0);
    }
  }
}

// ---- out = accbf@Wo + bo, fp32 out ----
__global__ __launch_bounds__(256) void gemm_out(const bf16* __restrict__ accbf, const bf16* __restrict__ Wot,
                                                float* __restrict__ out, const float* __restrict__ bo) {
  __shared__ bf16 As[128 * 64];
  __shared__ bf16 Bs[64 * 64];
  int tid = threadIdx.x;
  int row0 = blockIdx.y * 128, col0 = blockIdx.x * 64;
  f32x4 acc[4][2] = {};
  gemm_core(accbf, Wot, 1024, row0, col0, As, Bs, tid, acc);
  int w = tid >> 6, lane = tid & 63, qd = lane >> 4, l16 = lane & 15;
  int mr = (w & 1) * 64, nc = (w >> 1) * 32;
#pragma unroll
  for (int i = 0; i < 4; ++i)
#pragma unroll
    for (int j = 0; j < 2; ++j)
#pragma unroll
      for (int r = 0; r < 4; ++r) {
        int rr = row0 + mr + i * 16 + qd * 4 + r;
        int cc = col0 + nc + j * 16 + l16;
        out[(size_t)rr * kD + cc] = acc[i][j][r] + bo[cc];
      }
}

// ---- split-K fp32 NN GEMM for ck|cv merged: z<8 -> cxk, z>=8 -> cxv ----
__global__ __launch_bounds__(256) void sgemm_nn_sk2(const float* __restrict__ Ak, const float* __restrict__ Av,
                                                    const float* __restrict__ Wk, const float* __restrict__ Wv,
                                                    float* __restrict__ part) {
  __shared__ float As2[64][17];
  __shared__ float Bs[16][68];
  const float* A = (blockIdx.z < 8) ? Ak : Av;
  const float* Bm = (blockIdx.z < 8) ? Wk : Wv;
  int tid = threadIdx.x;
  int tm = tid >> 4, tn = tid & 15;
  int row0 = blockIdx.y * 64, col0 = blockIdx.x * 64;
  int k0b = (blockIdx.z & 7) * 128;
  float acc[4][4] = {{0.f}};
  for (int k0 = k0b; k0 < k0b + 128; k0 += 16) {
#pragma unroll
    for (int i = 0; i < 4; ++i) {
      int idx = tid + i * 256;
      As2[idx >> 4][idx & 15] = A[(size_t)(row0 + (idx >> 4)) * 1024 + k0 + (idx & 15)];
      Bs[idx >> 6][idx & 63] = Bm[(size_t)(k0 + (idx >> 6)) * 1024 + col0 + (idx & 63)];
    }
    __syncthreads();
#pragma unroll
    for (int kk = 0; kk < 16; ++kk) {
      float a[4], b[4];
#pragma unroll
      for (int i = 0; i < 4; ++i) a[i] = As2[tm * 4 + i][kk];
#pragma unroll
      for (int j = 0; j < 4; ++j) b[j] = Bs[kk][tn * 4 + j];
#pragma unroll
      for (int i = 0; i < 4; ++i)
#pragma unroll
        for (int j = 0; j < 4; ++j) acc[i][j] += a[i] * b[j];
    }
    __syncthreads();
  }
  float* pp = part + (size_t)blockIdx.z * 131072;
#pragma unroll
  for (int i = 0; i < 4; ++i) {
    float4 v = make_float4(acc[i][0], acc[i][1], acc[i][2], acc[i][3]);
    *(float4*)&pp[(size_t)(row0 + tm * 4 + i) * 1024 + col0 + tn * 4] = v;
  }
}

// ---- reduce ck|cv partials with inline cpe ----
__global__ __launch_bounds__(256) void reduce_ckcv(const float* __restrict__ part, float* __restrict__ ck,
                                                   float* __restrict__ cv, const float* __restrict__ wkc,
                                                   const float* __restrict__ wvc, const float* __restrict__ wpe) {
  int half = blockIdx.x >> 7;
  int i4 = (((blockIdx.x & 127) * 256) + threadIdx.x) * 4;
  const float* pp = part + (size_t)half * 8 * 131072;
  float4 s = *(const float4*)&pp[i4];
  for (int z = 1; z < 8; ++z) {
    float4 p = *(const float4*)&pp[(size_t)z * 131072 + i4];
    s.x += p.x; s.y += p.y; s.z += p.z; s.w += p.w;
  }
  int c = i4 & 1023;
  const float* w = half ? wvc : wkc;
  float e0 = 0.f, e1 = 0.f, e2 = 0.f, e3 = 0.f;
  for (int t = 0; t < 16; ++t) {
    float wt = w[t];
    const float* pe = wpe + t * 1024 + c;
    e0 += wt * pe[0]; e1 += wt * pe[1]; e2 += wt * pe[2]; e3 += wt * pe[3];
  }
  s.x += e0; s.y += e1; s.z += e2; s.w += e3;
  float* dst = half ? cv : ck;
  *(float4*)&dst[i4] = s;
}

// ---- split-K fp32 NT GEMM: M1 partials (imp path, fp32-exact) ----
__global__ __launch_bounds__(256) void sgemm_nt_sk(const float* __restrict__ A, const float* __restrict__ Bt,
                                                   float* __restrict__ part, int M, int N, int K, int KC) {
  __shared__ float As2[64][17];
  __shared__ float Bs2[64][17];
  int tid = threadIdx.x;
  int tm = tid >> 4, tn = tid & 15;
  int row0 = blockIdx.y * 64, col0 = blockIdx.x * 64;
  int k0b = blockIdx.z * KC;
  float acc[4][4] = {{0.f}};
  for (int k0 = k0b; k0 < k0b + KC; k0 += 16) {
#pragma unroll
    for (int i = 0; i < 4; ++i) {
      int idx = tid + i * 256;
      As2[idx >> 4][idx & 15] = A[(size_t)(row0 + (idx >> 4)) * K + k0 + (idx & 15)];
      Bs2[idx >> 4][idx & 15] = Bt[(size_t)(col0 + (idx >> 4)) * K + k0 + (idx & 15)];
    }
    __syncthreads();
#pragma unroll
    for (int kk = 0; kk < 16; ++kk) {
      float a[4], b[4];
#pragma unroll
      for (int i = 0; i < 4; ++i) a[i] = As2[tm * 4 + i][kk];
#pragma unroll
      for (int j = 0; j < 4; ++j) b[j] = Bs2[tn * 4 + j][kk];
#pragma unroll
      for (int i = 0; i < 4; ++i)
#pragma unroll
        for (int j = 0; j < 4; ++j) acc[i][j] += a[i] * b[j];
    }
    __syncthreads();
  }
  float* pp = part + (size_t)blockIdx.z * M * N;
#pragma unroll
  for (int i = 0; i < 4; ++i) {
    float4 v = make_float4(acc[i][0], acc[i][1], acc[i][2], acc[i][3]);
    *(float4*)&pp[(size_t)(row0 + tm * 4 + i) * N + col0 + tn * 4] = v;
  }
}

// ---- generic split-K reduce (M1) ----
__global__ __launch_bounds__(256) void reduce_sk(const float* __restrict__ part, float* __restrict__ C,
                                                 int total, int SK) {
  int i4 = (blockIdx.x * 256 + threadIdx.x) * 4;
  float4 s = *(const float4*)&part[i4];
  for (int z = 1; z < SK; ++z) {
    float4 p = *(const float4*)&part[(size_t)z * total + i4];
    s.x += p.x; s.y += p.y; s.z += p.z; s.w += p.w;
  }
  *(float4*)&C[i4] = s;
}

// ---- split-K imp partials ----
__global__ __launch_bounds__(256) void imp_sk(const float* __restrict__ A, const float* __restrict__ M1,
                                              float* __restrict__ part, int KC) {
  __shared__ float As2[64][17];
  __shared__ float Bs[16][68];
  int tid = threadIdx.x;
  int tm = tid >> 4, tn = tid & 15;
  int row0 = blockIdx.y * 64;
  int colbase = (row0 >> 10) * 64;
  int k0b = blockIdx.z * KC;
  float acc[4][4] = {{0.f}};
  for (int k0 = k0b; k0 < k0b + KC; k0 += 16) {
#pragma unroll
    for (int i = 0; i < 4; ++i) {
      int idx = tid + i * 256;
      As2[idx >> 4][idx & 15] = A[(size_t)(row0 + (idx >> 4)) * 1024 + k0 + (idx & 15)];
    }
#pragma unroll
    for (int rr = 0; rr < 4; ++rr) {
      int id2 = tid + rr * 256;
      Bs[id2 >> 6][id2 & 63] = M1[(size_t)(k0 + (id2 >> 6)) * 128 + colbase + (id2 & 63)];
    }
    __syncthreads();
#pragma unroll
    for (int kk = 0; kk < 16; ++kk) {
      float a[4], b[4];
#pragma unroll
      for (int i = 0; i < 4; ++i) a[i] = As2[tm * 4 + i][kk];
#pragma unroll
      for (int j = 0; j < 4; ++j) b[j] = Bs[kk][tn * 4 + j];
#pragma unroll
      for (int i = 0; i < 4; ++i)
#pragma unroll
        for (int j = 0; j < 4; ++j) acc[i][j] += a[i] * b[j];
    }
    __syncthreads();
  }
  float* pp = part + (size_t)blockIdx.z * 131072;
#pragma unroll
  for (int i = 0; i < 4; ++i) {
    float4 v = make_float4(acc[i][0], acc[i][1], acc[i][2], acc[i][3]);
    *(float4*)&pp[(size_t)(row0 + tm * 4 + i) * 64 + tn * 4] = v;
  }
}

// ---- wave-parallel imp-reduce + top-2: one wave per (b,s), lane = block n ----
__global__ __launch_bounds__(256) void topk_wave(const float* __restrict__ part, int* __restrict__ tk) {
  int wid = threadIdx.x >> 6, lane = threadIdx.x & 63;
  int bs = blockIdx.x * 4 + wid;
  float v = 0.f;
  const float* p = part + (size_t)bs * 64 + lane;
#pragma unroll
  for (int z = 0; z < 8; ++z) v += p[(size_t)z * 131072];
  // top-1 with tie -> lower index (matches lax.top_k)
  float v1 = v; int i1 = lane;
#pragma unroll
  for (int off = 32; off; off >>= 1) {
    float ov = __shfl_xor(v1, off);
    int oi = __shfl_xor(i1, off);
    if (ov > v1 || (ov == v1 && oi < i1)) { v1 = ov; i1 = oi; }
  }
  float v2 = (lane == i1) ? -3.0e38f : v;
  int i2 = lane;
#pragma unroll
  for (int off = 32; off; off >>= 1) {
    float ov = __shfl_xor(v2, off);
    int oi = __shfl_xor(i2, off);
    if (ov > v2 || (ov == v2 && oi < i2)) { v2 = ov; i2 = oi; }
  }
  if (lane == 0) {
    tk[bs * 2] = i1;
    tk[bs * 2 + 1] = i2;
  }
}

// ---- staging helpers for comp attention (fp32 ck/cv -> swizzled bf16 LDS) ----
__device__ inline void stage_rows_bf16(const float* __restrict__ src, size_t pitch,
                                       bf16* __restrict__ dst, int tid) {
  int r = tid >> 2, qq = tid & 3;
  const float4* sp = (const float4*)(src + (size_t)r * pitch) + qq * 4;
  float4 f0 = sp[0], f1 = sp[1], f2 = sp[2], f3 = sp[3];
  bf16x8 lo, hi;
  lo[0] = (bf16)f0.x; lo[1] = (bf16)f0.y; lo[2] = (bf16)f0.z; lo[3] = (bf16)f0.w;
  lo[4] = (bf16)f1.x; lo[5] = (bf16)f1.y; lo[6] = (bf16)f1.z; lo[7] = (bf16)f1.w;
  hi[0] = (bf16)f2.x; hi[1] = (bf16)f2.y; hi[2] = (bf16)f2.z; hi[3] = (bf16)f2.w;
  hi[4] = (bf16)f3.x; hi[5] = (bf16)f3.y; hi[6] = (bf16)f3.z; hi[7] = (bf16)f3.w;
  int cb = qq * 2;
  *(bf16x8*)&dst[SWZ_IDX(r, cb)]     = lo;
  *(bf16x8*)&dst[SWZ_IDX(r, cb + 1)] = hi;
}

__device__ inline void stage_cols_bf16(const float* __restrict__ src, size_t pitch,
                                       bf16* __restrict__ dst, int tid) {
  int lane = tid & 63, w = tid >> 6;
  const float4* sp = (const float4*)(src + (size_t)lane * pitch + w * 16);
  float4 f[4];
  f[0] = sp[0]; f[1] = sp[1]; f[2] = sp[2]; f[3] = sp[3];
  const float* ff = (const float*)f;
#pragma unroll
  for (int i = 0; i < 16; ++i) {
    int d = w * 16 + i;
    dst[(d << 6) + ((((lane >> 3) ^ (d & 7))) << 3) + (lane & 7)] = (bf16)ff[i];
  }
}

// ---- fused comp + window MFMA flash attention; epilogue adds sel part (accb)
// and writes bf16 accbf directly ----
__global__ __launch_bounds__(256) void attn_mfma(const bf16* __restrict__ qbf, const bf16* __restrict__ kbf,
                                                 const bf16* __restrict__ vbf, const float* __restrict__ ck,
                                                 const float* __restrict__ cv, const float* __restrict__ gat,
                                                 const float* __restrict__ selp, bf16* __restrict__ accbf) {
  __shared__ bf16 Qs[64 * 64];
  __shared__ bf16 Ks[64 * 64];
  __shared__ bf16 Vt[64 * 64];
  __shared__ bf16 Ps[4 * 16 * 64];
  int tid = threadIdx.x, w = tid >> 6, lane = tid & 63;
  int l8 = lane >> 3, s8 = lane & 7;
  int qd = lane >> 4, l16 = lane & 15;
  int s0 = blockIdx.x * 64, h = blockIdx.y, b = blockIdx.z;
  bf16* Pw = Ps + w * 1024;

  const bf16* qsrc = qbf + ((size_t)(b * 1024 + s0)) * kD + h * 64;
#pragma unroll
  for (int i = 0; i < 2; ++i) {
    int row = w * 16 + i * 8 + l8;
    async_ld16(&qsrc[(size_t)row * kD + (s8 ^ l8) * 8], Qs + w * 1024 + i * 512);
  }
  stage_rows_bf16(ck + ((size_t)(b * 64)) * kD + h * 64, kD, Ks, tid);
  stage_cols_bf16(cv + ((size_t)(b * 64)) * kD + h * 64, kD, Vt, tid);
  __syncthreads();

  // compressed attention (single 64-key chunk, no mask)
  f32x4 oc[4] = {};
  float lc[4];
  {
    f32x4 sacc[4] = {};
#pragma unroll
    for (int ks = 0; ks < 2; ++ks) {
      bf16x8 aq = LDV(Qs, w * 16 + l16, qd + 4 * ks);
#pragma unroll
      for (int j = 0; j < 4; ++j)
        sacc[j] = __builtin_amdgcn_mfma_f32_16x16x32_bf16(aq, LDV(Ks, 16 * j + l16, qd + 4 * ks), sacc[j], 0, 0, 0);
    }
#pragma unroll
    for (int j = 0; j < 4; ++j)
#pragma unroll
      for (int r = 0; r < 4; ++r) sacc[j][r] *= kInv;
#pragma unroll
    for (int r = 0; r < 4; ++r) {
      float mx = sacc[0][r];
#pragma unroll
      for (int j = 1; j < 4; ++j) mx = fmaxf(mx, sacc[j][r]);
#pragma unroll
      for (int off = 8; off; off >>= 1) mx = fmaxf(mx, __shfl_xor(mx, off));
      int qrow = qd * 4 + r;
      float rs = 0.f;
#pragma unroll
      for (int j = 0; j < 4; ++j) {
        float e = __expf(sacc[j][r] - mx);
        int col = l16 + 16 * j;
        Pw[(qrow << 6) + ((((col >> 3) ^ (qrow & 7))) << 3) + (col & 7)] = (bf16)e;
        rs += e;
      }
#pragma unroll
      for (int off = 8; off; off >>= 1) rs += __shfl_xor(rs, off);
      lc[r] = rs;
    }
    __syncthreads();
#pragma unroll
    for (int ks = 0; ks < 2; ++ks) {
      bf16x8 ap = LDV(Pw, l16, qd + 4 * ks);
#pragma unroll
      for (int j = 0; j < 4; ++j)
        oc[j] = __builtin_amdgcn_mfma_f32_16x16x32_bf16(ap, LDV(Vt, 16 * j + l16, qd + 4 * ks), oc[j], 0, 0, 0);
    }
  }

  // sliding-window attention (online softmax over 64-key chunks)
  f32x4 ow[4] = {};
  float mw[4], lw[4];
#pragma unroll
  for (int r = 0; r < 4; ++r) { mw[r] = -1e30f; lw[r] = 0.f; }
  int kb0 = s0 - 256; if (kb0 < 0) kb0 = 0;
  int nck = (s0 + 64 - kb0) >> 6;
  for (int c = 0; c < nck; ++c) {
    int kbase = kb0 + c * 64;
    __syncthreads();
    const bf16* ksrc = kbf + ((size_t)(b * 1024 + kbase)) * kD + h * 64;
#pragma unroll
    for (int i = 0; i < 2; ++i) {
      int row = w * 16 + i * 8 + l8;
      async_ld16(&ksrc[(size_t)row * kD + (s8 ^ l8) * 8], Ks + w * 1024 + i * 512);
    }
    const bf16* vsrc = vbf + ((size_t)(b * 1024 + kbase + lane)) * kD + h * 64 + w * 16;
    bf16x8 v0 = *(const bf16x8*)vsrc;
    bf16x8 v1 = *(const bf16x8*)(vsrc + 8);
#pragma unroll
    for (int i = 0; i < 8; ++i) { int d = w * 16 + i;     Vt[(d << 6) + ((l8 ^ (d & 7)) << 3) + s8] = v0[i]; }
#pragma unroll
    for (int i = 0; i < 8; ++i) { int d = w * 16 + 8 + i; Vt[(d << 6) + ((l8 ^ (d & 7)) << 3) + s8] = v1[i]; }
    __syncthreads();
    f32x4 sacc[4] = {};
#pragma unroll
    for (int ks = 0; ks < 2; ++ks) {
      bf16x8 aq = LDV(Qs, w * 16 + l16, qd + 4 * ks);
#pragma unroll
      for (int j = 0; j < 4; ++j)
        sacc[j] = __builtin_amdgcn_mfma_f32_16x16x32_bf16(aq, LDV(Ks, 16 * j + l16, qd + 4 * ks), sacc[j], 0, 0, 0);
    }
#pragma unroll
    for (int j = 0; j < 4; ++j)
#pragma unroll
      for (int r = 0; r < 4; ++r) {
        int key = kbase + 16 * j + l16;
        int sq = s0 + w * 16 + qd * 4 + r;
        float sc = sacc[j][r] * kInv;
        sacc[j][r] = (key <= sq && sq - key <= 256) ? sc : -1e30f;
      }
#pragma unroll
    for (int r = 0; r < 4; ++r) {
      float mx = sacc[0][r];
#pragma unroll
      for (int j = 1; j < 4; ++j) mx = fmaxf(mx, sacc[j][r]);
#pragma unroll
      for (int off = 8; off; off >>= 1) mx = fmaxf(mx, __shfl_xor(mx, off));
      float mn = fmaxf(mw[r], mx);
      float alpha = __expf(mw[r] - mn);
      mw[r] = mn;
      int qrow = qd * 4 + r;
      float rs = 0.f;
#pragma unroll
      for (int j = 0; j < 4; ++j) {
        float e = __expf(sacc[j][r] - mn);
        int col = l16 + 16 * j;
        Pw[(qrow << 6) + ((((col >> 3) ^ (qrow & 7))) << 3) + (col & 7)] = (bf16)e;
        rs += e;
      }
#pragma unroll
      for (int off = 8; off; off >>= 1) rs += __shfl_xor(rs, off);
      lw[r] = lw[r] * alpha + rs;
#pragma unroll
      for (int j = 0; j < 4; ++j) ow[j][r] *= alpha;
    }
    __syncthreads();
#pragma unroll
    for (int ks = 0; ks < 2; ++ks) {
      bf16x8 ap = LDV(Pw, l16, qd + 4 * ks);
#pragma unroll
      for (int j = 0; j < 4; ++j)
        ow[j] = __builtin_amdgcn_mfma_f32_16x16x32_bf16(ap, LDV(Vt, 16 * j + l16, qd + 4 * ks), ow[j], 0, 0, 0);
    }
  }

  // epilogue: accbf = bf16(g0*oc/lc + g2*ow/lw + selp)
#pragma unroll
  for (int r = 0; r < 4; ++r) {
    int sq = s0 + w * 16 + qd * 4 + r;
    size_t row = (size_t)b * 1024 + sq;
    float g0 = gat[row * 3 + 0], g2 = gat[row * 3 + 2];
    float c0 = g0 / lc[r], c2 = g2 / lw[r];
#pragma unroll
    for (int j = 0; j < 4; ++j) {
      size_t off = row * kD + h * 64 + 16 * j + l16;
      accbf[off] = (bf16)(oc[j][r] * c0 + ow[j][r] * c2 + selp[off]);
    }
  }
}

// ---- selected attention: writes selp = g1*out_sel (first writer of accb) ----
__global__ __launch_bounds__(256) void sel_attn2(const bf16* __restrict__ qbf, const bf16* __restrict__ kbf,
                                                 const bf16* __restrict__ vbf, const int* __restrict__ tk,
                                                 const float* __restrict__ gat, float* __restrict__ selp) {
  int wid = threadIdx.x >> 6, lane = threadIdx.x & 63;
  int g = blockIdx.x * 4 + wid;
  int h = g & 15, bs = g >> 4, b = bs >> 10, s = bs & 1023;
  __shared__ float qs[4][64];
  qs[wid][lane] = (float)qbf[(size_t)bs * kD + h * 64 + lane];
  __syncthreads();
  int m = lane & 15, dg = lane >> 4;
  int blk = tk[((size_t)(m >> 3) * 1024 + s) * 2 + b];     // top_idx[j, s, b]
  int tok = (m >> 3) * 1024 + blk * 16 + (m & 7);          // row in batch j=m>>3
  const bf16* kp = kbf + (size_t)tok * kD + h * 64 + dg * 16;
  bf16x8 k0 = *(const bf16x8*)kp;
  bf16x8 k1 = *(const bf16x8*)(kp + 8);
  float sc = 0.f;
#pragma unroll
  for (int i = 0; i < 8; ++i) sc += (float)k0[i] * qs[wid][dg * 16 + i];
#pragma unroll
  for (int i = 0; i < 8; ++i) sc += (float)k1[i] * qs[wid][dg * 16 + 8 + i];
  sc += __shfl_xor(sc, 16);
  sc += __shfl_xor(sc, 32);
  sc *= kInv;
  float mx = sc;
#pragma unroll
  for (int off = 8; off; off >>= 1) mx = fmaxf(mx, __shfl_xor(mx, off));
  float e = __expf(sc - mx);
  float ss = e;
#pragma unroll
  for (int off = 8; off; off >>= 1) ss += __shfl_xor(ss, off);
  float p = e / ss;
  const bf16* vb = vbf + h * 64 + lane;
  float o = 0.f;
#pragma unroll
  for (int mi = 0; mi < 16; ++mi) {
    int tm = __shfl(tok, mi);
    float pm = __shfl(p, mi);
    o += pm * (float)vb[(size_t)tm * kD];
  }
  selp[(size_t)bs * kD + h * 64 + lane] = gat[bs * 3 + 1] * o;
}

extern "C" void kernel_launch(void* const* d_in, const int* in_sizes, int n_in,
                              void* d_out, int out_size, void* d_ws, size_t ws_size,
                              hipStream_t stream) {
  const float* x   = (const float*)d_in[0];
  const float* Wq  = (const float*)d_in[1];
  const float* Wk  = (const float*)d_in[2];
  const float* Wv  = (const float*)d_in[3];
  const float* Wo  = (const float*)d_in[4];
  const float* bo  = (const float*)d_in[5];
  const float* Wg  = (const float*)d_in[6];
  const float* bg  = (const float*)d_in[7];
  const float* wkc = (const float*)d_in[8];
  const float* wvc = (const float*)d_in[9];
  const float* wpe = (const float*)d_in[10];
  float* out = (float*)d_out;

  float* ws    = (float*)d_ws;
  bf16*  qkvbf = (bf16*)ws;                    // 3 x 2097152 bf16 (= 3145728 f32)
  float* accb  = ws + 3145728;                 // 2097152 (sel partial, fp32)
  float* ck    = accb + 2097152;               // 131072
  float* cv    = ck + 131072;
  float* cxk   = cv + 131072;
  float* cxv   = cxk + 131072;
  float* M1    = cxv + 131072;                 // [1024][128]
  float* gat   = M1 + 131072;                  // 6144
  int*   tk    = (int*)(gat + 6144);           // 4096 ints
  bf16*  xbf   = (bf16*)(gat + 6144 + 4096);   // 2097152 bf16 (= 1048576 f32)
  bf16*  Wt4   = (bf16*)((float*)xbf + 1048576);   // 4 x 1048576 bf16 (= 2097152 f32)
  bf16*  accbf = (bf16*)((float*)Wt4 + 2097152);   // 2097152 bf16 (= 1048576 f32)
  float* skbuf  = (float*)accbf + 1048576;     // 16 x 131072 (ck|cv partials)
  float* skbuf2 = skbuf + 2097152;             // 8 x 131072 (M1 then imp partials)
  const bf16* qbf = qkvbf;
  const bf16* kbf = qkvbf + 2097152;
  const bf16* vbf = qkvbf + 2 * 2097152;

  prep_kernel<<<3584, 256, 0, stream>>>(x, wkc, wvc, Wg, bg, cxk, cxv, xbf, gat);
  transpose4<<<dim3(32, 32, 4), 256, 0, stream>>>(Wq, Wk, Wv, Wo, Wt4);

  gemm_qkv3<<<dim3(16, 16), 256, 0, stream>>>(xbf, Wt4, qkvbf, wpe);

  sgemm_nn_sk2<<<dim3(16, 2, 16), 256, 0, stream>>>(cxk, cxv, Wk, Wv, skbuf);
  reduce_ckcv<<<256, 256, 0, stream>>>(skbuf, ck, cv, wkc, wvc, wpe);

  sgemm_nt_sk<<<dim3(2, 16, 8), 256, 0, stream>>>(Wq, ck, skbuf2, 1024, 128, 1024, 128);
  reduce_sk<<<128, 256, 0, stream>>>(skbuf2, M1, 131072, 8);
  imp_sk<<<dim3(1, 32, 8), 256, 0, stream>>>(x, M1, skbuf2, 128);
  topk_wave<<<512, 256, 0, stream>>>(skbuf2, tk);

  sel_attn2<<<8192, 256, 0, stream>>>(qbf, kbf, vbf, tk, gat, accb);
  attn_mfma<<<dim3(16, 16, 2), 256, 0, stream>>>(qbf, kbf, vbf, ck, cv, gat, accb, accbf);

  gemm_out<<<dim3(16, 16), 256, 0, stream>>>(accbf, Wt4 + (size_t)3 * 1048576, out, bo);
}

// Round 7
// 217.344 us; speedup vs baseline: 5.3108x; 1.0210x over previous
//
#include <hip/hip_runtime.h>

// NativeSparseAttention round 7: attn K-loop restructured — double-buffered
// K/V chunks with prefetch-after-barrier (1 barrier/chunk, load latency hidden
// behind QK MFMA), wave-private P (no P barrier), prep+transpose fused.
// B=2 S=1024 D=1024 H=KV=16 HD=64 Nc=64 CB=16 SB=8 J=2 W=256

typedef __bf16 bf16;
typedef bf16 bf16x8 __attribute__((ext_vector_type(8)));
typedef float f32x4 __attribute__((ext_vector_type(4)));

constexpr int kD = 1024;
constexpr float kInv = 0.125f;  // 1/sqrt(64), exact power of 2

// Swizzled LDS tile: row stride 64 bf16 = 128 B = 32 banks; 16B chunk cb of row
// stored at slot cb^(row&7) -> every 64-lane b128 access conflict-free.
#define SWZ_IDX(row, cb) (((row) << 6) + (((cb) ^ ((row) & 7)) << 3))
#define LDV(arr, row, cb) (*(const bf16x8*)&(arr)[SWZ_IDX(row, cb)])

// Async 16B global->LDS; LDS dest = wave-uniform base + lane*16. One call per
// wave stages 8 rows x 64 cols; global chunk s8^l8 lands in slot s8 (SWZ match).
__device__ __forceinline__ void async_ld16(const bf16* g, bf16* l) {
  __builtin_amdgcn_global_load_lds(
      (const __attribute__((address_space(1))) unsigned int*)g,
      (__attribute__((address_space(3))) unsigned int*)l, 16, 0, 0);
}

// ---- fused prep: [0,512) cx ; [512,1536) x->bf16 ; [1536,3584) gates ;
//      [3584,7680) transpose 4 weights -> bf16 [C][R] ----
__global__ __launch_bounds__(256) void prep_all(const float* __restrict__ x, const float* __restrict__ wkc,
                                                const float* __restrict__ wvc, const float* __restrict__ Wg,
                                                const float* __restrict__ bg, const float* __restrict__ Wq,
                                                const float* __restrict__ Wk, const float* __restrict__ Wv,
                                                const float* __restrict__ Wo, float* __restrict__ cxk,
                                                float* __restrict__ cxv, bf16* __restrict__ xbf,
                                                float* __restrict__ gates, bf16* __restrict__ Wt4) {
  __shared__ float sh[32 * 33];
  int blk = blockIdx.x, tid = threadIdx.x;
  if (blk < 512) {  // cx
    int idx = blk * 256 + tid;
    int d = idx & 1023, bn = idx >> 10;
    const float* xp = x + (size_t)bn * 16 * kD + d;
    float a = 0.f, c = 0.f;
    for (int t = 0; t < 16; ++t) {
      float xv = xp[(size_t)t * kD];
      a += wkc[t] * xv;
      c += wvc[t] * xv;
    }
    cxk[idx] = a;
    cxv[idx] = c;
  } else if (blk < 1536) {  // cvt x -> bf16
    int i = (blk - 512) * 256 + tid;
    const float4* p = (const float4*)x + (size_t)i * 2;
    float4 a = p[0], b = p[1];
    bf16x8 v;
    v[0] = (bf16)a.x; v[1] = (bf16)a.y; v[2] = (bf16)a.z; v[3] = (bf16)a.w;
    v[4] = (bf16)b.x; v[5] = (bf16)b.y; v[6] = (bf16)b.z; v[7] = (bf16)b.w;
    *(bf16x8*)&xbf[(size_t)i * 8] = v;
  } else if (blk < 3584) {  // gates
    int bs = blk - 1536;
    float (*red)[256] = (float(*)[256])sh;
    const float* xp = x + (size_t)bs * kD;
    float p0 = 0.f, p1 = 0.f, p2 = 0.f;
    for (int d = tid; d < kD; d += 256) {
      float xv = xp[d];
      p0 += xv * Wg[d * 3 + 0];
      p1 += xv * Wg[d * 3 + 1];
      p2 += xv * Wg[d * 3 + 2];
    }
    red[0][tid] = p0; red[1][tid] = p1; red[2][tid] = p2;
    __syncthreads();
    for (int off = 128; off > 0; off >>= 1) {
      if (tid < off) {
        red[0][tid] += red[0][tid + off];
        red[1][tid] += red[1][tid + off];
        red[2][tid] += red[2][tid + off];
      }
      __syncthreads();
    }
    if (tid < 3) gates[bs * 3 + tid] = 1.f / (1.f + __expf(-(red[tid][0] + bg[tid])));
  } else {  // transpose
    int t4 = blk - 3584;
    int z = t4 >> 10, rem = t4 & 1023;
    const float* in = (z == 0) ? Wq : (z == 1) ? Wk : (z == 2) ? Wv : Wo;
    bf16* outp = Wt4 + (size_t)z * 1048576;
    int c0 = (rem & 31) * 32, r0 = (rem >> 5) * 32;
    float (*t)[33] = (float(*)[33])sh;
    int tx = tid & 31, ty = tid >> 5;
#pragma unroll
    for (int i = 0; i < 32; i += 8) t[ty + i][tx] = in[(size_t)(r0 + ty + i) * 1024 + c0 + tx];
    __syncthreads();
#pragma unroll
    for (int i = 0; i < 32; i += 8) outp[(size_t)(c0 + ty + i) * 1024 + r0 + tx] = (bf16)t[tx][ty + i];
  }
}

// ---- z-fused QKV GEMM: one 128x64 tile for all 3 weights; A-frags reused 3x ----
__global__ __launch_bounds__(256) void gemm_qkv3(const bf16* __restrict__ xbf, const bf16* __restrict__ Wt4,
                                                 bf16* __restrict__ qkv, const float* __restrict__ wpe) {
  __shared__ bf16 As[128 * 64];
  __shared__ bf16 Bs[3 * 64 * 64];
  int tid = threadIdx.x, w = tid >> 6, lane = tid & 63;
  int l8 = lane >> 3, s8 = lane & 7;
  int qd = lane >> 4, l16 = lane & 15;
  int row0 = blockIdx.y * 128, col0 = blockIdx.x * 64;
  int mr = (w & 1) * 64, nc = (w >> 1) * 32;
  f32x4 acc[3][4][2] = {};
  for (int k0 = 0; k0 < 1024; k0 += 64) {
    __syncthreads();
#pragma unroll
    for (int i = 0; i < 4; ++i) {
      int row = w * 32 + i * 8 + l8;
      async_ld16(&xbf[(size_t)(row0 + row) * 1024 + k0 + (s8 ^ l8) * 8], As + w * 2048 + i * 512);
    }
#pragma unroll
    for (int i = 0; i < 6; ++i) {
      int g = w * 6 + i;
      int z = g >> 3, rg = g & 7;
      int row = rg * 8 + l8;
      async_ld16(&Wt4[(size_t)z * 1048576 + (size_t)(col0 + row) * 1024 + k0 + (s8 ^ l8) * 8],
                 Bs + z * 4096 + rg * 512);
    }
    __syncthreads();
#pragma unroll
    for (int ks = 0; ks < 2; ++ks) {
      bf16x8 af[4];
#pragma unroll
      for (int i = 0; i < 4; ++i) af[i] = LDV(As, mr + i * 16 + l16, ks * 4 + qd);
#pragma unroll
      for (int z = 0; z < 3; ++z) {
        bf16x8 bfr[2];
#pragma unroll
        for (int j = 0; j < 2; ++j) bfr[j] = LDV(Bs + z * 4096, nc + j * 16 + l16, ks * 4 + qd);
#pragma unroll
        for (int i = 0; i < 4; ++i)
#pragma unroll
          for (int j = 0; j < 2; ++j)
            acc[z][i][j] = __builtin_amdgcn_mfma_f32_16x16x32_bf16(af[i], bfr[j], acc[z][i][j], 0, 0, 0);
      }
    }
  }
#pragma unroll
  for (int z = 0; z < 3; ++z) {
    bf16* C = qkv + (size_t)z * 2097152;
#pragma unroll
    for (int i = 0; i < 4; ++i)
#pragma unroll
      for (int j = 0; j < 2; ++j)
#pragma unroll
        for (int r = 0; r < 4; ++r) {
          int rr = row0 + mr + i * 16 + qd * 4 + r;
          int cc = col0 + nc + j * 16 + l16;
          float v = acc[z][i][j][r];
          if (z) v += wpe[(rr & 15) * kD + cc];
          C[(size_t)rr * kD + cc] = (bf16)v;
        }
  }
}

// ---- bf16 MFMA GEMM core (gemm_out): BM=128 BN=64 BK=64, async staging ----
__device__ __forceinline__ void gemm_core(const bf16* __restrict__ A, const bf16* __restrict__ Bt,
                                          int K, int row0, int col0, bf16* As, bf16* Bs,
                                          int tid, f32x4 (&acc)[4][2]) {
  int w = tid >> 6, lane = tid & 63;
  int l8 = lane >> 3, s8 = lane & 7;
  int qd = lane >> 4, l16 = lane & 15;
  int mr = (w & 1) * 64, nc = (w >> 1) * 32;
  for (int k0 = 0; k0 < K; k0 += 64) {
    __syncthreads();
#pragma unroll
    for (int i = 0; i < 4; ++i) {
      int row = w * 32 + i * 8 + l8;
      async_ld16(&A[(size_t)(row0 + row) * K + k0 + (s8 ^ l8) * 8], As + w * 2048 + i * 512);
    }
#pragma unroll
    for (int i = 0; i < 2; ++i) {
      int row = w * 16 + i * 8 + l8;
      async_ld16(&Bt[(size_t)(col0 + row) * K + k0 + (s8 ^ l8) * 8], Bs + w * 1024 + i * 512);
    }
    __syncthreads();
#pragma unroll
    for (int ks = 0; ks < 2; ++ks) {
      bf16x8 af[4], bfr[2];
#pragma unroll
      for (int i = 0; i < 4; ++i) af[i] = LDV(As, mr + i * 16 + l16, ks * 4 + qd);
#pragma unroll
      for (int j = 0; j < 2; ++j) bfr[j] = LDV(Bs, nc + j * 16 + l16, ks * 4 + qd);
#pragma unroll
      for (int i = 0; i < 4; ++i)
#pragma unroll
        for (int j = 0; j < 2; ++j)
          acc[i][j] = __builtin_amdgcn_mfma_f32_16x16x32_bf16(af[i], bfr[j], acc[i][j], 0, 0, 0);
    }
  }
}

// ---- out = accbf@Wo + bo, fp32 out ----
__global__ __launch_bounds__(256) void gemm_out(const bf16* __restrict__ accbf, const bf16* __restrict__ Wot,
                                                float* __restrict__ out, const float* __restrict__ bo) {
  __shared__ bf16 As[128 * 64];
  __shared__ bf16 Bs[64 * 64];
  int tid = threadIdx.x;
  int row0 = blockIdx.y * 128, col0 = blockIdx.x * 64;
  f32x4 acc[4][2] = {};
  gemm_core(accbf, Wot, 1024, row0, col0, As, Bs, tid, acc);
  int w = tid >> 6, lane = tid & 63, qd = lane >> 4, l16 = lane & 15;
  int mr = (w & 1) * 64, nc = (w >> 1) * 32;
#pragma unroll
  for (int i = 0; i < 4; ++i)
#pragma unroll
    for (int j = 0; j < 2; ++j)
#pragma unroll
      for (int r = 0; r < 4; ++r) {
        int rr = row0 + mr + i * 16 + qd * 4 + r;
        int cc = col0 + nc + j * 16 + l16;
        out[(size_t)rr * kD + cc] = acc[i][j][r] + bo[cc];
      }
}

// ---- split-K fp32 NN GEMM for ck|cv merged: z<8 -> cxk, z>=8 -> cxv ----
__global__ __launch_bounds__(256) void sgemm_nn_sk2(const float* __restrict__ Ak, const float* __restrict__ Av,
                                                    const float* __restrict__ Wk, const float* __restrict__ Wv,
                                                    float* __restrict__ part) {
  __shared__ float As2[64][17];
  __shared__ float Bs[16][68];
  const float* A = (blockIdx.z < 8) ? Ak : Av;
  const float* Bm = (blockIdx.z < 8) ? Wk : Wv;
  int tid = threadIdx.x;
  int tm = tid >> 4, tn = tid & 15;
  int row0 = blockIdx.y * 64, col0 = blockIdx.x * 64;
  int k0b = (blockIdx.z & 7) * 128;
  float acc[4][4] = {{0.f}};
  for (int k0 = k0b; k0 < k0b + 128; k0 += 16) {
#pragma unroll
    for (int i = 0; i < 4; ++i) {
      int idx = tid + i * 256;
      As2[idx >> 4][idx & 15] = A[(size_t)(row0 + (idx >> 4)) * 1024 + k0 + (idx & 15)];
      Bs[idx >> 6][idx & 63] = Bm[(size_t)(k0 + (idx >> 6)) * 1024 + col0 + (idx & 63)];
    }
    __syncthreads();
#pragma unroll
    for (int kk = 0; kk < 16; ++kk) {
      float a[4], b[4];
#pragma unroll
      for (int i = 0; i < 4; ++i) a[i] = As2[tm * 4 + i][kk];
#pragma unroll
      for (int j = 0; j < 4; ++j) b[j] = Bs[kk][tn * 4 + j];
#pragma unroll
      for (int i = 0; i < 4; ++i)
#pragma unroll
        for (int j = 0; j < 4; ++j) acc[i][j] += a[i] * b[j];
    }
    __syncthreads();
  }
  float* pp = part + (size_t)blockIdx.z * 131072;
#pragma unroll
  for (int i = 0; i < 4; ++i) {
    float4 v = make_float4(acc[i][0], acc[i][1], acc[i][2], acc[i][3]);
    *(float4*)&pp[(size_t)(row0 + tm * 4 + i) * 1024 + col0 + tn * 4] = v;
  }
}

// ---- reduce ck|cv partials with inline cpe ----
__global__ __launch_bounds__(256) void reduce_ckcv(const float* __restrict__ part, float* __restrict__ ck,
                                                   float* __restrict__ cv, const float* __restrict__ wkc,
                                                   const float* __restrict__ wvc, const float* __restrict__ wpe) {
  int half = blockIdx.x >> 7;
  int i4 = (((blockIdx.x & 127) * 256) + threadIdx.x) * 4;
  const float* pp = part + (size_t)half * 8 * 131072;
  float4 s = *(const float4*)&pp[i4];
  for (int z = 1; z < 8; ++z) {
    float4 p = *(const float4*)&pp[(size_t)z * 131072 + i4];
    s.x += p.x; s.y += p.y; s.z += p.z; s.w += p.w;
  }
  int c = i4 & 1023;
  const float* w = half ? wvc : wkc;
  float e0 = 0.f, e1 = 0.f, e2 = 0.f, e3 = 0.f;
  for (int t = 0; t < 16; ++t) {
    float wt = w[t];
    const float* pe = wpe + t * 1024 + c;
    e0 += wt * pe[0]; e1 += wt * pe[1]; e2 += wt * pe[2]; e3 += wt * pe[3];
  }
  s.x += e0; s.y += e1; s.z += e2; s.w += e3;
  float* dst = half ? cv : ck;
  *(float4*)&dst[i4] = s;
}

// ---- split-K fp32 NT GEMM: M1 partials (imp path, fp32-exact) ----
__global__ __launch_bounds__(256) void sgemm_nt_sk(const float* __restrict__ A, const float* __restrict__ Bt,
                                                   float* __restrict__ part, int M, int N, int K, int KC) {
  __shared__ float As2[64][17];
  __shared__ float Bs2[64][17];
  int tid = threadIdx.x;
  int tm = tid >> 4, tn = tid & 15;
  int row0 = blockIdx.y * 64, col0 = blockIdx.x * 64;
  int k0b = blockIdx.z * KC;
  float acc[4][4] = {{0.f}};
  for (int k0 = k0b; k0 < k0b + KC; k0 += 16) {
#pragma unroll
    for (int i = 0; i < 4; ++i) {
      int idx = tid + i * 256;
      As2[idx >> 4][idx & 15] = A[(size_t)(row0 + (idx >> 4)) * K + k0 + (idx & 15)];
      Bs2[idx >> 4][idx & 15] = Bt[(size_t)(col0 + (idx >> 4)) * K + k0 + (idx & 15)];
    }
    __syncthreads();
#pragma unroll
    for (int kk = 0; kk < 16; ++kk) {
      float a[4], b[4];
#pragma unroll
      for (int i = 0; i < 4; ++i) a[i] = As2[tm * 4 + i][kk];
#pragma unroll
      for (int j = 0; j < 4; ++j) b[j] = Bs2[tn * 4 + j][kk];
#pragma unroll
      for (int i = 0; i < 4; ++i)
#pragma unroll
        for (int j = 0; j < 4; ++j) acc[i][j] += a[i] * b[j];
    }
    __syncthreads();
  }
  float* pp = part + (size_t)blockIdx.z * M * N;
#pragma unroll
  for (int i = 0; i < 4; ++i) {
    float4 v = make_float4(acc[i][0], acc[i][1], acc[i][2], acc[i][3]);
    *(float4*)&pp[(size_t)(row0 + tm * 4 + i) * N + col0 + tn * 4] = v;
  }
}

// ---- generic split-K reduce (M1) ----
__global__ __launch_bounds__(256) void reduce_sk(const float* __restrict__ part, float* __restrict__ C,
                                                 int total, int SK) {
  int i4 = (blockIdx.x * 256 + threadIdx.x) * 4;
  float4 s = *(const float4*)&part[i4];
  for (int z = 1; z < SK; ++z) {
    float4 p = *(const float4*)&part[(size_t)z * total + i4];
    s.x += p.x; s.y += p.y; s.z += p.z; s.w += p.w;
  }
  *(float4*)&C[i4] = s;
}

// ---- split-K imp partials ----
__global__ __launch_bounds__(256) void imp_sk(const float* __restrict__ A, const float* __restrict__ M1,
                                              float* __restrict__ part, int KC) {
  __shared__ float As2[64][17];
  __shared__ float Bs[16][68];
  int tid = threadIdx.x;
  int tm = tid >> 4, tn = tid & 15;
  int row0 = blockIdx.y * 64;
  int colbase = (row0 >> 10) * 64;
  int k0b = blockIdx.z * KC;
  float acc[4][4] = {{0.f}};
  for (int k0 = k0b; k0 < k0b + KC; k0 += 16) {
#pragma unroll
    for (int i = 0; i < 4; ++i) {
      int idx = tid + i * 256;
      As2[idx >> 4][idx & 15] = A[(size_t)(row0 + (idx >> 4)) * 1024 + k0 + (idx & 15)];
    }
#pragma unroll
    for (int rr = 0; rr < 4; ++rr) {
      int id2 = tid + rr * 256;
      Bs[id2 >> 6][id2 & 63] = M1[(size_t)(k0 + (id2 >> 6)) * 128 + colbase + (id2 & 63)];
    }
    __syncthreads();
#pragma unroll
    for (int kk = 0; kk < 16; ++kk) {
      float a[4], b[4];
#pragma unroll
      for (int i = 0; i < 4; ++i) a[i] = As2[tm * 4 + i][kk];
#pragma unroll
      for (int j = 0; j < 4; ++j) b[j] = Bs[kk][tn * 4 + j];
#pragma unroll
      for (int i = 0; i < 4; ++i)
#pragma unroll
        for (int j = 0; j < 4; ++j) acc[i][j] += a[i] * b[j];
    }
    __syncthreads();
  }
  float* pp = part + (size_t)blockIdx.z * 131072;
#pragma unroll
  for (int i = 0; i < 4; ++i) {
    float4 v = make_float4(acc[i][0], acc[i][1], acc[i][2], acc[i][3]);
    *(float4*)&pp[(size_t)(row0 + tm * 4 + i) * 64 + tn * 4] = v;
  }
}

// ---- wave-parallel imp-reduce + top-2: one wave per (b,s), lane = block n ----
__global__ __launch_bounds__(256) void topk_wave(const float* __restrict__ part, int* __restrict__ tk) {
  int wid = threadIdx.x >> 6, lane = threadIdx.x & 63;
  int bs = blockIdx.x * 4 + wid;
  float v = 0.f;
  const float* p = part + (size_t)bs * 64 + lane;
#pragma unroll
  for (int z = 0; z < 8; ++z) v += p[(size_t)z * 131072];
  float v1 = v; int i1 = lane;
#pragma unroll
  for (int off = 32; off; off >>= 1) {
    float ov = __shfl_xor(v1, off);
    int oi = __shfl_xor(i1, off);
    if (ov > v1 || (ov == v1 && oi < i1)) { v1 = ov; i1 = oi; }
  }
  float v2 = (lane == i1) ? -3.0e38f : v;
  int i2 = lane;
#pragma unroll
  for (int off = 32; off; off >>= 1) {
    float ov = __shfl_xor(v2, off);
    int oi = __shfl_xor(i2, off);
    if (ov > v2 || (ov == v2 && oi < i2)) { v2 = ov; i2 = oi; }
  }
  if (lane == 0) {
    tk[bs * 2] = i1;
    tk[bs * 2 + 1] = i2;
  }
}

// ---- staging helpers for comp attention (fp32 ck/cv -> swizzled bf16 LDS) ----
__device__ inline void stage_rows_bf16(const float* __restrict__ src, size_t pitch,
                                       bf16* __restrict__ dst, int tid) {
  int r = tid >> 2, qq = tid & 3;
  const float4* sp = (const float4*)(src + (size_t)r * pitch) + qq * 4;
  float4 f0 = sp[0], f1 = sp[1], f2 = sp[2], f3 = sp[3];
  bf16x8 lo, hi;
  lo[0] = (bf16)f0.x; lo[1] = (bf16)f0.y; lo[2] = (bf16)f0.z; lo[3] = (bf16)f0.w;
  lo[4] = (bf16)f1.x; lo[5] = (bf16)f1.y; lo[6] = (bf16)f1.z; lo[7] = (bf16)f1.w;
  hi[0] = (bf16)f2.x; hi[1] = (bf16)f2.y; hi[2] = (bf16)f2.z; hi[3] = (bf16)f2.w;
  hi[4] = (bf16)f3.x; hi[5] = (bf16)f3.y; hi[6] = (bf16)f3.z; hi[7] = (bf16)f3.w;
  int cb = qq * 2;
  *(bf16x8*)&dst[SWZ_IDX(r, cb)]     = lo;
  *(bf16x8*)&dst[SWZ_IDX(r, cb + 1)] = hi;
}

__device__ inline void stage_cols_bf16(const float* __restrict__ src, size_t pitch,
                                       bf16* __restrict__ dst, int tid) {
  int lane = tid & 63, w = tid >> 6;
  const float4* sp = (const float4*)(src + (size_t)lane * pitch + w * 16);
  float4 f[4];
  f[0] = sp[0]; f[1] = sp[1]; f[2] = sp[2]; f[3] = sp[3];
  const float* ff = (const float*)f;
#pragma unroll
  for (int i = 0; i < 16; ++i) {
    int d = w * 16 + i;
    dst[(d << 6) + ((((lane >> 3) ^ (d & 7))) << 3) + (lane & 7)] = (bf16)ff[i];
  }
}

// ---- fused comp + window MFMA flash attention, double-buffered K/V ----
__global__ __launch_bounds__(256) void attn_mfma(const bf16* __restrict__ qbf, const bf16* __restrict__ kbf,
                                                 const bf16* __restrict__ vbf, const float* __restrict__ ck,
                                                 const float* __restrict__ cv, const float* __restrict__ gat,
                                                 const float* __restrict__ selp, bf16* __restrict__ accbf) {
  __shared__ bf16 Qs[4096];
  __shared__ bf16 Kb[2][4096];
  __shared__ bf16 Vb[2][4096];
  __shared__ bf16 Ps[4096];
  int tid = threadIdx.x, w = tid >> 6, lane = tid & 63;
  int l8 = lane >> 3, s8 = lane & 7;
  int qd = lane >> 4, l16 = lane & 15;
  int s0 = blockIdx.x * 64, h = blockIdx.y, b = blockIdx.z;
  bf16* Pw = Ps + w * 1024;  // wave-private: DS in-order + lgkmcnt => no barrier needed P->PV

  // stage Q (async) + comp K/V (manual, fp32 src) into buf0
  const bf16* qsrc = qbf + ((size_t)(b * 1024 + s0)) * kD + h * 64;
#pragma unroll
  for (int i = 0; i < 2; ++i) {
    int row = w * 16 + i * 8 + l8;
    async_ld16(&qsrc[(size_t)row * kD + (s8 ^ l8) * 8], Qs + w * 1024 + i * 512);
  }
  stage_rows_bf16(ck + ((size_t)(b * 64)) * kD + h * 64, kD, Kb[0], tid);
  stage_cols_bf16(cv + ((size_t)(b * 64)) * kD + h * 64, kD, Vb[0], tid);
  __syncthreads();

  int kb0 = s0 - 256; if (kb0 < 0) kb0 = 0;
  int nck = (s0 + 64 - kb0) >> 6;  // 1..5 window chunks

  // prefetch window chunk 0 into buf1 (async K fire-and-forget; V -> VGPRs)
  bf16x8 pv0, pv1;
  {
    const bf16* ksrc = kbf + ((size_t)(b * 1024 + kb0)) * kD + h * 64;
#pragma unroll
    for (int i = 0; i < 2; ++i) {
      int row = w * 16 + i * 8 + l8;
      async_ld16(&ksrc[(size_t)row * kD + (s8 ^ l8) * 8], Kb[1] + w * 1024 + i * 512);
    }
    const bf16* vsrc = vbf + ((size_t)(b * 1024 + kb0 + lane)) * kD + h * 64 + w * 16;
    pv0 = *(const bf16x8*)vsrc;
    pv1 = *(const bf16x8*)(vsrc + 8);
  }

  // ---- compressed attention on buf0 ----
  f32x4 oc[4] = {};
  float lc[4];
  {
    f32x4 sacc[4] = {};
#pragma unroll
    for (int ks = 0; ks < 2; ++ks) {
      bf16x8 aq = LDV(Qs, w * 16 + l16, qd + 4 * ks);
#pragma unroll
      for (int j = 0; j < 4; ++j)
        sacc[j] = __builtin_amdgcn_mfma_f32_16x16x32_bf16(aq, LDV(Kb[0], 16 * j + l16, qd + 4 * ks), sacc[j], 0, 0, 0);
    }
    // store chunk0's V into buf1 (vmcnt wait hidden behind the QK MFMAs above)
    {
      bf16* Vt = Vb[1];
#pragma unroll
      for (int i = 0; i < 8; ++i) { int d = w * 16 + i;     Vt[(d << 6) + ((l8 ^ (d & 7)) << 3) + s8] = pv0[i]; }
#pragma unroll
      for (int i = 0; i < 8; ++i) { int d = w * 16 + 8 + i; Vt[(d << 6) + ((l8 ^ (d & 7)) << 3) + s8] = pv1[i]; }
    }
#pragma unroll
    for (int j = 0; j < 4; ++j)
#pragma unroll
      for (int r = 0; r < 4; ++r) sacc[j][r] *= kInv;
#pragma unroll
    for (int r = 0; r < 4; ++r) {
      float mx = sacc[0][r];
#pragma unroll
      for (int j = 1; j < 4; ++j) mx = fmaxf(mx, sacc[j][r]);
#pragma unroll
      for (int off = 8; off; off >>= 1) mx = fmaxf(mx, __shfl_xor(mx, off));
      int qrow = qd * 4 + r;
      float rs = 0.f;
#pragma unroll
      for (int j = 0; j < 4; ++j) {
        float e = __expf(sacc[j][r] - mx);
        int col = l16 + 16 * j;
        Pw[(qrow << 6) + ((((col >> 3) ^ (qrow & 7))) << 3) + (col & 7)] = (bf16)e;
        rs += e;
      }
#pragma unroll
      for (int off = 8; off; off >>= 1) rs += __shfl_xor(rs, off);
      lc[r] = rs;
    }
#pragma unroll
    for (int ks = 0; ks < 2; ++ks) {
      bf16x8 ap = LDV(Pw, l16, qd + 4 * ks);
#pragma unroll
      for (int j = 0; j < 4; ++j)
        oc[j] = __builtin_amdgcn_mfma_f32_16x16x32_bf16(ap, LDV(Vb[0], 16 * j + l16, qd + 4 * ks), oc[j], 0, 0, 0);
    }
  }

  // ---- sliding-window attention, 1 barrier per chunk, prefetch-after-barrier ----
  f32x4 ow[4] = {};
  float mw[4], lw[4];
#pragma unroll
  for (int r = 0; r < 4; ++r) { mw[r] = -1e30f; lw[r] = 0.f; }
  for (int c = 0; c < nck; ++c) {
    int cur = (c & 1) ^ 1, oth = c & 1;
    int kbase = kb0 + c * 64;
    __syncthreads();  // chunk c async-K drained; V stores visible; buf[oth] readers done
    if (c + 1 < nck) {
      const bf16* ksrc = kbf + ((size_t)(b * 1024 + kbase + 64)) * kD + h * 64;
#pragma unroll
      for (int i = 0; i < 2; ++i) {
        int row = w * 16 + i * 8 + l8;
        async_ld16(&ksrc[(size_t)row * kD + (s8 ^ l8) * 8], Kb[oth] + w * 1024 + i * 512);
      }
      const bf16* vsrc = vbf + ((size_t)(b * 1024 + kbase + 64 + lane)) * kD + h * 64 + w * 16;
      pv0 = *(const bf16x8*)vsrc;
      pv1 = *(const bf16x8*)(vsrc + 8);
    }
    f32x4 sacc[4] = {};
#pragma unroll
    for (int ks = 0; ks < 2; ++ks) {
      bf16x8 aq = LDV(Qs, w * 16 + l16, qd + 4 * ks);
#pragma unroll
      for (int j = 0; j < 4; ++j)
        sacc[j] = __builtin_amdgcn_mfma_f32_16x16x32_bf16(aq, LDV(Kb[cur], 16 * j + l16, qd + 4 * ks), sacc[j], 0, 0, 0);
    }
    if (c + 1 < nck) {  // V(c+1) VGPR -> LDS; vmcnt wait hidden behind QK
      bf16* Vt = Vb[oth];
#pragma unroll
      for (int i = 0; i < 8; ++i) { int d = w * 16 + i;     Vt[(d << 6) + ((l8 ^ (d & 7)) << 3) + s8] = pv0[i]; }
#pragma unroll
      for (int i = 0; i < 8; ++i) { int d = w * 16 + 8 + i; Vt[(d << 6) + ((l8 ^ (d & 7)) << 3) + s8] = pv1[i]; }
    }
#pragma unroll
    for (int j = 0; j < 4; ++j)
#pragma unroll
      for (int r = 0; r < 4; ++r) {
        int key = kbase + 16 * j + l16;
        int sq = s0 + w * 16 + qd * 4 + r;
        float sc = sacc[j][r] * kInv;
        sacc[j][r] = (key <= sq && sq - key <= 256) ? sc : -1e30f;
      }
#pragma unroll
    for (int r = 0; r < 4; ++r) {
      float mx = sacc[0][r];
#pragma unroll
      for (int j = 1; j < 4; ++j) mx = fmaxf(mx, sacc[j][r]);
#pragma unroll
      for (int off = 8; off; off >>= 1) mx = fmaxf(mx, __shfl_xor(mx, off));
      float mn = fmaxf(mw[r], mx);
      float alpha = __expf(mw[r] - mn);
      mw[r] = mn;
      int qrow = qd * 4 + r;
      float rs = 0.f;
#pragma unroll
      for (int j = 0; j < 4; ++j) {
        float e = __expf(sacc[j][r] - mn);
        int col = l16 + 16 * j;
        Pw[(qrow << 6) + ((((col >> 3) ^ (qrow & 7))) << 3) + (col & 7)] = (bf16)e;
        rs += e;
      }
#pragma unroll
      for (int off = 8; off; off >>= 1) rs += __shfl_xor(rs, off);
      lw[r] = lw[r] * alpha + rs;
#pragma unroll
      for (int j = 0; j < 4; ++j) ow[j][r] *= alpha;
    }
#pragma unroll
    for (int ks = 0; ks < 2; ++ks) {
      bf16x8 ap = LDV(Pw, l16, qd + 4 * ks);
#pragma unroll
      for (int j = 0; j < 4; ++j)
        ow[j] = __builtin_amdgcn_mfma_f32_16x16x32_bf16(ap, LDV(Vb[cur], 16 * j + l16, qd + 4 * ks), ow[j], 0, 0, 0);
    }
  }

  // epilogue: accbf = bf16(g0*oc/lc + g2*ow/lw + selp)
#pragma unroll
  for (int r = 0; r < 4; ++r) {
    int sq = s0 + w * 16 + qd * 4 + r;
    size_t row = (size_t)b * 1024 + sq;
    float g0 = gat[row * 3 + 0], g2 = gat[row * 3 + 2];
    float c0 = g0 / lc[r], c2 = g2 / lw[r];
#pragma unroll
    for (int j = 0; j < 4; ++j) {
      size_t off = row * kD + h * 64 + 16 * j + l16;
      accbf[off] = (bf16)(oc[j][r] * c0 + ow[j][r] * c2 + selp[off]);
    }
  }
}

// ---- selected attention: writes selp = g1*out_sel ----
__global__ __launch_bounds__(256) void sel_attn2(const bf16* __restrict__ qbf, const bf16* __restrict__ kbf,
                                                 const bf16* __restrict__ vbf, const int* __restrict__ tk,
                                                 const float* __restrict__ gat, float* __restrict__ selp) {
  int wid = threadIdx.x >> 6, lane = threadIdx.x & 63;
  int g = blockIdx.x * 4 + wid;
  int h = g & 15, bs = g >> 4, b = bs >> 10, s = bs & 1023;
  __shared__ float qs[4][64];
  qs[wid][lane] = (float)qbf[(size_t)bs * kD + h * 64 + lane];
  __syncthreads();
  int m = lane & 15, dg = lane >> 4;
  int blk = tk[((size_t)(m >> 3) * 1024 + s) * 2 + b];
  int tok = (m >> 3) * 1024 + blk * 16 + (m & 7);
  const bf16* kp = kbf + (size_t)tok * kD + h * 64 + dg * 16;
  bf16x8 k0 = *(const bf16x8*)kp;
  bf16x8 k1 = *(const bf16x8*)(kp + 8);
  float sc = 0.f;
#pragma unroll
  for (int i = 0; i < 8; ++i) sc += (float)k0[i] * qs[wid][dg * 16 + i];
#pragma unroll
  for (int i = 0; i < 8; ++i) sc += (float)k1[i] * qs[wid][dg * 16 + 8 + i];
  sc += __shfl_xor(sc, 16);
  sc += __shfl_xor(sc, 32);
  sc *= kInv;
  float mx = sc;
#pragma unroll
  for (int off = 8; off; off >>= 1) mx = fmaxf(mx, __shfl_xor(mx, off));
  float e = __expf(sc - mx);
  float ss = e;
#pragma unroll
  for (int off = 8; off; off >>= 1) ss += __shfl_xor(ss, off);
  float p = e / ss;
  const bf16* vb = vbf + h * 64 + lane;
  float o = 0.f;
#pragma unroll
  for (int mi = 0; mi < 16; ++mi) {
    int tm = __shfl(tok, mi);
    float pm = __shfl(p, mi);
    o += pm * (float)vb[(size_t)tm * kD];
  }
  selp[(size_t)bs * kD + h * 64 + lane] = gat[bs * 3 + 1] * o;
}

extern "C" void kernel_launch(void* const* d_in, const int* in_sizes, int n_in,
                              void* d_out, int out_size, void* d_ws, size_t ws_size,
                              hipStream_t stream) {
  const float* x   = (const float*)d_in[0];
  const float* Wq  = (const float*)d_in[1];
  const float* Wk  = (const float*)d_in[2];
  const float* Wv  = (const float*)d_in[3];
  const float* Wo  = (const float*)d_in[4];
  const float* bo  = (const float*)d_in[5];
  const float* Wg  = (const float*)d_in[6];
  const float* bg  = (const float*)d_in[7];
  const float* wkc = (const float*)d_in[8];
  const float* wvc = (const float*)d_in[9];
  const float* wpe = (const float*)d_in[10];
  float* out = (float*)d_out;

  float* ws    = (float*)d_ws;
  bf16*  qkvbf = (bf16*)ws;                    // 3 x 2097152 bf16
  float* accb  = ws + 3145728;                 // 2097152 (sel partial, fp32)
  float* ck    = accb + 2097152;               // 131072
  float* cv    = ck + 131072;
  float* cxk   = cv + 131072;
  float* cxv   = cxk + 131072;
  float* M1    = cxv + 131072;                 // [1024][128]
  float* gat   = M1 + 131072;                  // 6144
  int*   tk    = (int*)(gat + 6144);           // 4096 ints
  bf16*  xbf   = (bf16*)(gat + 6144 + 4096);   // 2097152 bf16
  bf16*  Wt4   = (bf16*)((float*)xbf + 1048576);   // 4 x 1048576 bf16
  bf16*  accbf = (bf16*)((float*)Wt4 + 2097152);   // 2097152 bf16
  float* skbuf  = (float*)accbf + 1048576;     // 16 x 131072 (ck|cv partials)
  float* skbuf2 = skbuf + 2097152;             // 8 x 131072 (M1 then imp partials)
  const bf16* qbf = qkvbf;
  const bf16* kbf = qkvbf + 2097152;
  const bf16* vbf = qkvbf + 2 * 2097152;

  prep_all<<<7680, 256, 0, stream>>>(x, wkc, wvc, Wg, bg, Wq, Wk, Wv, Wo, cxk, cxv, xbf, gat, Wt4);

  gemm_qkv3<<<dim3(16, 16), 256, 0, stream>>>(xbf, Wt4, qkvbf, wpe);

  sgemm_nn_sk2<<<dim3(16, 2, 16), 256, 0, stream>>>(cxk, cxv, Wk, Wv, skbuf);
  reduce_ckcv<<<256, 256, 0, stream>>>(skbuf, ck, cv, wkc, wvc, wpe);

  sgemm_nt_sk<<<dim3(2, 16, 8), 256, 0, stream>>>(Wq, ck, skbuf2, 1024, 128, 1024, 128);
  reduce_sk<<<128, 256, 0, stream>>>(skbuf2, M1, 131072, 8);
  imp_sk<<<dim3(1, 32, 8), 256, 0, stream>>>(x, M1, skbuf2, 128);
  topk_wave<<<512, 256, 0, stream>>>(skbuf2, tk);

  sel_attn2<<<8192, 256, 0, stream>>>(qbf, kbf, vbf, tk, gat, accb);
  attn_mfma<<<dim3(16, 16, 2), 256, 0, stream>>>(qbf, kbf, vbf, ck, cv, gat, accb, accbf);

  gemm_out<<<dim3(16, 16), 256, 0, stream>>>(accbf, Wt4 + (size_t)3 * 1048576, out, bo);
}